// Round 3
// baseline (1575.234 us; speedup 1.0000x reference)
//
#include <hip/hip_runtime.h>

// pSGM non-local block, MI355X (round 3: exact-fp32 f path via 3-plane trunc split).
// Softmax over N=12544 with std-11 logits: output scale is set by "hub" rows through
// the BN variance, so f must match fp32 to ~1e-5 (near-tie winner flips otherwise).
// f-path GEMMs: 6-term bf16 MFMA on exact 3-plane truncation splits; k_stats6 and
// k_pv6 share one accumulation order (bit-identical f). Smooth paths stay bf16;
// y uses 2-plane store + 3-term W-conv.

#define B_ 2
#define C_ 256
#define CI_ 128
#define NPIX 12544
#define NS 3136
#define SLICES 8

typedef short bf16x8 __attribute__((ext_vector_type(8)));
typedef float f32x4 __attribute__((ext_vector_type(4)));
typedef float f32x8 __attribute__((ext_vector_type(8)));

__device__ __forceinline__ short f2bf(float f) {
    unsigned u = __float_as_uint(f);
    u = (u + 0x7fff + ((u >> 16) & 1)) >> 16;   // RNE
    return (short)u;
}
__device__ __forceinline__ float bf2f(short s) {
    return __uint_as_float(((unsigned)(unsigned short)s) << 16);
}
__device__ __forceinline__ f32x4 mfma16(bf16x8 a, bf16x8 b, f32x4 c) {
    return __builtin_amdgcn_mfma_f32_16x16x32_bf16(a, b, c, 0, 0, 0);
}

struct Frag3 { bf16x8 h, m, l; };
struct Frag2 { bf16x8 h, m; };

__device__ __forceinline__ Frag3 split8_3(const float* __restrict__ p) {
    Frag3 f;
    f32x8 v = *(const f32x8*)p;
#pragma unroll
    for (int j = 0; j < 8; j++) {
        float x = v[j];
        unsigned uh = __float_as_uint(x) & 0xffff0000u;
        float r1 = x - __uint_as_float(uh);
        unsigned um = __float_as_uint(r1) & 0xffff0000u;
        float r2 = r1 - __uint_as_float(um);
        f.h[j] = (short)(uh >> 16);
        f.m[j] = (short)(um >> 16);
        f.l[j] = f2bf(r2);
    }
    return f;
}
__device__ __forceinline__ Frag2 split8_2(const float* __restrict__ p) {
    Frag2 f;
    f32x8 v = *(const f32x8*)p;
#pragma unroll
    for (int j = 0; j < 8; j++) {
        float x = v[j];
        unsigned uh = __float_as_uint(x) & 0xffff0000u;
        float r1 = x - __uint_as_float(uh);
        f.h[j] = (short)(uh >> 16);
        f.m[j] = f2bf(r1);
    }
    return f;
}
__device__ __forceinline__ Frag3 ld3(const short* __restrict__ h, const short* __restrict__ m,
                                     const short* __restrict__ l, size_t off) {
    Frag3 f;
    f.h = *(const bf16x8*)(h + off);
    f.m = *(const bf16x8*)(m + off);
    f.l = *(const bf16x8*)(l + off);
    return f;
}
// 6-term product — order must be IDENTICAL everywhere f is computed
__device__ __forceinline__ f32x4 mm6(Frag3 a, Frag3 b, f32x4 acc) {
    acc = mfma16(a.h, b.l, acc);
    acc = mfma16(a.l, b.h, acc);
    acc = mfma16(a.m, b.m, acc);
    acc = mfma16(a.m, b.h, acc);
    acc = mfma16(a.h, b.m, acc);
    acc = mfma16(a.h, b.h, acc);
    return acc;
}
__device__ __forceinline__ f32x4 mm3(Frag2 a, Frag2 b, f32x4 acc) {
    acc = mfma16(a.m, b.h, acc);
    acc = mfma16(a.h, b.m, acc);
    acc = mfma16(a.h, b.h, acc);
    return acc;
}

// ---- transpose: (C_,NPIX) fp32 -> (NPIX,C_) fp32 ----
__global__ void k_transpose(const float* __restrict__ src, float* __restrict__ dst) {
    __shared__ float tile[32][33];
    int b = blockIdx.z;
    const float* s = src + (size_t)b * C_ * NPIX;
    float* d = dst + (size_t)b * NPIX * C_;
    int p0 = blockIdx.x * 32, c0 = blockIdx.y * 32;
    for (int i = threadIdx.y; i < 32; i += 8)
        tile[i][threadIdx.x] = s[(size_t)(c0 + i) * NPIX + p0 + threadIdx.x];
    __syncthreads();
    for (int i = threadIdx.y; i < 32; i += 8)
        d[(size_t)(p0 + i) * C_ + c0 + threadIdx.x] = tile[threadIdx.x][i];
}

// ---- theta conv: 6-term MFMA, 3-plane bf16 out ----
__global__ __launch_bounds__(256) void k_conv6p(const float* __restrict__ A,
        const float* __restrict__ W, const float* __restrict__ bias,
        short* __restrict__ oh, short* __restrict__ om, short* __restrict__ ol) {
    int wid = threadIdx.x >> 6, lane = threadIdx.x & 63;
    int quad = lane >> 4, l16 = lane & 15;
    int b = blockIdx.y;
    const float* Ab = A + (size_t)b * NPIX * C_;
    size_t ob = (size_t)b * NPIX * CI_;
    int row0 = blockIdx.x * 64 + wid * 16;
    f32x4 acc[8] = {};
    for (int kk = 0; kk < C_; kk += 32) {
        Frag3 a = split8_3(Ab + (size_t)(row0 + l16) * C_ + kk + quad * 8);
#pragma unroll
        for (int cc = 0; cc < 8; cc++) {
            Frag3 w = split8_3(W + (size_t)(cc * 16 + l16) * C_ + kk + quad * 8);
            acc[cc] = mm6(a, w, acc[cc]);
        }
    }
#pragma unroll
    for (int cc = 0; cc < 8; cc++) {
        int c = cc * 16 + l16;
        float bv = bias[c];
#pragma unroll
        for (int r = 0; r < 4; r++) {
            float v = acc[cc][r] + bv;
            unsigned uh = __float_as_uint(v) & 0xffff0000u;
            float r1 = v - __uint_as_float(uh);
            unsigned um = __float_as_uint(r1) & 0xffff0000u;
            float r2 = r1 - __uint_as_float(um);
            size_t o = ob + (size_t)(row0 + quad * 4 + r) * CI_ + c;
            oh[o] = (short)(uh >> 16);
            om[o] = (short)(um >> 16);
            ol[o] = f2bf(r2);
        }
    }
}

// ---- phi conv: 6-term MFMA, fp32 out (split happens after pooling) ----
__global__ __launch_bounds__(256) void k_conv6f(const float* __restrict__ A,
        const float* __restrict__ W, const float* __restrict__ bias,
        float* __restrict__ outf) {
    int wid = threadIdx.x >> 6, lane = threadIdx.x & 63;
    int quad = lane >> 4, l16 = lane & 15;
    int b = blockIdx.y;
    const float* Ab = A + (size_t)b * NPIX * C_;
    float* Ob = outf + (size_t)b * NPIX * CI_;
    int row0 = blockIdx.x * 64 + wid * 16;
    f32x4 acc[8] = {};
    for (int kk = 0; kk < C_; kk += 32) {
        Frag3 a = split8_3(Ab + (size_t)(row0 + l16) * C_ + kk + quad * 8);
#pragma unroll
        for (int cc = 0; cc < 8; cc++) {
            Frag3 w = split8_3(W + (size_t)(cc * 16 + l16) * C_ + kk + quad * 8);
            acc[cc] = mm6(a, w, acc[cc]);
        }
    }
#pragma unroll
    for (int cc = 0; cc < 8; cc++) {
        int c = cc * 16 + l16;
        float bv = bias[c];
#pragma unroll
        for (int r = 0; r < 4; r++)
            Ob[(size_t)(row0 + quad * 4 + r) * CI_ + c] = acc[cc][r] + bv;
    }
}

// ---- g conv: 3-term (2-plane), bf16 out ----
__global__ __launch_bounds__(256) void k_convg(const float* __restrict__ A,
        const float* __restrict__ W, const float* __restrict__ bias,
        short* __restrict__ out) {
    int wid = threadIdx.x >> 6, lane = threadIdx.x & 63;
    int quad = lane >> 4, l16 = lane & 15;
    int b = blockIdx.y;
    const float* Ab = A + (size_t)b * NPIX * C_;
    short* Ob = out + (size_t)b * NPIX * CI_;
    int row0 = blockIdx.x * 64 + wid * 16;
    f32x4 acc[8] = {};
    for (int kk = 0; kk < C_; kk += 32) {
        Frag2 a = split8_2(Ab + (size_t)(row0 + l16) * C_ + kk + quad * 8);
#pragma unroll
        for (int cc = 0; cc < 8; cc++) {
            Frag2 w = split8_2(W + (size_t)(cc * 16 + l16) * C_ + kk + quad * 8);
            acc[cc] = mm3(a, w, acc[cc]);
        }
    }
#pragma unroll
    for (int cc = 0; cc < 8; cc++) {
        int c = cc * 16 + l16;
        float bv = bias[c];
#pragma unroll
        for (int r = 0; r < 4; r++)
            Ob[(size_t)(row0 + quad * 4 + r) * CI_ + c] = f2bf(acc[cc][r] + bv);
    }
}

// ---- pool (1,2,2): pfull fp32 -> phit 3-plane; gfull bf16 -> g_c (128,Ns) ----
__global__ void k_pool3(const float* __restrict__ pfull, const short* __restrict__ gfull,
                        short* __restrict__ pth, short* __restrict__ ptm,
                        short* __restrict__ ptl, short* __restrict__ g_c) {
    int b = blockIdx.y;
    int idx = blockIdx.x * 256 + threadIdx.x;       // idx = m*128 + ci
    int ci = idx & 127, m = idx >> 7;
    int t = m / 196, r2i = m - t * 196;
    int h2 = r2i / 14, w2 = r2i - h2 * 14;
    size_t p = (size_t)t * 784 + (size_t)(2 * h2) * 28 + 2 * w2;
    size_t i0 = (size_t)b * NPIX * CI_ + p * CI_ + ci;
    float pv = fmaxf(fmaxf(pfull[i0], pfull[i0 + CI_]),
                     fmaxf(pfull[i0 + 28 * CI_], pfull[i0 + 29 * CI_]));
    unsigned uh = __float_as_uint(pv) & 0xffff0000u;
    float r1 = pv - __uint_as_float(uh);
    unsigned um = __float_as_uint(r1) & 0xffff0000u;
    float r2 = r1 - __uint_as_float(um);
    size_t ob = (size_t)b * NS * CI_;
    pth[ob + idx] = (short)(uh >> 16);
    ptm[ob + idx] = (short)(um >> 16);
    ptl[ob + idx] = f2bf(r2);
    float g0 = fmaxf(fmaxf(bf2f(gfull[i0]), bf2f(gfull[i0 + CI_])),
                     fmaxf(bf2f(gfull[i0 + 28 * CI_]), bf2f(gfull[i0 + 29 * CI_])));
    g_c[ob + (size_t)ci * NS + m] = f2bf(g0);
}

// ---- softmax column stats (6-term f); wave -> 16 m-cols ----
__global__ __launch_bounds__(256) void k_stats6(
        const short* __restrict__ thh, const short* __restrict__ thm, const short* __restrict__ thl,
        const short* __restrict__ phh, const short* __restrict__ phm, const short* __restrict__ phl,
        float* __restrict__ Mpart, float* __restrict__ Spart) {
    int wid = threadIdx.x >> 6, lane = threadIdx.x & 63;
    int quad = lane >> 4, l16 = lane & 15;
    int b = blockIdx.z;
    int m0 = blockIdx.x * 64 + wid * 16;
    size_t tb = (size_t)b * NPIX * CI_, pb = (size_t)b * NS * CI_;
    Frag3 bf[4];
#pragma unroll
    for (int kk = 0; kk < 4; kk++)
        bf[kk] = ld3(phh, phm, phl, pb + (size_t)(m0 + l16) * CI_ + kk * 32 + quad * 8);
    float Mx = -1e30f, S = 0.f;
    int n_beg = blockIdx.y * (NPIX / SLICES), n_end = n_beg + NPIX / SLICES;
    for (int n = n_beg; n < n_end; n += 16) {
        f32x4 acc = {};
#pragma unroll
        for (int kk = 0; kk < 4; kk++) {
            Frag3 a = ld3(thh, thm, thl, tb + (size_t)(n + l16) * CI_ + kk * 32 + quad * 8);
            acc = mm6(a, bf[kk], acc);
        }
        float tm = fmaxf(fmaxf(acc[0], acc[1]), fmaxf(acc[2], acc[3]));
        tm = fmaxf(tm, __shfl_xor(tm, 16, 64));
        tm = fmaxf(tm, __shfl_xor(tm, 32, 64));
        float nM = fmaxf(Mx, tm);
        float ps = __expf(acc[0] - nM) + __expf(acc[1] - nM) +
                   __expf(acc[2] - nM) + __expf(acc[3] - nM);
        ps += __shfl_xor(ps, 16, 64);
        ps += __shfl_xor(ps, 32, 64);
        S = S * __expf(Mx - nM) + ps;
        Mx = nM;
    }
    if (quad == 0) {
        size_t o = ((size_t)(b * SLICES + blockIdx.y)) * NS + m0 + l16;
        Mpart[o] = Mx;
        Spart[o] = S;
    }
}

__global__ void k_combine(const float* __restrict__ Mpart, const float* __restrict__ Spart,
                          float* __restrict__ Mg, float* __restrict__ iS) {
    int i = blockIdx.x * 256 + threadIdx.x;
    if (i >= B_ * NS) return;
    int b = i / NS, m = i - b * NS;
    float gm = -1e30f;
#pragma unroll
    for (int s = 0; s < SLICES; s++)
        gm = fmaxf(gm, Mpart[((size_t)(b * SLICES + s)) * NS + m]);
    float sum = 0.f;
#pragma unroll
    for (int s = 0; s < SLICES; s++) {
        size_t o = ((size_t)(b * SLICES + s)) * NS + m;
        sum += Spart[o] * __expf(Mpart[o] - gm);
    }
    Mg[i] = gm;
    iS[i] = 1.f / sum;
}

// ---- PV: recompute f (6-term, same order), p bf16 via LDS, y 2-plane out ----
__global__ __launch_bounds__(256) void k_pv6(
        const short* __restrict__ thh, const short* __restrict__ thm, const short* __restrict__ thl,
        const short* __restrict__ phh, const short* __restrict__ phm, const short* __restrict__ phl,
        const short* __restrict__ gmat, const float* __restrict__ Mg,
        const float* __restrict__ iS, short* __restrict__ yh, short* __restrict__ ym) {
    __shared__ __align__(16) short ptile[4][16 * 40];
    int wid = threadIdx.x >> 6, lane = threadIdx.x & 63;
    int quad = lane >> 4, l16 = lane & 15;
    int b = blockIdx.y;
    int n0 = blockIdx.x * 64 + wid * 16;
    size_t tb = (size_t)b * NPIX * CI_, pb = (size_t)b * NS * CI_;
    const short* gc = gmat + (size_t)b * CI_ * NS;
    const float* Mb = Mg + (size_t)b * NS;
    const float* sb = iS + (size_t)b * NS;
    Frag3 af[4];
#pragma unroll
    for (int kk = 0; kk < 4; kk++)
        af[kk] = ld3(thh, thm, thl, tb + (size_t)(n0 + l16) * CI_ + kk * 32 + quad * 8);
    f32x4 yacc[8] = {};
    short* myp = &ptile[wid][0];
    for (int m0 = 0; m0 < NS; m0 += 32) {
#pragma unroll
        for (int h = 0; h < 32; h += 16) {
            f32x4 f0 = {};
#pragma unroll
            for (int kk = 0; kk < 4; kk++) {
                Frag3 bfr = ld3(phh, phm, phl,
                                pb + (size_t)(m0 + h + l16) * CI_ + kk * 32 + quad * 8);
                f0 = mm6(af[kk], bfr, f0);
            }
            float M0 = Mb[m0 + h + l16], s0 = sb[m0 + h + l16];
#pragma unroll
            for (int r = 0; r < 4; r++)
                myp[(quad * 4 + r) * 40 + h + l16] = f2bf(__expf(f0[r] - M0) * s0);
        }
        __syncthreads();
        bf16x8 pa = *(const bf16x8*)(myp + l16 * 40 + quad * 8);
#pragma unroll
        for (int cc = 0; cc < 8; cc++) {
            bf16x8 gb = *(const bf16x8*)(gc + (size_t)(cc * 16 + l16) * NS + m0 + quad * 8);
            yacc[cc] = mfma16(pa, gb, yacc[cc]);
        }
    }
    short* yhb = yh + tb;
    short* ymb = ym + tb;
#pragma unroll
    for (int cc = 0; cc < 8; cc++)
#pragma unroll
        for (int r = 0; r < 4; r++) {
            float v = yacc[cc][r];
            unsigned uh = __float_as_uint(v) & 0xffff0000u;
            size_t o = (size_t)(n0 + quad * 4 + r) * CI_ + cc * 16 + l16;
            yhb[o] = (short)(uh >> 16);
            ymb[o] = f2bf(v - __uint_as_float(uh));
        }
}

// ---- W conv (3-term, 2-plane y, 2-plane W) + fused BN stats ----
__global__ __launch_bounds__(256) void k_wconv3(const short* __restrict__ yh,
        const short* __restrict__ ym, const float* __restrict__ W,
        const float* __restrict__ bias, float* __restrict__ Wy, float* __restrict__ stat) {
    int wid = threadIdx.x >> 6, lane = threadIdx.x & 63;
    int quad = lane >> 4, l16 = lane & 15;
    int b = blockIdx.z;
    size_t yb = (size_t)b * NPIX * CI_;
    float* Wyb = Wy + (size_t)b * NPIX * C_;
    int row0 = blockIdx.x * 64 + wid * 16;
    int col0 = blockIdx.y * 128;
    f32x4 acc[8] = {};
#pragma unroll
    for (int kk = 0; kk < 4; kk++) {
        size_t ao = yb + (size_t)(row0 + l16) * CI_ + kk * 32 + quad * 8;
        bf16x8 ah = *(const bf16x8*)(yh + ao);
        bf16x8 am = *(const bf16x8*)(ym + ao);
#pragma unroll
        for (int cc = 0; cc < 8; cc++) {
            Frag2 w = split8_2(W + (size_t)(col0 + cc * 16 + l16) * CI_ + kk * 32 + quad * 8);
            acc[cc] = mfma16(am, w.h, acc[cc]);
            acc[cc] = mfma16(ah, w.m, acc[cc]);
            acc[cc] = mfma16(ah, w.h, acc[cc]);
        }
    }
#pragma unroll
    for (int cc = 0; cc < 8; cc++) {
        int c = col0 + cc * 16 + l16;
        float bv = bias[c];
        float s1 = 0.f, s2 = 0.f;
#pragma unroll
        for (int r = 0; r < 4; r++) {
            float v = acc[cc][r] + bv;
            Wyb[(size_t)(row0 + quad * 4 + r) * C_ + c] = v;
            s1 += v;
            s2 += v * v;
        }
        s1 += __shfl_xor(s1, 16, 64); s1 += __shfl_xor(s1, 32, 64);
        s2 += __shfl_xor(s2, 16, 64); s2 += __shfl_xor(s2, 32, 64);
        if (quad == 0) {
            atomicAdd(&stat[c], s1);
            atomicAdd(&stat[C_ + c], s2);
        }
    }
}

__global__ void k_bnfin(const float* __restrict__ stat, const float* __restrict__ gamma,
                        const float* __restrict__ beta, float* __restrict__ sc,
                        float* __restrict__ sh) {
    int c = threadIdx.x;
    const float inv = 1.f / (float)(B_ * NPIX);
    float mean = stat[c] * inv;
    float var = stat[C_ + c] * inv - mean * mean;
    float s = gamma[c] * rsqrtf(var + 1e-5f);
    sc[c] = s;
    sh[c] = beta[c] - mean * s;
}

__global__ void k_final(const float* __restrict__ Wy, const float* __restrict__ x,
                        const float* __restrict__ sc, const float* __restrict__ sh,
                        float* __restrict__ out) {
    __shared__ float tile[32][33];
    int b = blockIdx.z;
    const float* Wyb = Wy + (size_t)b * NPIX * C_;
    const float* xb = x + (size_t)b * C_ * NPIX;
    float* ob = out + (size_t)b * C_ * NPIX;
    int p0 = blockIdx.x * 32, c0 = blockIdx.y * 32;
    for (int i = threadIdx.y; i < 32; i += 8)
        tile[i][threadIdx.x] = Wyb[(size_t)(p0 + i) * C_ + c0 + threadIdx.x];
    __syncthreads();
    for (int i = threadIdx.y; i < 32; i += 8) {
        int c = c0 + i;
        size_t o = (size_t)c * NPIX + p0 + threadIdx.x;
        ob[o] = tile[threadIdx.x][i] * sc[c] + sh[c] + xb[o];
    }
}

extern "C" void kernel_launch(void* const* d_in, const int* in_sizes, int n_in,
                              void* d_out, int out_size, void* d_ws, size_t ws_size,
                              hipStream_t stream) {
    (void)in_sizes; (void)n_in; (void)out_size; (void)ws_size;
    const float* x     = (const float*)d_in[0];
    const float* mask  = (const float*)d_in[1];
    const float* g_w   = (const float*)d_in[2];
    const float* g_b   = (const float*)d_in[3];
    const float* th_w  = (const float*)d_in[4];
    const float* th_b  = (const float*)d_in[5];
    const float* ph_w  = (const float*)d_in[6];
    const float* ph_b  = (const float*)d_in[7];
    const float* W_w   = (const float*)d_in[8];
    const float* W_b   = (const float*)d_in[9];
    const float* gamma = (const float*)d_in[10];
    const float* beta  = (const float*)d_in[11];
    float* out = (float*)d_out;

    char* ws = (char*)d_ws;
    float* xt    = (float*)(ws + 0);              // 25,690,112 (mask-t, then x-t, then Wy)
    float* Wy    = (float*)(ws + 0);              // alias (after g conv done)
    short* thH   = (short*)(ws + 25690112);       // 6,422,528
    short* thM   = (short*)(ws + 32112640);       // 6,422,528
    short* thL   = (short*)(ws + 38535168);       // 6,422,528
    float* pfull = (float*)(ws + 44957696);       // 12,845,056 fp32 phi (pre-pool)
    short* yH    = (short*)(ws + 44957696);       // alias after pool
    short* yM    = (short*)(ws + 51380224);       // alias after pool
    short* gfull = (short*)(ws + 57802752);       // 6,422,528
    short* ptH   = (short*)(ws + 64225280);       // 1,605,632
    short* ptM   = (short*)(ws + 65830912);       // 1,605,632
    short* ptL   = (short*)(ws + 67436544);       // 1,605,632
    short* gc    = (short*)(ws + 69042176);       // 1,605,632
    float* Mpart = (float*)(ws + 70647808);       // 200,704
    float* Spart = (float*)(ws + 70848512);       // 200,704
    float* Mg    = (float*)(ws + 71049216);       // 25,088
    float* iSg   = (float*)(ws + 71074304);       // 25,088
    float* stat  = (float*)(ws + 71099392);       // 2,048
    float* sc    = (float*)(ws + 71101440);       // 1,024
    float* sh    = (float*)(ws + 71102464);       // 1,024

    hipMemsetAsync(stat, 0, 2048, stream);

    dim3 tb32(32, 8);
    k_transpose<<<dim3(NPIX / 32, C_ / 32, B_), tb32, 0, stream>>>(mask, xt);
    k_conv6p<<<dim3(NPIX / 64, B_), 256, 0, stream>>>(xt, th_w, th_b, thH, thM, thL);

    k_transpose<<<dim3(NPIX / 32, C_ / 32, B_), tb32, 0, stream>>>(x, xt);
    k_conv6f<<<dim3(NPIX / 64, B_), 256, 0, stream>>>(xt, ph_w, ph_b, pfull);
    k_convg<<<dim3(NPIX / 64, B_), 256, 0, stream>>>(xt, g_w, g_b, gfull);

    k_pool3<<<dim3(NS * CI_ / 256, B_), 256, 0, stream>>>(pfull, gfull, ptH, ptM, ptL, gc);

    k_stats6<<<dim3(NS / 64, SLICES, B_), 256, 0, stream>>>(thH, thM, thL, ptH, ptM, ptL,
                                                            Mpart, Spart);
    k_combine<<<(B_ * NS + 255) / 256, 256, 0, stream>>>(Mpart, Spart, Mg, iSg);

    k_pv6<<<dim3(NPIX / 64, B_), 256, 0, stream>>>(thH, thM, thL, ptH, ptM, ptL, gc,
                                                   Mg, iSg, yH, yM);

    k_wconv3<<<dim3(NPIX / 64, C_ / 128, B_), 256, 0, stream>>>(yH, yM, W_w, W_b, Wy, stat);
    k_bnfin<<<1, 256, 0, stream>>>(stat, gamma, beta, sc, sh);
    k_final<<<dim3(NPIX / 32, C_ / 32, B_), tb32, 0, stream>>>(Wy, x, sc, sh, out);
}

// Round 4
// 1175.243 us; speedup vs baseline: 1.3403x; 1.3403x over previous
//
#include <hip/hip_runtime.h>

// pSGM non-local block, MI355X (round 4: latency-bound fixes).
// r3 passed (absmax 1.0/2.86, 1575us; k_pv 753us @ MfmaUtil 7.5%, Occ 16.6%).
// Changes: (1) k_pv m-sliced x2 (fp32 partials in dead xt region + combine),
// block=64 => 12.2 waves/CU; (2) dual independent MFMA chains (ILP 2x) in pv
// and stats; (3) f at 4-term (h,m planes; df~2.4e-4, out err +0.02 per the
// measured err=100*df model); convs keep exact 6-term; weights pre-split once.

#define B_ 2
#define C_ 256
#define CI_ 128
#define NPIX 12544
#define NS 3136
#define SLICES 8
#define NSLICE 2

typedef short bf16x8 __attribute__((ext_vector_type(8)));
typedef float f32x4 __attribute__((ext_vector_type(4)));
typedef float f32x8 __attribute__((ext_vector_type(8)));

__device__ __forceinline__ short f2bf(float f) {
    unsigned u = __float_as_uint(f);
    u = (u + 0x7fff + ((u >> 16) & 1)) >> 16;   // RNE
    return (short)u;
}
__device__ __forceinline__ float bf2f(short s) {
    return __uint_as_float(((unsigned)(unsigned short)s) << 16);
}
__device__ __forceinline__ f32x4 mfma16(bf16x8 a, bf16x8 b, f32x4 c) {
    return __builtin_amdgcn_mfma_f32_16x16x32_bf16(a, b, c, 0, 0, 0);
}

struct Frag3 { bf16x8 h, m, l; };
struct Frag2 { bf16x8 h, m; };

__device__ __forceinline__ Frag3 split8_3(const float* __restrict__ p) {
    Frag3 f;
    f32x8 v = *(const f32x8*)p;
#pragma unroll
    for (int j = 0; j < 8; j++) {
        float x = v[j];
        unsigned uh = __float_as_uint(x) & 0xffff0000u;
        float r1 = x - __uint_as_float(uh);
        unsigned um = __float_as_uint(r1) & 0xffff0000u;
        float r2 = r1 - __uint_as_float(um);
        f.h[j] = (short)(uh >> 16);
        f.m[j] = (short)(um >> 16);
        f.l[j] = f2bf(r2);
    }
    return f;
}
__device__ __forceinline__ Frag3 ld3(const short* __restrict__ h, const short* __restrict__ m,
                                     const short* __restrict__ l, size_t off) {
    Frag3 f;
    f.h = *(const bf16x8*)(h + off);
    f.m = *(const bf16x8*)(m + off);
    f.l = *(const bf16x8*)(l + off);
    return f;
}
__device__ __forceinline__ Frag2 ld2(const short* __restrict__ h, const short* __restrict__ m,
                                     size_t off) {
    Frag2 f;
    f.h = *(const bf16x8*)(h + off);
    f.m = *(const bf16x8*)(m + off);
    return f;
}
__device__ __forceinline__ f32x4 mm6(Frag3 a, Frag3 b, f32x4 acc) {
    acc = mfma16(a.h, b.l, acc);
    acc = mfma16(a.l, b.h, acc);
    acc = mfma16(a.m, b.m, acc);
    acc = mfma16(a.m, b.h, acc);
    acc = mfma16(a.h, b.m, acc);
    acc = mfma16(a.h, b.h, acc);
    return acc;
}
// 4-term f product (same helper used by stats and pv)
__device__ __forceinline__ f32x4 mm4(Frag2 a, Frag2 b, f32x4 acc) {
    acc = mfma16(a.m, b.m, acc);
    acc = mfma16(a.m, b.h, acc);
    acc = mfma16(a.h, b.m, acc);
    acc = mfma16(a.h, b.h, acc);
    return acc;
}

// ---- weight pre-split kernels ----
__global__ void k_split3(const float* __restrict__ a, short* __restrict__ oh,
                         short* __restrict__ om, short* __restrict__ ol, int n) {
    int i = blockIdx.x * 256 + threadIdx.x;
    if (i >= n) return;
    float x = a[i];
    unsigned uh = __float_as_uint(x) & 0xffff0000u;
    float r1 = x - __uint_as_float(uh);
    unsigned um = __float_as_uint(r1) & 0xffff0000u;
    float r2 = r1 - __uint_as_float(um);
    oh[i] = (short)(uh >> 16);
    om[i] = (short)(um >> 16);
    ol[i] = f2bf(r2);
}
__global__ void k_split2(const float* __restrict__ a, short* __restrict__ oh,
                         short* __restrict__ om, int n) {
    int i = blockIdx.x * 256 + threadIdx.x;
    if (i >= n) return;
    float x = a[i];
    unsigned uh = __float_as_uint(x) & 0xffff0000u;
    oh[i] = (short)(uh >> 16);
    om[i] = f2bf(x - __uint_as_float(uh));
}

// ---- transpose: (C_,NPIX) fp32 -> (NPIX,C_) fp32 ----
__global__ void k_transpose(const float* __restrict__ src, float* __restrict__ dst) {
    __shared__ float tile[32][33];
    int b = blockIdx.z;
    const float* s = src + (size_t)b * C_ * NPIX;
    float* d = dst + (size_t)b * NPIX * C_;
    int p0 = blockIdx.x * 32, c0 = blockIdx.y * 32;
    for (int i = threadIdx.y; i < 32; i += 8)
        tile[i][threadIdx.x] = s[(size_t)(c0 + i) * NPIX + p0 + threadIdx.x];
    __syncthreads();
    for (int i = threadIdx.y; i < 32; i += 8)
        d[(size_t)(p0 + i) * C_ + c0 + threadIdx.x] = tile[threadIdx.x][i];
}

// ---- theta conv: 6-term exact, pre-split W planes, 2-plane output ----
__global__ __launch_bounds__(256) void k_conv6p(const float* __restrict__ A,
        const short* __restrict__ WH, const short* __restrict__ WM, const short* __restrict__ WL,
        const float* __restrict__ bias, short* __restrict__ oh, short* __restrict__ om) {
    int wid = threadIdx.x >> 6, lane = threadIdx.x & 63;
    int quad = lane >> 4, l16 = lane & 15;
    int b = blockIdx.y;
    const float* Ab = A + (size_t)b * NPIX * C_;
    size_t ob = (size_t)b * NPIX * CI_;
    int row0 = blockIdx.x * 64 + wid * 16;
    f32x4 acc[8] = {};
    for (int kk = 0; kk < C_; kk += 32) {
        Frag3 a = split8_3(Ab + (size_t)(row0 + l16) * C_ + kk + quad * 8);
#pragma unroll
        for (int cc = 0; cc < 8; cc++) {
            Frag3 w = ld3(WH, WM, WL, (size_t)(cc * 16 + l16) * C_ + kk + quad * 8);
            acc[cc] = mm6(a, w, acc[cc]);
        }
    }
#pragma unroll
    for (int cc = 0; cc < 8; cc++) {
        int c = cc * 16 + l16;
        float bv = bias[c];
#pragma unroll
        for (int r = 0; r < 4; r++) {
            float v = acc[cc][r] + bv;
            unsigned uh = __float_as_uint(v) & 0xffff0000u;
            size_t o = ob + (size_t)(row0 + quad * 4 + r) * CI_ + c;
            oh[o] = (short)(uh >> 16);
            om[o] = f2bf(v - __uint_as_float(uh));
        }
    }
}

// ---- fused phi(6-term exact -> fp32) + g(3-term -> bf16) conv, shared A split ----
__global__ __launch_bounds__(256) void k_convxg(const float* __restrict__ A,
        const short* __restrict__ PH, const short* __restrict__ PM, const short* __restrict__ PL,
        const short* __restrict__ GH, const short* __restrict__ GM,
        const float* __restrict__ pbias, const float* __restrict__ gbias,
        float* __restrict__ pfull, short* __restrict__ gout) {
    int wid = threadIdx.x >> 6, lane = threadIdx.x & 63;
    int quad = lane >> 4, l16 = lane & 15;
    int b = blockIdx.y;
    const float* Ab = A + (size_t)b * NPIX * C_;
    float* Pb = pfull + (size_t)b * NPIX * CI_;
    short* Gb = gout + (size_t)b * NPIX * CI_;
    int row0 = blockIdx.x * 64 + wid * 16;
    f32x4 accp[8] = {}, accg[8] = {};
    for (int kk = 0; kk < C_; kk += 32) {
        Frag3 a = split8_3(Ab + (size_t)(row0 + l16) * C_ + kk + quad * 8);
        Frag2 a2; a2.h = a.h; a2.m = a.m;
#pragma unroll
        for (int cc = 0; cc < 8; cc++) {
            size_t wo = (size_t)(cc * 16 + l16) * C_ + kk + quad * 8;
            Frag3 wp = ld3(PH, PM, PL, wo);
            accp[cc] = mm6(a, wp, accp[cc]);
            Frag2 wg = ld2(GH, GM, wo);
            accg[cc] = mfma16(a2.m, wg.h, accg[cc]);
            accg[cc] = mfma16(a2.h, wg.m, accg[cc]);
            accg[cc] = mfma16(a2.h, wg.h, accg[cc]);
        }
    }
#pragma unroll
    for (int cc = 0; cc < 8; cc++) {
        int c = cc * 16 + l16;
        float pbv = pbias[c], gbv = gbias[c];
#pragma unroll
        for (int r = 0; r < 4; r++) {
            size_t o = (size_t)(row0 + quad * 4 + r) * CI_ + c;
            Pb[o] = accp[cc][r] + pbv;
            Gb[o] = f2bf(accg[cc][r] + gbv);
        }
    }
}

// ---- pool (1,2,2): pfull fp32 -> phit 2-plane; gfull bf16 -> g_c (128,Ns) ----
__global__ void k_pool(const float* __restrict__ pfull, const short* __restrict__ gfull,
                       short* __restrict__ pth, short* __restrict__ ptm,
                       short* __restrict__ g_c) {
    int b = blockIdx.y;
    int idx = blockIdx.x * 256 + threadIdx.x;       // idx = m*128 + ci
    int ci = idx & 127, m = idx >> 7;
    int t = m / 196, r2i = m - t * 196;
    int h2 = r2i / 14, w2 = r2i - h2 * 14;
    size_t p = (size_t)t * 784 + (size_t)(2 * h2) * 28 + 2 * w2;
    size_t i0 = (size_t)b * NPIX * CI_ + p * CI_ + ci;
    float pv = fmaxf(fmaxf(pfull[i0], pfull[i0 + CI_]),
                     fmaxf(pfull[i0 + 28 * CI_], pfull[i0 + 29 * CI_]));
    unsigned uh = __float_as_uint(pv) & 0xffff0000u;
    size_t ob = (size_t)b * NS * CI_;
    pth[ob + idx] = (short)(uh >> 16);
    ptm[ob + idx] = f2bf(pv - __uint_as_float(uh));
    float g0 = fmaxf(fmaxf(bf2f(gfull[i0]), bf2f(gfull[i0 + CI_])),
                     fmaxf(bf2f(gfull[i0 + 28 * CI_]), bf2f(gfull[i0 + 29 * CI_])));
    g_c[ob + (size_t)ci * NS + m] = f2bf(g0);
}

// ---- softmax column stats: 4-term f, dual-n ILP; wave -> 16 m-cols ----
__global__ __launch_bounds__(256) void k_stats4(
        const short* __restrict__ thh, const short* __restrict__ thm,
        const short* __restrict__ phh, const short* __restrict__ phm,
        float* __restrict__ Mpart, float* __restrict__ Spart) {
    int wid = threadIdx.x >> 6, lane = threadIdx.x & 63;
    int quad = lane >> 4, l16 = lane & 15;
    int b = blockIdx.z;
    int m0 = blockIdx.x * 64 + wid * 16;
    size_t tb = (size_t)b * NPIX * CI_, pb = (size_t)b * NS * CI_;
    Frag2 bf[4];
#pragma unroll
    for (int kk = 0; kk < 4; kk++)
        bf[kk] = ld2(phh, phm, pb + (size_t)(m0 + l16) * CI_ + kk * 32 + quad * 8);
    float Mx = -1e30f, S = 0.f;
    int n_beg = blockIdx.y * (NPIX / SLICES), n_end = n_beg + NPIX / SLICES;
    for (int n = n_beg; n < n_end; n += 32) {
        f32x4 a0 = {}, a1 = {};
#pragma unroll
        for (int kk = 0; kk < 4; kk++) {
            Frag2 x0 = ld2(thh, thm, tb + (size_t)(n + l16) * CI_ + kk * 32 + quad * 8);
            Frag2 x1 = ld2(thh, thm, tb + (size_t)(n + 16 + l16) * CI_ + kk * 32 + quad * 8);
            a0 = mm4(x0, bf[kk], a0);
            a1 = mm4(x1, bf[kk], a1);
        }
        float tm0 = fmaxf(fmaxf(a0[0], a0[1]), fmaxf(a0[2], a0[3]));
        float tm1 = fmaxf(fmaxf(a1[0], a1[1]), fmaxf(a1[2], a1[3]));
        float tm = fmaxf(tm0, tm1);
        tm = fmaxf(tm, __shfl_xor(tm, 16, 64));
        tm = fmaxf(tm, __shfl_xor(tm, 32, 64));
        float nM = fmaxf(Mx, tm);
        float ps = __expf(a0[0] - nM) + __expf(a0[1] - nM) +
                   __expf(a0[2] - nM) + __expf(a0[3] - nM) +
                   __expf(a1[0] - nM) + __expf(a1[1] - nM) +
                   __expf(a1[2] - nM) + __expf(a1[3] - nM);
        ps += __shfl_xor(ps, 16, 64);
        ps += __shfl_xor(ps, 32, 64);
        S = S * __expf(Mx - nM) + ps;
        Mx = nM;
    }
    if (quad == 0) {
        size_t o = ((size_t)(b * SLICES + blockIdx.y)) * NS + m0 + l16;
        Mpart[o] = Mx;
        Spart[o] = S;
    }
}

__global__ void k_combine(const float* __restrict__ Mpart, const float* __restrict__ Spart,
                          float* __restrict__ Mg, float* __restrict__ iS) {
    int i = blockIdx.x * 256 + threadIdx.x;
    if (i >= B_ * NS) return;
    int b = i / NS, m = i - b * NS;
    float gm = -1e30f;
#pragma unroll
    for (int s = 0; s < SLICES; s++)
        gm = fmaxf(gm, Mpart[((size_t)(b * SLICES + s)) * NS + m]);
    float sum = 0.f;
#pragma unroll
    for (int s = 0; s < SLICES; s++) {
        size_t o = ((size_t)(b * SLICES + s)) * NS + m;
        sum += Spart[o] * __expf(Mpart[o] - gm);
    }
    Mg[i] = gm;
    iS[i] = 1.f / sum;
}

// ---- PV: 4-term f recompute, dual f0/f1 chains, m-sliced, 1 wave/block ----
// grid (NPIX/16, NSLICE, B_), block 64. part[slice][b][n][ci] fp32.
__global__ __launch_bounds__(64) void k_pv4(
        const short* __restrict__ thh, const short* __restrict__ thm,
        const short* __restrict__ phh, const short* __restrict__ phm,
        const short* __restrict__ gmat, const float* __restrict__ Mg,
        const float* __restrict__ iS, float* __restrict__ part) {
    __shared__ __align__(16) short ptile[16 * 40];
    int lane = threadIdx.x;
    int quad = lane >> 4, l16 = lane & 15;
    int b = blockIdx.z, slice = blockIdx.y;
    int n0 = blockIdx.x * 16;
    size_t tb = (size_t)b * NPIX * CI_, pb = (size_t)b * NS * CI_;
    const short* gc = gmat + (size_t)b * CI_ * NS;
    const float* Mb = Mg + (size_t)b * NS;
    const float* sb = iS + (size_t)b * NS;
    Frag2 af[4];
#pragma unroll
    for (int kk = 0; kk < 4; kk++)
        af[kk] = ld2(thh, thm, tb + (size_t)(n0 + l16) * CI_ + kk * 32 + quad * 8);
    f32x4 yacc[8] = {};
    int m_beg = slice * (NS / NSLICE), m_end = m_beg + NS / NSLICE;
    for (int m0 = m_beg; m0 < m_end; m0 += 32) {
        f32x4 f0 = {}, f1 = {};
#pragma unroll
        for (int kk = 0; kk < 4; kk++) {
            Frag2 b0 = ld2(phh, phm, pb + (size_t)(m0 + l16) * CI_ + kk * 32 + quad * 8);
            Frag2 b1 = ld2(phh, phm, pb + (size_t)(m0 + 16 + l16) * CI_ + kk * 32 + quad * 8);
            f0 = mm4(af[kk], b0, f0);
            f1 = mm4(af[kk], b1, f1);
        }
        float M0 = Mb[m0 + l16], M1 = Mb[m0 + 16 + l16];
        float s0 = sb[m0 + l16], s1 = sb[m0 + 16 + l16];
#pragma unroll
        for (int r = 0; r < 4; r++) {
            ptile[(quad * 4 + r) * 40 + l16]      = f2bf(__expf(f0[r] - M0) * s0);
            ptile[(quad * 4 + r) * 40 + 16 + l16] = f2bf(__expf(f1[r] - M1) * s1);
        }
        __syncthreads();    // single-wave barrier: orders LDS write->read
        bf16x8 pa = *(const bf16x8*)(ptile + l16 * 40 + quad * 8);
#pragma unroll
        for (int cc = 0; cc < 8; cc++) {
            bf16x8 gb = *(const bf16x8*)(gc + (size_t)(cc * 16 + l16) * NS + m0 + quad * 8);
            yacc[cc] = mfma16(pa, gb, yacc[cc]);
        }
        __syncthreads();
    }
    float* po = part + (((size_t)(slice * B_ + b)) * NPIX) * CI_;
#pragma unroll
    for (int cc = 0; cc < 8; cc++)
#pragma unroll
        for (int r = 0; r < 4; r++)
            po[(size_t)(n0 + quad * 4 + r) * CI_ + cc * 16 + l16] = yacc[cc][r];
}

// ---- combine partial y (2 slices) -> 2-plane bf16 ----
__global__ void k_ycombine(const float* __restrict__ part, short* __restrict__ yh,
                           short* __restrict__ ym) {
    size_t i = (size_t)blockIdx.x * 256 + threadIdx.x;
    const size_t n = (size_t)B_ * NPIX * CI_;
    if (i >= n) return;
    float v = part[i] + part[n + i];
    unsigned uh = __float_as_uint(v) & 0xffff0000u;
    yh[i] = (short)(uh >> 16);
    ym[i] = f2bf(v - __uint_as_float(uh));
}

// ---- W conv (3-term, 2-plane y x pre-split 2-plane W) + fused BN stats ----
__global__ __launch_bounds__(256) void k_wconv3(const short* __restrict__ yh,
        const short* __restrict__ ym, const short* __restrict__ WH,
        const short* __restrict__ WM, const float* __restrict__ bias,
        float* __restrict__ Wy, float* __restrict__ stat) {
    int wid = threadIdx.x >> 6, lane = threadIdx.x & 63;
    int quad = lane >> 4, l16 = lane & 15;
    int b = blockIdx.z;
    size_t yb = (size_t)b * NPIX * CI_;
    float* Wyb = Wy + (size_t)b * NPIX * C_;
    int row0 = blockIdx.x * 64 + wid * 16;
    int col0 = blockIdx.y * 128;
    f32x4 acc[8] = {};
#pragma unroll
    for (int kk = 0; kk < 4; kk++) {
        size_t ao = yb + (size_t)(row0 + l16) * CI_ + kk * 32 + quad * 8;
        bf16x8 ah = *(const bf16x8*)(yh + ao);
        bf16x8 am = *(const bf16x8*)(ym + ao);
#pragma unroll
        for (int cc = 0; cc < 8; cc++) {
            Frag2 w = ld2(WH, WM, (size_t)(col0 + cc * 16 + l16) * CI_ + kk * 32 + quad * 8);
            acc[cc] = mfma16(am, w.h, acc[cc]);
            acc[cc] = mfma16(ah, w.m, acc[cc]);
            acc[cc] = mfma16(ah, w.h, acc[cc]);
        }
    }
#pragma unroll
    for (int cc = 0; cc < 8; cc++) {
        int c = col0 + cc * 16 + l16;
        float bv = bias[c];
        float s1 = 0.f, s2 = 0.f;
#pragma unroll
        for (int r = 0; r < 4; r++) {
            float v = acc[cc][r] + bv;
            Wyb[(size_t)(row0 + quad * 4 + r) * C_ + c] = v;
            s1 += v;
            s2 += v * v;
        }
        s1 += __shfl_xor(s1, 16, 64); s1 += __shfl_xor(s1, 32, 64);
        s2 += __shfl_xor(s2, 16, 64); s2 += __shfl_xor(s2, 32, 64);
        if (quad == 0) {
            atomicAdd(&stat[c], s1);
            atomicAdd(&stat[C_ + c], s2);
        }
    }
}

__global__ void k_bnfin(const float* __restrict__ stat, const float* __restrict__ gamma,
                        const float* __restrict__ beta, float* __restrict__ sc,
                        float* __restrict__ sh) {
    int c = threadIdx.x;
    const float inv = 1.f / (float)(B_ * NPIX);
    float mean = stat[c] * inv;
    float var = stat[C_ + c] * inv - mean * mean;
    float s = gamma[c] * rsqrtf(var + 1e-5f);
    sc[c] = s;
    sh[c] = beta[c] - mean * s;
}

__global__ void k_final(const float* __restrict__ Wy, const float* __restrict__ x,
                        const float* __restrict__ sc, const float* __restrict__ sh,
                        float* __restrict__ out) {
    __shared__ float tile[32][33];
    int b = blockIdx.z;
    const float* Wyb = Wy + (size_t)b * NPIX * C_;
    const float* xb = x + (size_t)b * C_ * NPIX;
    float* ob = out + (size_t)b * C_ * NPIX;
    int p0 = blockIdx.x * 32, c0 = blockIdx.y * 32;
    for (int i = threadIdx.y; i < 32; i += 8)
        tile[i][threadIdx.x] = Wyb[(size_t)(p0 + i) * C_ + c0 + threadIdx.x];
    __syncthreads();
    for (int i = threadIdx.y; i < 32; i += 8) {
        int c = c0 + i;
        size_t o = (size_t)c * NPIX + p0 + threadIdx.x;
        ob[o] = tile[threadIdx.x][i] * sc[c] + sh[c] + xb[o];
    }
}

extern "C" void kernel_launch(void* const* d_in, const int* in_sizes, int n_in,
                              void* d_out, int out_size, void* d_ws, size_t ws_size,
                              hipStream_t stream) {
    (void)in_sizes; (void)n_in; (void)out_size; (void)ws_size;
    const float* x     = (const float*)d_in[0];
    const float* mask  = (const float*)d_in[1];
    const float* g_w   = (const float*)d_in[2];
    const float* g_b   = (const float*)d_in[3];
    const float* th_w  = (const float*)d_in[4];
    const float* th_b  = (const float*)d_in[5];
    const float* ph_w  = (const float*)d_in[6];
    const float* ph_b  = (const float*)d_in[7];
    const float* W_w   = (const float*)d_in[8];
    const float* W_b   = (const float*)d_in[9];
    const float* gamma = (const float*)d_in[10];
    const float* beta  = (const float*)d_in[11];
    float* out = (float*)d_out;

    char* ws = (char*)d_ws;
    // [0, 25.69MB): xt (transposes+convs) -> part (pv, 2 slices) -> Wy (wconv/final)
    float* xt    = (float*)(ws + 0);
    float* part  = (float*)(ws + 0);
    float* Wy    = (float*)(ws + 0);
    short* thH   = (short*)(ws + 25690112);       // 6,422,528
    short* wwH   = (short*)(ws + 25690112);       // alias: W split, after pv
    short* wwM   = (short*)(ws + 25755648);
    short* thM   = (short*)(ws + 32112640);       // 6,422,528
    short* thL   = (short*)(ws + 38535168);       // unused (kept for layout)
    float* pfull = (float*)(ws + 44957696);       // 12,845,056 fp32 phi (pre-pool)
    short* yH    = (short*)(ws + 44957696);       // alias after pool
    short* yM    = (short*)(ws + 51380224);       // alias after pool
    short* gfull = (short*)(ws + 57802752);       // 6,422,528
    // pt region start doubles as weight-plane scratch (dead once pool runs)
    short* thwH  = (short*)(ws + 64225280);       // 65,536 each
    short* thwM  = thwH + 32768;
    short* thwL  = thwM + 32768;
    short* phwH  = thwL + 32768;
    short* phwM  = phwH + 32768;
    short* phwL  = phwM + 32768;
    short* gwH   = phwL + 32768;
    short* gwM   = gwH + 32768;
    short* ptH   = (short*)(ws + 64225280);       // 1,605,632 (after convs)
    short* ptM   = (short*)(ws + 65830912);       // 1,605,632
    short* gc    = (short*)(ws + 69042176);       // 1,605,632
    float* Mpart = (float*)(ws + 70647808);       // 200,704
    float* Spart = (float*)(ws + 70848512);       // 200,704
    float* Mg    = (float*)(ws + 71049216);       // 25,088
    float* iSg   = (float*)(ws + 71074304);       // 25,088
    float* stat  = (float*)(ws + 71099392);       // 2,048
    float* sc    = (float*)(ws + 71101440);       // 1,024
    float* sh    = (float*)(ws + 71102464);       // 1,024
    (void)thL;

    hipMemsetAsync(stat, 0, 2048, stream);

    // weight pre-splits (into pt-region scratch; dead after convs)
    k_split3<<<128, 256, 0, stream>>>(th_w, thwH, thwM, thwL, CI_ * C_);
    k_split3<<<128, 256, 0, stream>>>(ph_w, phwH, phwM, phwL, CI_ * C_);
    k_split2<<<128, 256, 0, stream>>>(g_w, gwH, gwM, CI_ * C_);

    dim3 tb32(32, 8);
    k_transpose<<<dim3(NPIX / 32, C_ / 32, B_), tb32, 0, stream>>>(mask, xt);
    k_conv6p<<<dim3(NPIX / 64, B_), 256, 0, stream>>>(xt, thwH, thwM, thwL, th_b, thH, thM);

    k_transpose<<<dim3(NPIX / 32, C_ / 32, B_), tb32, 0, stream>>>(x, xt);
    k_convxg<<<dim3(NPIX / 64, B_), 256, 0, stream>>>(xt, phwH, phwM, phwL, gwH, gwM,
                                                      ph_b, g_b, pfull, gfull);

    k_pool<<<dim3(NS * CI_ / 256, B_), 256, 0, stream>>>(pfull, gfull, ptH, ptM, gc);

    k_stats4<<<dim3(NS / 64, SLICES, B_), 256, 0, stream>>>(thH, thM, ptH, ptM, Mpart, Spart);
    k_combine<<<(B_ * NS + 255) / 256, 256, 0, stream>>>(Mpart, Spart, Mg, iSg);

    k_pv4<<<dim3(NPIX / 16, NSLICE, B_), 64, 0, stream>>>(thH, thM, ptH, ptM, gc,
                                                          Mg, iSg, part);

    // W split into thH region (dead after pv), then combine + wconv
    k_split2<<<128, 256, 0, stream>>>(W_w, wwH, wwM, C_ * CI_);
    k_ycombine<<<(B_ * NPIX * CI_ + 255) / 256, 256, 0, stream>>>(part, yH, yM);

    k_wconv3<<<dim3(NPIX / 64, C_ / 128, B_), 256, 0, stream>>>(yH, yM, wwH, wwM, W_b, Wy, stat);
    k_bnfin<<<1, 256, 0, stream>>>(stat, gamma, beta, sc, sh);
    k_final<<<dim3(NPIX / 32, C_ / 32, B_), tb32, 0, stream>>>(Wy, x, sc, sh, out);
}

// Round 5
// 1148.308 us; speedup vs baseline: 1.3718x; 1.0235x over previous
//
#include <hip/hip_runtime.h>

// pSGM non-local block, MI355X (round 5).
// r4: 1175us, absmax 0.5; k_pv4 460us @ MfmaUtil 8.9/Occ 28.5 — serial-chain bound.
// r5 changes:
//  - k_pv5: computes f^T (A=phi,B=theta); PV A-frag built via 8 __shfl + 4 selects
//    (no per-iter LDS roundtrip/barrier). p~ = exp(f); M,iS folded into g
//    (g'[m,c] = exp(-M[m])*iS[m]*g[m,c], scaled once by k_gscale).
//    4-wave blocks (m-interleaved), block-end LDS y-reduction; 24.5 waves/CU.
//  - k_stats: SLICES 14 (21.4 waves/CU).
//  - convs: 2-wave cc-split blocks (12.25 waves/CU).
//  - absmax floor is the bf16 smooth path (measured r3/r4), so stats/pv f need
//    only ~1e-3 agreement — no shared accumulation order required.

#define B_ 2
#define C_ 256
#define CI_ 128
#define NPIX 12544
#define NS 3136
#define SLICES 14

typedef short bf16x8 __attribute__((ext_vector_type(8)));
typedef float f32x4 __attribute__((ext_vector_type(4)));
typedef float f32x8 __attribute__((ext_vector_type(8)));

__device__ __forceinline__ short f2bf(float f) {
    unsigned u = __float_as_uint(f);
    u = (u + 0x7fff + ((u >> 16) & 1)) >> 16;   // RNE
    return (short)u;
}
__device__ __forceinline__ float bf2f(short s) {
    return __uint_as_float(((unsigned)(unsigned short)s) << 16);
}
__device__ __forceinline__ f32x4 mfma16(bf16x8 a, bf16x8 b, f32x4 c) {
    return __builtin_amdgcn_mfma_f32_16x16x32_bf16(a, b, c, 0, 0, 0);
}

struct Frag3 { bf16x8 h, m, l; };
struct Frag2 { bf16x8 h, m; };

__device__ __forceinline__ Frag3 split8_3(const float* __restrict__ p) {
    Frag3 f;
    f32x8 v = *(const f32x8*)p;
#pragma unroll
    for (int j = 0; j < 8; j++) {
        float x = v[j];
        unsigned uh = __float_as_uint(x) & 0xffff0000u;
        float r1 = x - __uint_as_float(uh);
        unsigned um = __float_as_uint(r1) & 0xffff0000u;
        float r2 = r1 - __uint_as_float(um);
        f.h[j] = (short)(uh >> 16);
        f.m[j] = (short)(um >> 16);
        f.l[j] = f2bf(r2);
    }
    return f;
}
__device__ __forceinline__ Frag3 ld3(const short* __restrict__ h, const short* __restrict__ m,
                                     const short* __restrict__ l, size_t off) {
    Frag3 f;
    f.h = *(const bf16x8*)(h + off);
    f.m = *(const bf16x8*)(m + off);
    f.l = *(const bf16x8*)(l + off);
    return f;
}
__device__ __forceinline__ Frag2 ld2(const short* __restrict__ h, const short* __restrict__ m,
                                     size_t off) {
    Frag2 f;
    f.h = *(const bf16x8*)(h + off);
    f.m = *(const bf16x8*)(m + off);
    return f;
}
__device__ __forceinline__ f32x4 mm6(Frag3 a, Frag3 b, f32x4 acc) {
    acc = mfma16(a.h, b.l, acc);
    acc = mfma16(a.l, b.h, acc);
    acc = mfma16(a.m, b.m, acc);
    acc = mfma16(a.m, b.h, acc);
    acc = mfma16(a.h, b.m, acc);
    acc = mfma16(a.h, b.h, acc);
    return acc;
}
__device__ __forceinline__ f32x4 mm4(Frag2 a, Frag2 b, f32x4 acc) {
    acc = mfma16(a.m, b.m, acc);
    acc = mfma16(a.m, b.h, acc);
    acc = mfma16(a.h, b.m, acc);
    acc = mfma16(a.h, b.h, acc);
    return acc;
}

// ---- weight pre-splits ----
__global__ void k_split3(const float* __restrict__ a, short* __restrict__ oh,
                         short* __restrict__ om, short* __restrict__ ol, int n) {
    int i = blockIdx.x * 256 + threadIdx.x;
    if (i >= n) return;
    float x = a[i];
    unsigned uh = __float_as_uint(x) & 0xffff0000u;
    float r1 = x - __uint_as_float(uh);
    unsigned um = __float_as_uint(r1) & 0xffff0000u;
    float r2 = r1 - __uint_as_float(um);
    oh[i] = (short)(uh >> 16);
    om[i] = (short)(um >> 16);
    ol[i] = f2bf(r2);
}
__global__ void k_split2(const float* __restrict__ a, short* __restrict__ oh,
                         short* __restrict__ om, int n) {
    int i = blockIdx.x * 256 + threadIdx.x;
    if (i >= n) return;
    float x = a[i];
    unsigned uh = __float_as_uint(x) & 0xffff0000u;
    oh[i] = (short)(uh >> 16);
    om[i] = f2bf(x - __uint_as_float(uh));
}

// ---- transpose: (C_,NPIX) fp32 -> (NPIX,C_) fp32 ----
__global__ void k_transpose(const float* __restrict__ src, float* __restrict__ dst) {
    __shared__ float tile[32][33];
    int b = blockIdx.z;
    const float* s = src + (size_t)b * C_ * NPIX;
    float* d = dst + (size_t)b * NPIX * C_;
    int p0 = blockIdx.x * 32, c0 = blockIdx.y * 32;
    for (int i = threadIdx.y; i < 32; i += 8)
        tile[i][threadIdx.x] = s[(size_t)(c0 + i) * NPIX + p0 + threadIdx.x];
    __syncthreads();
    for (int i = threadIdx.y; i < 32; i += 8)
        d[(size_t)(p0 + i) * C_ + c0 + threadIdx.x] = tile[threadIdx.x][i];
}

// ---- theta conv: 6-term, 2-wave cc-split, 2-plane out. grid (NPIX/16, B), block 128 ----
__global__ __launch_bounds__(128) void k_conv6p(const float* __restrict__ A,
        const short* __restrict__ WH, const short* __restrict__ WM, const short* __restrict__ WL,
        const float* __restrict__ bias, short* __restrict__ oh, short* __restrict__ om) {
    int wid = threadIdx.x >> 6, lane = threadIdx.x & 63;
    int quad = lane >> 4, l16 = lane & 15;
    int b = blockIdx.y;
    const float* Ab = A + (size_t)b * NPIX * C_;
    size_t ob = (size_t)b * NPIX * CI_;
    int row0 = blockIdx.x * 16;
    int ccb = wid * 4;
    f32x4 acc[4] = {};
    for (int kk = 0; kk < C_; kk += 32) {
        Frag3 a = split8_3(Ab + (size_t)(row0 + l16) * C_ + kk + quad * 8);
#pragma unroll
        for (int c4 = 0; c4 < 4; c4++) {
            Frag3 w = ld3(WH, WM, WL, (size_t)((ccb + c4) * 16 + l16) * C_ + kk + quad * 8);
            acc[c4] = mm6(a, w, acc[c4]);
        }
    }
#pragma unroll
    for (int c4 = 0; c4 < 4; c4++) {
        int c = (ccb + c4) * 16 + l16;
        float bv = bias[c];
#pragma unroll
        for (int r = 0; r < 4; r++) {
            float v = acc[c4][r] + bv;
            unsigned uh = __float_as_uint(v) & 0xffff0000u;
            size_t o = ob + (size_t)(row0 + quad * 4 + r) * CI_ + c;
            oh[o] = (short)(uh >> 16);
            om[o] = f2bf(v - __uint_as_float(uh));
        }
    }
}

// ---- fused phi(6-term->fp32) + g(3-term->bf16), 2-wave cc-split. grid (NPIX/16, B), block 128 ----
__global__ __launch_bounds__(128) void k_convxg(const float* __restrict__ A,
        const short* __restrict__ PH, const short* __restrict__ PM, const short* __restrict__ PL,
        const short* __restrict__ GH, const short* __restrict__ GM,
        const float* __restrict__ pbias, const float* __restrict__ gbias,
        float* __restrict__ pfull, short* __restrict__ gout) {
    int wid = threadIdx.x >> 6, lane = threadIdx.x & 63;
    int quad = lane >> 4, l16 = lane & 15;
    int b = blockIdx.y;
    const float* Ab = A + (size_t)b * NPIX * C_;
    float* Pb = pfull + (size_t)b * NPIX * CI_;
    short* Gb = gout + (size_t)b * NPIX * CI_;
    int row0 = blockIdx.x * 16;
    int ccb = wid * 4;
    f32x4 accp[4] = {}, accg[4] = {};
    for (int kk = 0; kk < C_; kk += 32) {
        Frag3 a = split8_3(Ab + (size_t)(row0 + l16) * C_ + kk + quad * 8);
#pragma unroll
        for (int c4 = 0; c4 < 4; c4++) {
            size_t wo = (size_t)((ccb + c4) * 16 + l16) * C_ + kk + quad * 8;
            Frag3 wp = ld3(PH, PM, PL, wo);
            accp[c4] = mm6(a, wp, accp[c4]);
            Frag2 wg = ld2(GH, GM, wo);
            accg[c4] = mfma16(a.m, wg.h, accg[c4]);
            accg[c4] = mfma16(a.h, wg.m, accg[c4]);
            accg[c4] = mfma16(a.h, wg.h, accg[c4]);
        }
    }
#pragma unroll
    for (int c4 = 0; c4 < 4; c4++) {
        int c = (ccb + c4) * 16 + l16;
        float pbv = pbias[c], gbv = gbias[c];
#pragma unroll
        for (int r = 0; r < 4; r++) {
            size_t o = (size_t)(row0 + quad * 4 + r) * CI_ + c;
            Pb[o] = accp[c4][r] + pbv;
            Gb[o] = f2bf(accg[c4][r] + gbv);
        }
    }
}

// ---- pool (1,2,2): pfull fp32 -> phit 2-plane; gfull bf16 -> gcf fp32 (128,Ns) ----
__global__ void k_pool(const float* __restrict__ pfull, const short* __restrict__ gfull,
                       short* __restrict__ pth, short* __restrict__ ptm,
                       float* __restrict__ gcf) {
    int b = blockIdx.y;
    int idx = blockIdx.x * 256 + threadIdx.x;       // idx = m*128 + ci
    int ci = idx & 127, m = idx >> 7;
    int t = m / 196, r2i = m - t * 196;
    int h2 = r2i / 14, w2 = r2i - h2 * 14;
    size_t p = (size_t)t * 784 + (size_t)(2 * h2) * 28 + 2 * w2;
    size_t i0 = (size_t)b * NPIX * CI_ + p * CI_ + ci;
    float pv = fmaxf(fmaxf(pfull[i0], pfull[i0 + CI_]),
                     fmaxf(pfull[i0 + 28 * CI_], pfull[i0 + 29 * CI_]));
    unsigned uh = __float_as_uint(pv) & 0xffff0000u;
    size_t ob = (size_t)b * NS * CI_;
    pth[ob + idx] = (short)(uh >> 16);
    ptm[ob + idx] = f2bf(pv - __uint_as_float(uh));
    float g0 = fmaxf(fmaxf(bf2f(gfull[i0]), bf2f(gfull[i0 + CI_])),
                     fmaxf(bf2f(gfull[i0 + 28 * CI_]), bf2f(gfull[i0 + 29 * CI_])));
    gcf[ob + (size_t)ci * NS + m] = g0;
}

// ---- softmax column stats: 4-term f, dual-n ILP. grid (NS/64, SLICES, B), block 256 ----
__global__ __launch_bounds__(256) void k_stats4(
        const short* __restrict__ thh, const short* __restrict__ thm,
        const short* __restrict__ phh, const short* __restrict__ phm,
        float* __restrict__ Mpart, float* __restrict__ Spart) {
    int wid = threadIdx.x >> 6, lane = threadIdx.x & 63;
    int quad = lane >> 4, l16 = lane & 15;
    int b = blockIdx.z;
    int m0 = blockIdx.x * 64 + wid * 16;
    size_t tb = (size_t)b * NPIX * CI_, pb = (size_t)b * NS * CI_;
    Frag2 bf[4];
#pragma unroll
    for (int kk = 0; kk < 4; kk++)
        bf[kk] = ld2(phh, phm, pb + (size_t)(m0 + l16) * CI_ + kk * 32 + quad * 8);
    float Mx = -1e30f, S = 0.f;
    int n_beg = blockIdx.y * (NPIX / SLICES), n_end = n_beg + NPIX / SLICES;
    for (int n = n_beg; n < n_end; n += 32) {
        f32x4 a0 = {}, a1 = {};
#pragma unroll
        for (int kk = 0; kk < 4; kk++) {
            Frag2 x0 = ld2(thh, thm, tb + (size_t)(n + l16) * CI_ + kk * 32 + quad * 8);
            Frag2 x1 = ld2(thh, thm, tb + (size_t)(n + 16 + l16) * CI_ + kk * 32 + quad * 8);
            a0 = mm4(x0, bf[kk], a0);
            a1 = mm4(x1, bf[kk], a1);
        }
        float tm0 = fmaxf(fmaxf(a0[0], a0[1]), fmaxf(a0[2], a0[3]));
        float tm1 = fmaxf(fmaxf(a1[0], a1[1]), fmaxf(a1[2], a1[3]));
        float tm = fmaxf(tm0, tm1);
        tm = fmaxf(tm, __shfl_xor(tm, 16, 64));
        tm = fmaxf(tm, __shfl_xor(tm, 32, 64));
        float nM = fmaxf(Mx, tm);
        float ps = __expf(a0[0] - nM) + __expf(a0[1] - nM) +
                   __expf(a0[2] - nM) + __expf(a0[3] - nM) +
                   __expf(a1[0] - nM) + __expf(a1[1] - nM) +
                   __expf(a1[2] - nM) + __expf(a1[3] - nM);
        ps += __shfl_xor(ps, 16, 64);
        ps += __shfl_xor(ps, 32, 64);
        S = S * __expf(Mx - nM) + ps;
        Mx = nM;
    }
    if (quad == 0) {
        size_t o = ((size_t)(b * SLICES + blockIdx.y)) * NS + m0 + l16;
        Mpart[o] = Mx;
        Spart[o] = S;
    }
}

// ---- combine: wS[b][m] = exp(-M[m]) / S[m] ----
__global__ void k_combine(const float* __restrict__ Mpart, const float* __restrict__ Spart,
                          float* __restrict__ wS) {
    int i = blockIdx.x * 256 + threadIdx.x;
    if (i >= B_ * NS) return;
    int b = i / NS, m = i - b * NS;
    float gm = -1e30f;
#pragma unroll
    for (int s = 0; s < SLICES; s++)
        gm = fmaxf(gm, Mpart[((size_t)(b * SLICES + s)) * NS + m]);
    float sum = 0.f;
#pragma unroll
    for (int s = 0; s < SLICES; s++) {
        size_t o = ((size_t)(b * SLICES + s)) * NS + m;
        sum += Spart[o] * __expf(Mpart[o] - gm);
    }
    wS[i] = __expf(-gm) / sum;
}

// ---- g scale: gc_bf16[ci][m] = bf16(gcf * wS[m]) ----
__global__ void k_gscale(const float* __restrict__ gcf, const float* __restrict__ wS,
                         short* __restrict__ gc) {
    int i = blockIdx.x * 256 + threadIdx.x;
    int b = i / (CI_ * NS);
    int m = i % NS;
    gc[i] = f2bf(gcf[i] * wS[b * NS + m]);
}

// ---- PV: f^T + shuffle-transform, folded softmax, 4-wave m-split + LDS y-reduce ----
// grid (NPIX/16, B), block 256.
__global__ __launch_bounds__(256, 4) void k_pv5(
        const short* __restrict__ thh, const short* __restrict__ thm,
        const short* __restrict__ phh, const short* __restrict__ phm,
        const short* __restrict__ gmat, short* __restrict__ yh, short* __restrict__ ym) {
    __shared__ __align__(16) float red[2][64 * 36];
    int wid = threadIdx.x >> 6, lane = threadIdx.x & 63;
    int quad = lane >> 4, l16 = lane & 15;
    int b = blockIdx.y;
    int n0 = blockIdx.x * 16;
    size_t tb = (size_t)b * NPIX * CI_, pb = (size_t)b * NS * CI_;
    const short* gcb = gmat + (size_t)b * CI_ * NS;
    Frag2 af[4];                 // theta B-frags (cols n0..n0+15), fixed per block
#pragma unroll
    for (int kk = 0; kk < 4; kk++)
        af[kk] = ld2(thh, thm, tb + (size_t)(n0 + l16) * CI_ + kk * 32 + quad * 8);
    f32x4 yacc[8] = {};
    int srcLo = ((2 * quad) & 3) * 16 + l16;
    int srcHi = ((2 * quad + 1) & 3) * 16 + l16;
    bool hiTile = quad >= 2;
    for (int i = wid; i < NS / 32; i += 4) {
        int m0 = i * 32;
        f32x4 f0 = {}, f1 = {};
#pragma unroll
        for (int kk = 0; kk < 4; kk++) {
            Frag2 p0 = ld2(phh, phm, pb + (size_t)(m0 + l16) * CI_ + kk * 32 + quad * 8);
            Frag2 p1 = ld2(phh, phm, pb + (size_t)(m0 + 16 + l16) * CI_ + kk * 32 + quad * 8);
            f0 = mm4(p0, af[kk], f0);    // f^T tile0: reg r = m0+4*quad+r, col n = l16
            f1 = mm4(p1, af[kk], f1);    // f^T tile1: m0+16+4*quad+r
        }
        // p~ = exp(f) (M, 1/S folded into g'); pack reg pairs into dwords
        unsigned t0d0 = (unsigned)(unsigned short)f2bf(__expf(f0[0])) |
                        ((unsigned)(unsigned short)f2bf(__expf(f0[1])) << 16);
        unsigned t0d1 = (unsigned)(unsigned short)f2bf(__expf(f0[2])) |
                        ((unsigned)(unsigned short)f2bf(__expf(f0[3])) << 16);
        unsigned t1d0 = (unsigned)(unsigned short)f2bf(__expf(f1[0])) |
                        ((unsigned)(unsigned short)f2bf(__expf(f1[1])) << 16);
        unsigned t1d1 = (unsigned)(unsigned short)f2bf(__expf(f1[2])) |
                        ((unsigned)(unsigned short)f2bf(__expf(f1[3])) << 16);
        // A-frag for PV: lane (quad,l16) needs p[n=l16][m0 + 8*quad + j], j=0..7
        unsigned lo0t0 = __shfl(t0d0, srcLo), lo1t0 = __shfl(t0d1, srcLo);
        unsigned hi0t0 = __shfl(t0d0, srcHi), hi1t0 = __shfl(t0d1, srcHi);
        unsigned lo0t1 = __shfl(t1d0, srcLo), lo1t1 = __shfl(t1d1, srcLo);
        unsigned hi0t1 = __shfl(t1d0, srcHi), hi1t1 = __shfl(t1d1, srcHi);
        unsigned pd[4];
        pd[0] = hiTile ? lo0t1 : lo0t0;
        pd[1] = hiTile ? lo1t1 : lo1t0;
        pd[2] = hiTile ? hi0t1 : hi0t0;
        pd[3] = hiTile ? hi1t1 : hi1t0;
        bf16x8 pa;
        __builtin_memcpy(&pa, pd, 16);
#pragma unroll
        for (int cc = 0; cc < 8; cc++) {
            bf16x8 gb = *(const bf16x8*)(gcb + (size_t)(cc * 16 + l16) * NS + m0 + quad * 8);
            yacc[cc] = mfma16(pa, gb, yacc[cc]);
        }
    }
    // block y-reduction: waves 1,3 -> slots; 0,2 add; 2 -> slot0; 0 adds + stores
    int rb = lane * 36;
    if (wid == 1) {
#pragma unroll
        for (int cc = 0; cc < 8; cc++) *(f32x4*)&red[0][rb + cc * 4] = yacc[cc];
    } else if (wid == 3) {
#pragma unroll
        for (int cc = 0; cc < 8; cc++) *(f32x4*)&red[1][rb + cc * 4] = yacc[cc];
    }
    __syncthreads();
    if (wid == 0) {
#pragma unroll
        for (int cc = 0; cc < 8; cc++) yacc[cc] += *(const f32x4*)&red[0][rb + cc * 4];
    } else if (wid == 2) {
#pragma unroll
        for (int cc = 0; cc < 8; cc++) yacc[cc] += *(const f32x4*)&red[1][rb + cc * 4];
    }
    __syncthreads();
    if (wid == 2) {
#pragma unroll
        for (int cc = 0; cc < 8; cc++) *(f32x4*)&red[0][rb + cc * 4] = yacc[cc];
    }
    __syncthreads();
    if (wid == 0) {
        short* yhb = yh + tb;
        short* ymb = ym + tb;
#pragma unroll
        for (int cc = 0; cc < 8; cc++) {
            f32x4 v4 = yacc[cc] + *(const f32x4*)&red[0][rb + cc * 4];
#pragma unroll
            for (int r = 0; r < 4; r++) {
                float v = v4[r];
                unsigned uh = __float_as_uint(v) & 0xffff0000u;
                size_t o = (size_t)(n0 + quad * 4 + r) * CI_ + cc * 16 + l16;
                yhb[o] = (short)(uh >> 16);
                ymb[o] = f2bf(v - __uint_as_float(uh));
            }
        }
    }
}

// ---- W conv (3-term) + fused BN stats. grid (NPIX/64, C_/128, B), block 256 ----
__global__ __launch_bounds__(256) void k_wconv3(const short* __restrict__ yh,
        const short* __restrict__ ym, const short* __restrict__ WH,
        const short* __restrict__ WM, const float* __restrict__ bias,
        float* __restrict__ Wy, float* __restrict__ stat) {
    int wid = threadIdx.x >> 6, lane = threadIdx.x & 63;
    int quad = lane >> 4, l16 = lane & 15;
    int b = blockIdx.z;
    size_t yb = (size_t)b * NPIX * CI_;
    float* Wyb = Wy + (size_t)b * NPIX * C_;
    int row0 = blockIdx.x * 64 + wid * 16;
    int col0 = blockIdx.y * 128;
    f32x4 acc[8] = {};
#pragma unroll
    for (int kk = 0; kk < 4; kk++) {
        size_t ao = yb + (size_t)(row0 + l16) * CI_ + kk * 32 + quad * 8;
        bf16x8 ah = *(const bf16x8*)(yh + ao);
        bf16x8 am = *(const bf16x8*)(ym + ao);
#pragma unroll
        for (int cc = 0; cc < 8; cc++) {
            Frag2 w = ld2(WH, WM, (size_t)(col0 + cc * 16 + l16) * CI_ + kk * 32 + quad * 8);
            acc[cc] = mfma16(am, w.h, acc[cc]);
            acc[cc] = mfma16(ah, w.m, acc[cc]);
            acc[cc] = mfma16(ah, w.h, acc[cc]);
        }
    }
#pragma unroll
    for (int cc = 0; cc < 8; cc++) {
        int c = col0 + cc * 16 + l16;
        float bv = bias[c];
        float s1 = 0.f, s2 = 0.f;
#pragma unroll
        for (int r = 0; r < 4; r++) {
            float v = acc[cc][r] + bv;
            Wyb[(size_t)(row0 + quad * 4 + r) * C_ + c] = v;
            s1 += v;
            s2 += v * v;
        }
        s1 += __shfl_xor(s1, 16, 64); s1 += __shfl_xor(s1, 32, 64);
        s2 += __shfl_xor(s2, 16, 64); s2 += __shfl_xor(s2, 32, 64);
        if (quad == 0) {
            atomicAdd(&stat[c], s1);
            atomicAdd(&stat[C_ + c], s2);
        }
    }
}

__global__ void k_bnfin(const float* __restrict__ stat, const float* __restrict__ gamma,
                        const float* __restrict__ beta, float* __restrict__ sc,
                        float* __restrict__ sh) {
    int c = threadIdx.x;
    const float inv = 1.f / (float)(B_ * NPIX);
    float mean = stat[c] * inv;
    float var = stat[C_ + c] * inv - mean * mean;
    float s = gamma[c] * rsqrtf(var + 1e-5f);
    sc[c] = s;
    sh[c] = beta[c] - mean * s;
}

__global__ void k_final(const float* __restrict__ Wy, const float* __restrict__ x,
                        const float* __restrict__ sc, const float* __restrict__ sh,
                        float* __restrict__ out) {
    __shared__ float tile[32][33];
    int b = blockIdx.z;
    const float* Wyb = Wy + (size_t)b * NPIX * C_;
    const float* xb = x + (size_t)b * C_ * NPIX;
    float* ob = out + (size_t)b * C_ * NPIX;
    int p0 = blockIdx.x * 32, c0 = blockIdx.y * 32;
    for (int i = threadIdx.y; i < 32; i += 8)
        tile[i][threadIdx.x] = Wyb[(size_t)(p0 + i) * C_ + c0 + threadIdx.x];
    __syncthreads();
    for (int i = threadIdx.y; i < 32; i += 8) {
        int c = c0 + i;
        size_t o = (size_t)c * NPIX + p0 + threadIdx.x;
        ob[o] = tile[threadIdx.x][i] * sc[c] + sh[c] + xb[o];
    }
}

extern "C" void kernel_launch(void* const* d_in, const int* in_sizes, int n_in,
                              void* d_out, int out_size, void* d_ws, size_t ws_size,
                              hipStream_t stream) {
    (void)in_sizes; (void)n_in; (void)out_size; (void)ws_size;
    const float* x     = (const float*)d_in[0];
    const float* mask  = (const float*)d_in[1];
    const float* g_w   = (const float*)d_in[2];
    const float* g_b   = (const float*)d_in[3];
    const float* th_w  = (const float*)d_in[4];
    const float* th_b  = (const float*)d_in[5];
    const float* ph_w  = (const float*)d_in[6];
    const float* ph_b  = (const float*)d_in[7];
    const float* W_w   = (const float*)d_in[8];
    const float* W_b   = (const float*)d_in[9];
    const float* gamma = (const float*)d_in[10];
    const float* beta  = (const float*)d_in[11];
    float* out = (float*)d_out;

    char* ws = (char*)d_ws;
    // [0, 25.69MB) timeline: xt (transposes+convs) -> {gcf, Mpart, Spart, wS} -> Wy
    float* xt    = (float*)(ws + 0);
    float* gcf   = (float*)(ws + 0);              // 3,211,264  (pool -> gscale)
    float* Mpart = (float*)(ws + 4194304);        // 351,232
    float* Spart = (float*)(ws + 4718592);        // 351,232
    float* wS    = (float*)(ws + 5242880);        // 25,088
    float* Wy    = (float*)(ws + 0);              // 25,690,112 (wconv -> final)
    short* thH   = (short*)(ws + 25690112);       // 6,422,528
    short* wwH   = (short*)(ws + 25690112);       // alias: W split after pv
    short* wwM   = wwH + 32768;
    short* thM   = (short*)(ws + 32112640);       // 6,422,528
    float* pfull = (float*)(ws + 44957696);       // 12,845,056 (pre-pool)
    short* yH    = (short*)(ws + 44957696);       // alias after pool
    short* yM    = (short*)(ws + 51380224);
    short* gfull = (short*)(ws + 57802752);       // 6,422,528
    short* thwH  = (short*)(ws + 64225280);       // weight scratch (dead after convs)
    short* thwM  = thwH + 32768;
    short* thwL  = thwM + 32768;
    short* phwH  = thwL + 32768;
    short* phwM  = phwH + 32768;
    short* phwL  = phwM + 32768;
    short* gwH   = phwL + 32768;
    short* gwM   = gwH + 32768;
    short* ptH   = (short*)(ws + 64225280);       // 1,605,632 (after convs)
    short* ptM   = (short*)(ws + 65830912);       // 1,605,632
    short* gc    = (short*)(ws + 69042176);       // 1,605,632 (bf16, scaled)
    float* stat  = (float*)(ws + 71099392);       // 2,048
    float* sc    = (float*)(ws + 71101440);       // 1,024
    float* sh    = (float*)(ws + 71102464);       // 1,024

    hipMemsetAsync(stat, 0, 2048, stream);

    k_split3<<<128, 256, 0, stream>>>(th_w, thwH, thwM, thwL, CI_ * C_);
    k_split3<<<128, 256, 0, stream>>>(ph_w, phwH, phwM, phwL, CI_ * C_);
    k_split2<<<128, 256, 0, stream>>>(g_w, gwH, gwM, CI_ * C_);

    dim3 tb32(32, 8);
    k_transpose<<<dim3(NPIX / 32, C_ / 32, B_), tb32, 0, stream>>>(mask, xt);
    k_conv6p<<<dim3(NPIX / 16, B_), 128, 0, stream>>>(xt, thwH, thwM, thwL, th_b, thH, thM);

    k_transpose<<<dim3(NPIX / 32, C_ / 32, B_), tb32, 0, stream>>>(x, xt);
    k_convxg<<<dim3(NPIX / 16, B_), 128, 0, stream>>>(xt, phwH, phwM, phwL, gwH, gwM,
                                                      ph_b, g_b, pfull, gfull);

    k_pool<<<dim3(NS * CI_ / 256, B_), 256, 0, stream>>>(pfull, gfull, ptH, ptM, gcf);

    k_stats4<<<dim3(NS / 64, SLICES, B_), 256, 0, stream>>>(thH, thM, ptH, ptM, Mpart, Spart);
    k_combine<<<(B_ * NS + 255) / 256, 256, 0, stream>>>(Mpart, Spart, wS);
    k_gscale<<<(B_ * CI_ * NS) / 256, 256, 0, stream>>>(gcf, wS, gc);

    k_pv5<<<dim3(NPIX / 16, B_), 256, 0, stream>>>(thH, thM, ptH, ptM, gc, yH, yM);

    k_split2<<<128, 256, 0, stream>>>(W_w, wwH, wwM, C_ * CI_);
    k_wconv3<<<dim3(NPIX / 64, C_ / 128, B_), 256, 0, stream>>>(yH, yM, wwH, wwM, W_b, Wy, stat);
    k_bnfin<<<1, 256, 0, stream>>>(stat, gamma, beta, sc, sh);
    k_final<<<dim3(NPIX / 32, C_ / 32, B_), tb32, 0, stream>>>(Wy, x, sc, sh, out);
}

// Round 6
// 637.309 us; speedup vs baseline: 2.4717x; 1.8018x over previous
//
#include <hip/hip_runtime.h>

// pSGM non-local block, MI355X (round 6: fragment-contiguous layouts + max-free softmax).
// r5: 1148us; k_pv5 482us @ MfmaUtil 8.5 / Occ 36 — occupancy-insensitive => transaction/
// L2-fabric throughput bound from 16x-scattered 64B fragment loads + 3.8GB phi/g re-stream.
// r6: perm layout => every hot-loop load is one coalesced 1KB wave-load; softmax without
// running max (f<=~67 < 88 => S=sum exp(f-32) safe in fp32); 3-term f; PV m-halved with
// 4 waves sharing phi/g frags (L1 dedup); fp32 y-partials + combine; wconv reads y-perm.

#define B_ 2
#define C_ 256
#define CI_ 128
#define NPIX 12544
#define NS 3136
#define NSL 8

typedef short bf16x8 __attribute__((ext_vector_type(8)));
typedef float f32x4 __attribute__((ext_vector_type(4)));
typedef float f32x8 __attribute__((ext_vector_type(8)));

__device__ __forceinline__ short f2bf(float f) {
    unsigned u = __float_as_uint(f);
    u = (u + 0x7fff + ((u >> 16) & 1)) >> 16;   // RNE
    return (short)u;
}
__device__ __forceinline__ float bf2f(short s) {
    return __uint_as_float(((unsigned)(unsigned short)s) << 16);
}
__device__ __forceinline__ f32x4 mfma16(bf16x8 a, bf16x8 b, f32x4 c) {
    return __builtin_amdgcn_mfma_f32_16x16x32_bf16(a, b, c, 0, 0, 0);
}
// perm layout: element (row r, k<128) -> fragment-contiguous address (2B elems)
__device__ __forceinline__ size_t pidx(int r, int k) {
    return (size_t)((r >> 4) * 4 + (k >> 5)) * 512 +
           (size_t)((((k >> 3) & 3) * 128) + (r & 15) * 8 + (k & 7));
}

struct Frag3 { bf16x8 h, m, l; };
struct Frag2 { bf16x8 h, m; };

__device__ __forceinline__ Frag3 split8_3(const float* __restrict__ p) {
    Frag3 f;
    f32x8 v = *(const f32x8*)p;
#pragma unroll
    for (int j = 0; j < 8; j++) {
        float x = v[j];
        unsigned uh = __float_as_uint(x) & 0xffff0000u;
        float r1 = x - __uint_as_float(uh);
        unsigned um = __float_as_uint(r1) & 0xffff0000u;
        float r2 = r1 - __uint_as_float(um);
        f.h[j] = (short)(uh >> 16);
        f.m[j] = (short)(um >> 16);
        f.l[j] = f2bf(r2);
    }
    return f;
}
__device__ __forceinline__ Frag3 ld3(const short* __restrict__ h, const short* __restrict__ m,
                                     const short* __restrict__ l, size_t off) {
    Frag3 f;
    f.h = *(const bf16x8*)(h + off);
    f.m = *(const bf16x8*)(m + off);
    f.l = *(const bf16x8*)(l + off);
    return f;
}
__device__ __forceinline__ Frag2 ld2(const short* __restrict__ h, const short* __restrict__ m,
                                     size_t off) {
    Frag2 f;
    f.h = *(const bf16x8*)(h + off);
    f.m = *(const bf16x8*)(m + off);
    return f;
}
__device__ __forceinline__ f32x4 mm6(Frag3 a, Frag3 b, f32x4 acc) {
    acc = mfma16(a.h, b.l, acc);
    acc = mfma16(a.l, b.h, acc);
    acc = mfma16(a.m, b.m, acc);
    acc = mfma16(a.m, b.h, acc);
    acc = mfma16(a.h, b.m, acc);
    acc = mfma16(a.h, b.h, acc);
    return acc;
}
__device__ __forceinline__ f32x4 mm3(Frag2 a, Frag2 b, f32x4 acc) {
    acc = mfma16(a.m, b.h, acc);
    acc = mfma16(a.h, b.m, acc);
    acc = mfma16(a.h, b.h, acc);
    return acc;
}

// ---- weight pre-splits ----
__global__ void k_split3(const float* __restrict__ a, short* __restrict__ oh,
                         short* __restrict__ om, short* __restrict__ ol, int n) {
    int i = blockIdx.x * 256 + threadIdx.x;
    if (i >= n) return;
    float x = a[i];
    unsigned uh = __float_as_uint(x) & 0xffff0000u;
    float r1 = x - __uint_as_float(uh);
    unsigned um = __float_as_uint(r1) & 0xffff0000u;
    float r2 = r1 - __uint_as_float(um);
    oh[i] = (short)(uh >> 16);
    om[i] = (short)(um >> 16);
    ol[i] = f2bf(r2);
}
__global__ void k_split2(const float* __restrict__ a, short* __restrict__ oh,
                         short* __restrict__ om, int n) {
    int i = blockIdx.x * 256 + threadIdx.x;
    if (i >= n) return;
    float x = a[i];
    unsigned uh = __float_as_uint(x) & 0xffff0000u;
    oh[i] = (short)(uh >> 16);
    om[i] = f2bf(x - __uint_as_float(uh));
}

// ---- transpose: (C_,NPIX) fp32 -> (NPIX,C_) fp32 ----
__global__ void k_transpose(const float* __restrict__ src, float* __restrict__ dst) {
    __shared__ float tile[32][33];
    int b = blockIdx.z;
    const float* s = src + (size_t)b * C_ * NPIX;
    float* d = dst + (size_t)b * NPIX * C_;
    int p0 = blockIdx.x * 32, c0 = blockIdx.y * 32;
    for (int i = threadIdx.y; i < 32; i += 8)
        tile[i][threadIdx.x] = s[(size_t)(c0 + i) * NPIX + p0 + threadIdx.x];
    __syncthreads();
    for (int i = threadIdx.y; i < 32; i += 8)
        d[(size_t)(p0 + i) * C_ + c0 + threadIdx.x] = tile[threadIdx.x][i];
}

// ---- theta conv: 6-term exact, 2-plane PERM output. grid (NPIX/16, B), block 128 ----
__global__ __launch_bounds__(128) void k_conv6p(const float* __restrict__ A,
        const short* __restrict__ WH, const short* __restrict__ WM, const short* __restrict__ WL,
        const float* __restrict__ bias, short* __restrict__ oh, short* __restrict__ om) {
    int wid = threadIdx.x >> 6, lane = threadIdx.x & 63;
    int quad = lane >> 4, l16 = lane & 15;
    int b = blockIdx.y;
    const float* Ab = A + (size_t)b * NPIX * C_;
    size_t ob = (size_t)b * NPIX * CI_;
    int row0 = blockIdx.x * 16;
    int ccb = wid * 4;
    f32x4 acc[4] = {};
    for (int kk = 0; kk < C_; kk += 32) {
        Frag3 a = split8_3(Ab + (size_t)(row0 + l16) * C_ + kk + quad * 8);
#pragma unroll
        for (int c4 = 0; c4 < 4; c4++) {
            Frag3 w = ld3(WH, WM, WL, (size_t)((ccb + c4) * 16 + l16) * C_ + kk + quad * 8);
            acc[c4] = mm6(a, w, acc[c4]);
        }
    }
#pragma unroll
    for (int c4 = 0; c4 < 4; c4++) {
        int c = (ccb + c4) * 16 + l16;
        float bv = bias[c];
#pragma unroll
        for (int r = 0; r < 4; r++) {
            float v = acc[c4][r] + bv;
            unsigned uh = __float_as_uint(v) & 0xffff0000u;
            size_t o = ob + pidx(row0 + quad * 4 + r, c);
            oh[o] = (short)(uh >> 16);
            om[o] = f2bf(v - __uint_as_float(uh));
        }
    }
}

// ---- fused phi(6-term->fp32 std) + g(3-term->bf16 std). grid (NPIX/16, B), block 128 ----
__global__ __launch_bounds__(128) void k_convxg(const float* __restrict__ A,
        const short* __restrict__ PH, const short* __restrict__ PM, const short* __restrict__ PL,
        const short* __restrict__ GH, const short* __restrict__ GM,
        const float* __restrict__ pbias, const float* __restrict__ gbias,
        float* __restrict__ pfull, short* __restrict__ gout) {
    int wid = threadIdx.x >> 6, lane = threadIdx.x & 63;
    int quad = lane >> 4, l16 = lane & 15;
    int b = blockIdx.y;
    const float* Ab = A + (size_t)b * NPIX * C_;
    float* Pb = pfull + (size_t)b * NPIX * CI_;
    short* Gb = gout + (size_t)b * NPIX * CI_;
    int row0 = blockIdx.x * 16;
    int ccb = wid * 4;
    f32x4 accp[4] = {}, accg[4] = {};
    for (int kk = 0; kk < C_; kk += 32) {
        Frag3 a = split8_3(Ab + (size_t)(row0 + l16) * C_ + kk + quad * 8);
#pragma unroll
        for (int c4 = 0; c4 < 4; c4++) {
            size_t wo = (size_t)((ccb + c4) * 16 + l16) * C_ + kk + quad * 8;
            Frag3 wp = ld3(PH, PM, PL, wo);
            accp[c4] = mm6(a, wp, accp[c4]);
            Frag2 wg = ld2(GH, GM, wo);
            accg[c4] = mfma16(a.m, wg.h, accg[c4]);
            accg[c4] = mfma16(a.h, wg.m, accg[c4]);
            accg[c4] = mfma16(a.h, wg.h, accg[c4]);
        }
    }
#pragma unroll
    for (int c4 = 0; c4 < 4; c4++) {
        int c = (ccb + c4) * 16 + l16;
        float pbv = pbias[c], gbv = gbias[c];
#pragma unroll
        for (int r = 0; r < 4; r++) {
            size_t o = (size_t)(row0 + quad * 4 + r) * CI_ + c;
            Pb[o] = accp[c4][r] + pbv;
            Gb[o] = f2bf(accg[c4][r] + gbv);
        }
    }
}

// ---- pool: pfull fp32 -> phi 2-plane PERM; gfull bf16 -> gcf fp32 (ci, m) ----
__global__ void k_pool(const float* __restrict__ pfull, const short* __restrict__ gfull,
                       short* __restrict__ pth, short* __restrict__ ptm,
                       float* __restrict__ gcf) {
    int b = blockIdx.y;
    int idx = blockIdx.x * 256 + threadIdx.x;       // idx = m*128 + ci
    int ci = idx & 127, m = idx >> 7;
    int t = m / 196, r2i = m - t * 196;
    int h2 = r2i / 14, w2 = r2i - h2 * 14;
    size_t p = (size_t)t * 784 + (size_t)(2 * h2) * 28 + 2 * w2;
    size_t i0 = (size_t)b * NPIX * CI_ + p * CI_ + ci;
    float pv = fmaxf(fmaxf(pfull[i0], pfull[i0 + CI_]),
                     fmaxf(pfull[i0 + 28 * CI_], pfull[i0 + 29 * CI_]));
    unsigned uh = __float_as_uint(pv) & 0xffff0000u;
    size_t ob = (size_t)b * NS * CI_ + pidx(m, ci);
    pth[ob] = (short)(uh >> 16);
    ptm[ob] = f2bf(pv - __uint_as_float(uh));
    float g0 = fmaxf(fmaxf(bf2f(gfull[i0]), bf2f(gfull[i0 + CI_])),
                     fmaxf(bf2f(gfull[i0 + 28 * CI_]), bf2f(gfull[i0 + 29 * CI_])));
    gcf[(size_t)b * NS * CI_ + (size_t)ci * NS + m] = g0;
}

// ---- stats: S[m] = sum_n exp(f-32), max-free, 3-term, perm loads.
// grid (NS/64, NSL, B), block 256; wave = 16 m-cols. ----
__global__ __launch_bounds__(256) void k_stats(
        const short* __restrict__ thh, const short* __restrict__ thm,
        const short* __restrict__ phh, const short* __restrict__ phm,
        float* __restrict__ Spart) {
    int wid = threadIdx.x >> 6, lane = threadIdx.x & 63;
    int quad = lane >> 4, l16 = lane & 15;
    int b = blockIdx.z;
    size_t tb = (size_t)b * NPIX * CI_, pb = (size_t)b * NS * CI_;
    int mt = blockIdx.x * 4 + wid;                  // m-tile (16 m)
    Frag2 bf[4];
#pragma unroll
    for (int kk = 0; kk < 4; kk++)
        bf[kk] = ld2(phh, phm, pb + ((size_t)mt * 4 + kk) * 512 + lane * 8);
    float S = 0.f;
    int t_beg = blockIdx.y * (784 / NSL), t_end = t_beg + 784 / NSL;
    for (int t = t_beg; t < t_end; t += 2) {
        f32x4 a0 = {}, a1 = {};
#pragma unroll
        for (int kk = 0; kk < 4; kk++) {
            Frag2 x0 = ld2(thh, thm, tb + ((size_t)t * 4 + kk) * 512 + lane * 8);
            Frag2 x1 = ld2(thh, thm, tb + ((size_t)(t + 1) * 4 + kk) * 512 + lane * 8);
            a0 = mm3(x0, bf[kk], a0);
            a1 = mm3(x1, bf[kk], a1);
        }
        S += __expf(a0[0] - 32.f) + __expf(a0[1] - 32.f) +
             __expf(a0[2] - 32.f) + __expf(a0[3] - 32.f) +
             __expf(a1[0] - 32.f) + __expf(a1[1] - 32.f) +
             __expf(a1[2] - 32.f) + __expf(a1[3] - 32.f);
    }
    S += __shfl_xor(S, 16, 64);
    S += __shfl_xor(S, 32, 64);
    if (quad == 0)
        Spart[((size_t)(b * NSL + blockIdx.y)) * NS + mt * 16 + l16] = S;
}

// ---- combine: wS = 1/sum(Spart) ----
__global__ void k_combine(const float* __restrict__ Spart, float* __restrict__ wS) {
    int i = blockIdx.x * 256 + threadIdx.x;
    if (i >= B_ * NS) return;
    int b = i / NS, m = i - b * NS;
    float s = 0.f;
#pragma unroll
    for (int sl = 0; sl < NSL; sl++)
        s += Spart[((size_t)(b * NSL + sl)) * NS + m];
    wS[i] = 1.f / s;
}

// ---- g scale into PV-B perm layout: tile s covers m=32s..32s+31, cc = c-tile ----
__global__ void k_gscale(const float* __restrict__ gcf, const float* __restrict__ wS,
                         short* __restrict__ gc) {
    int i = blockIdx.x * 256 + threadIdx.x;         // B*CI*(NS/8) threads
    int b = i / (CI_ * (NS / 8));
    int rem = i - b * CI_ * (NS / 8);
    int c = rem / (NS / 8);
    int m8 = rem - c * (NS / 8);
    int m = m8 * 8;
    const float* gr = gcf + ((size_t)b * CI_ + c) * NS + m;
    const float* wr = wS + (size_t)b * NS + m;
    short* go = gc + (size_t)b * NS * CI_ + ((size_t)(m8 >> 2) * 8 + (c >> 4)) * 512 +
                (m8 & 3) * 128 + (c & 15) * 8;
#pragma unroll
    for (int j = 0; j < 8; j++) go[j] = f2bf(gr[j] * wr[j]);
}

// ---- PV: f^T 3-term + shfl transform, p~=exp(f-32), m-halved, perm loads.
// grid (NPIX/64, 2, B), block 256; wave = 16 n, streams its m-half. ----
__global__ __launch_bounds__(256, 2) void k_pv(
        const short* __restrict__ thh, const short* __restrict__ thm,
        const short* __restrict__ phh, const short* __restrict__ phm,
        const short* __restrict__ gp, float* __restrict__ part) {
    int wid = threadIdx.x >> 6, lane = threadIdx.x & 63;
    int quad = lane >> 4, l16 = lane & 15;
    int b = blockIdx.z, mh = blockIdx.y;
    int nt = blockIdx.x * 4 + wid;                  // n-tile (16 n)
    size_t tb = (size_t)b * NPIX * CI_, pb = (size_t)b * NS * CI_;
    const short* gpb = gp + (size_t)b * NS * CI_;
    Frag2 af[4];
#pragma unroll
    for (int kk = 0; kk < 4; kk++)
        af[kk] = ld2(thh, thm, tb + ((size_t)nt * 4 + kk) * 512 + lane * 8);
    f32x4 yacc[8] = {};
    int srcLo = ((2 * quad) & 3) * 16 + l16;
    int srcHi = ((2 * quad + 1) & 3) * 16 + l16;
    bool hiTile = quad >= 2;
    int s_beg = mh * 49, s_end = s_beg + 49;        // 32-m steps
    for (int s = s_beg; s < s_end; s++) {
        f32x4 f0 = {}, f1 = {};
#pragma unroll
        for (int kk = 0; kk < 4; kk++) {
            Frag2 p0 = ld2(phh, phm, pb + ((size_t)(2 * s) * 4 + kk) * 512 + lane * 8);
            Frag2 p1 = ld2(phh, phm, pb + ((size_t)(2 * s + 1) * 4 + kk) * 512 + lane * 8);
            f0 = mm3(p0, af[kk], f0);               // f^T tile0: reg r = 32s+4*quad+r, col n=l16
            f1 = mm3(p1, af[kk], f1);
        }
        unsigned t0d0 = (unsigned)(unsigned short)f2bf(__expf(f0[0] - 32.f)) |
                        ((unsigned)(unsigned short)f2bf(__expf(f0[1] - 32.f)) << 16);
        unsigned t0d1 = (unsigned)(unsigned short)f2bf(__expf(f0[2] - 32.f)) |
                        ((unsigned)(unsigned short)f2bf(__expf(f0[3] - 32.f)) << 16);
        unsigned t1d0 = (unsigned)(unsigned short)f2bf(__expf(f1[0] - 32.f)) |
                        ((unsigned)(unsigned short)f2bf(__expf(f1[1] - 32.f)) << 16);
        unsigned t1d1 = (unsigned)(unsigned short)f2bf(__expf(f1[2] - 32.f)) |
                        ((unsigned)(unsigned short)f2bf(__expf(f1[3] - 32.f)) << 16);
        unsigned lo0t0 = __shfl(t0d0, srcLo), lo1t0 = __shfl(t0d1, srcLo);
        unsigned hi0t0 = __shfl(t0d0, srcHi), hi1t0 = __shfl(t0d1, srcHi);
        unsigned lo0t1 = __shfl(t1d0, srcLo), lo1t1 = __shfl(t1d1, srcLo);
        unsigned hi0t1 = __shfl(t1d0, srcHi), hi1t1 = __shfl(t1d1, srcHi);
        unsigned pd[4];
        pd[0] = hiTile ? lo0t1 : lo0t0;
        pd[1] = hiTile ? lo1t1 : lo1t0;
        pd[2] = hiTile ? hi0t1 : hi0t0;
        pd[3] = hiTile ? hi1t1 : hi1t0;
        bf16x8 pa;
        __builtin_memcpy(&pa, pd, 16);
#pragma unroll
        for (int cc = 0; cc < 8; cc++) {
            bf16x8 gb = *(const bf16x8*)(gpb + (size_t)s * 4096 + cc * 512 + lane * 8);
            yacc[cc] = mfma16(pa, gb, yacc[cc]);
        }
    }
    // fp32 partials stored in perm element order (ycombine/wconv read coalesced)
    float* po = part + ((size_t)(mh * B_ + b)) * NPIX * CI_;
#pragma unroll
    for (int cc = 0; cc < 8; cc++)
#pragma unroll
        for (int r = 0; r < 4; r++)
            po[pidx(nt * 16 + quad * 4 + r, cc * 16 + l16)] = yacc[cc][r];
}

// ---- combine y halves -> 2-plane bf16 (perm order preserved) ----
__global__ void k_ycombine(const float* __restrict__ part, short* __restrict__ yh,
                           short* __restrict__ ym) {
    size_t i = (size_t)blockIdx.x * 256 + threadIdx.x;
    const size_t n = (size_t)B_ * NPIX * CI_;
    if (i >= n) return;
    float v = part[i] + part[n + i];
    unsigned uh = __float_as_uint(v) & 0xffff0000u;
    yh[i] = (short)(uh >> 16);
    ym[i] = f2bf(v - __uint_as_float(uh));
}

// ---- W conv (3-term, perm y reads) + fused BN stats. grid (NPIX/64, C_/128, B) ----
__global__ __launch_bounds__(256) void k_wconv3(const short* __restrict__ yh,
        const short* __restrict__ ym, const short* __restrict__ WH,
        const short* __restrict__ WM, const float* __restrict__ bias,
        float* __restrict__ Wy, float* __restrict__ stat) {
    int wid = threadIdx.x >> 6, lane = threadIdx.x & 63;
    int quad = lane >> 4, l16 = lane & 15;
    int b = blockIdx.z;
    size_t yb = (size_t)b * NPIX * CI_;
    float* Wyb = Wy + (size_t)b * NPIX * C_;
    int tile = blockIdx.x * 4 + wid;
    int row0 = tile * 16;
    int col0 = blockIdx.y * 128;
    f32x4 acc[8] = {};
#pragma unroll
    for (int kk = 0; kk < 4; kk++) {
        size_t ao = yb + ((size_t)tile * 4 + kk) * 512 + lane * 8;
        bf16x8 ah = *(const bf16x8*)(yh + ao);
        bf16x8 am = *(const bf16x8*)(ym + ao);
#pragma unroll
        for (int cc = 0; cc < 8; cc++) {
            Frag2 w = ld2(WH, WM, (size_t)(col0 + cc * 16 + l16) * CI_ + kk * 32 + quad * 8);
            acc[cc] = mfma16(am, w.h, acc[cc]);
            acc[cc] = mfma16(ah, w.m, acc[cc]);
            acc[cc] = mfma16(ah, w.h, acc[cc]);
        }
    }
#pragma unroll
    for (int cc = 0; cc < 8; cc++) {
        int c = col0 + cc * 16 + l16;
        float bv = bias[c];
        float s1 = 0.f, s2 = 0.f;
#pragma unroll
        for (int r = 0; r < 4; r++) {
            float v = acc[cc][r] + bv;
            Wyb[(size_t)(row0 + quad * 4 + r) * C_ + c] = v;
            s1 += v;
            s2 += v * v;
        }
        s1 += __shfl_xor(s1, 16, 64); s1 += __shfl_xor(s1, 32, 64);
        s2 += __shfl_xor(s2, 16, 64); s2 += __shfl_xor(s2, 32, 64);
        if (quad == 0) {
            atomicAdd(&stat[c], s1);
            atomicAdd(&stat[C_ + c], s2);
        }
    }
}

__global__ void k_bnfin(const float* __restrict__ stat, const float* __restrict__ gamma,
                        const float* __restrict__ beta, float* __restrict__ sc,
                        float* __restrict__ sh) {
    int c = threadIdx.x;
    const float inv = 1.f / (float)(B_ * NPIX);
    float mean = stat[c] * inv;
    float var = stat[C_ + c] * inv - mean * mean;
    float s = gamma[c] * rsqrtf(var + 1e-5f);
    sc[c] = s;
    sh[c] = beta[c] - mean * s;
}

__global__ void k_final(const float* __restrict__ Wy, const float* __restrict__ x,
                        const float* __restrict__ sc, const float* __restrict__ sh,
                        float* __restrict__ out) {
    __shared__ float tile[32][33];
    int b = blockIdx.z;
    const float* Wyb = Wy + (size_t)b * NPIX * C_;
    const float* xb = x + (size_t)b * C_ * NPIX;
    float* ob = out + (size_t)b * C_ * NPIX;
    int p0 = blockIdx.x * 32, c0 = blockIdx.y * 32;
    for (int i = threadIdx.y; i < 32; i += 8)
        tile[i][threadIdx.x] = Wyb[(size_t)(p0 + i) * C_ + c0 + threadIdx.x];
    __syncthreads();
    for (int i = threadIdx.y; i < 32; i += 8) {
        int c = c0 + i;
        size_t o = (size_t)c * NPIX + p0 + threadIdx.x;
        ob[o] = tile[threadIdx.x][i] * sc[c] + sh[c] + xb[o];
    }
}

extern "C" void kernel_launch(void* const* d_in, const int* in_sizes, int n_in,
                              void* d_out, int out_size, void* d_ws, size_t ws_size,
                              hipStream_t stream) {
    (void)in_sizes; (void)n_in; (void)out_size; (void)ws_size;
    const float* x     = (const float*)d_in[0];
    const float* mask  = (const float*)d_in[1];
    const float* g_w   = (const float*)d_in[2];
    const float* g_b   = (const float*)d_in[3];
    const float* th_w  = (const float*)d_in[4];
    const float* th_b  = (const float*)d_in[5];
    const float* ph_w  = (const float*)d_in[6];
    const float* ph_b  = (const float*)d_in[7];
    const float* W_w   = (const float*)d_in[8];
    const float* W_b   = (const float*)d_in[9];
    const float* gamma = (const float*)d_in[10];
    const float* beta  = (const float*)d_in[11];
    float* out = (float*)d_out;

    char* ws = (char*)d_ws;
    // [0, 25.69MB) timeline: xt -> {gcf, Spart, wS} -> part (pv) -> Wy
    float* xt    = (float*)(ws + 0);
    float* gcf   = (float*)(ws + 0);              // 3,211,264
    float* Spart = (float*)(ws + 4194304);        // 200,704
    float* wS    = (float*)(ws + 5242880);        // 25,088
    float* part  = (float*)(ws + 0);              // 25,690,112 (pv -> ycombine)
    float* Wy    = (float*)(ws + 0);              // 25,690,112 (wconv -> final)
    short* thH   = (short*)(ws + 25690112);       // 6,422,528 (perm)
    short* wwH   = (short*)(ws + 25690112);       // alias: W split after pv
    short* wwM   = wwH + 32768;
    short* thM   = (short*)(ws + 32112640);       // 6,422,528 (perm)
    float* pfull = (float*)(ws + 44957696);       // 12,845,056 (pre-pool)
    short* yH    = (short*)(ws + 44957696);       // alias after pool (perm)
    short* yM    = (short*)(ws + 51380224);       // (perm)
    short* gfull = (short*)(ws + 57802752);       // 6,422,528
    short* thwH  = (short*)(ws + 64225280);       // weight scratch (dead after convs)
    short* thwM  = thwH + 32768;
    short* thwL  = thwM + 32768;
    short* phwH  = thwL + 32768;
    short* phwM  = phwH + 32768;
    short* phwL  = phwM + 32768;
    short* gwH   = phwL + 32768;
    short* gwM   = gwH + 32768;
    short* ptH   = (short*)(ws + 64225280);       // 1,605,632 (perm, after convs)
    short* ptM   = (short*)(ws + 65830912);       // 1,605,632 (perm)
    short* gc    = (short*)(ws + 69042176);       // 1,605,632 (perm, scaled)
    float* stat  = (float*)(ws + 71099392);       // 2,048
    float* sc    = (float*)(ws + 71101440);       // 1,024
    float* sh    = (float*)(ws + 71102464);       // 1,024

    hipMemsetAsync(stat, 0, 2048, stream);

    k_split3<<<128, 256, 0, stream>>>(th_w, thwH, thwM, thwL, CI_ * C_);
    k_split3<<<128, 256, 0, stream>>>(ph_w, phwH, phwM, phwL, CI_ * C_);
    k_split2<<<128, 256, 0, stream>>>(g_w, gwH, gwM, CI_ * C_);

    dim3 tb32(32, 8);
    k_transpose<<<dim3(NPIX / 32, C_ / 32, B_), tb32, 0, stream>>>(mask, xt);
    k_conv6p<<<dim3(NPIX / 16, B_), 128, 0, stream>>>(xt, thwH, thwM, thwL, th_b, thH, thM);

    k_transpose<<<dim3(NPIX / 32, C_ / 32, B_), tb32, 0, stream>>>(x, xt);
    k_convxg<<<dim3(NPIX / 16, B_), 128, 0, stream>>>(xt, phwH, phwM, phwL, gwH, gwM,
                                                      ph_b, g_b, pfull, gfull);

    k_pool<<<dim3(NS * CI_ / 256, B_), 256, 0, stream>>>(pfull, gfull, ptH, ptM, gcf);

    k_stats<<<dim3(NS / 64, NSL, B_), 256, 0, stream>>>(thH, thM, ptH, ptM, Spart);
    k_combine<<<(B_ * NS + 255) / 256, 256, 0, stream>>>(Spart, wS);
    k_gscale<<<(B_ * CI_ * (NS / 8)) / 256, 256, 0, stream>>>(gcf, wS, gc);

    k_pv<<<dim3(NPIX / 64, 2, B_), 256, 0, stream>>>(thH, thM, ptH, ptM, gc, part);

    k_split2<<<128, 256, 0, stream>>>(W_w, wwH, wwM, C_ * CI_);
    k_ycombine<<<(int)(((size_t)B_ * NPIX * CI_ + 255) / 256), 256, 0, stream>>>(part, yH, yM);

    k_wconv3<<<dim3(NPIX / 64, C_ / 128, B_), 256, 0, stream>>>(yH, yM, wwH, wwM, W_b, Wy, stat);
    k_bnfin<<<1, 256, 0, stream>>>(stat, gamma, beta, sc, sh);
    k_final<<<dim3(NPIX / 32, C_ / 32, B_), tb32, 0, stream>>>(Wy, x, sc, sh, out);
}

// Round 7
// 614.588 us; speedup vs baseline: 2.5631x; 1.0370x over previous
//
#include <hip/hip_runtime.h>

// pSGM non-local block, MI355X (round 7: occupancy + conv de-VALU).
// r6: 637us; k_pv 174us @ MfmaUtil 19.7/Occ 25.6 — grid-limited (8.2 waves/CU).
// r7: pv m-split x4 (bf16 partials, 24.5 waves/CU); stats SLICES 14 (21.4 w/CU);
// transpose emits 2-plane bf16 perm(K=256) A so convs are pure load+MFMA
// (5-term A2xW3 for theta/phi — delta-f ~1e-4, same order as passing 3-term).

#define B_ 2
#define C_ 256
#define CI_ 128
#define NPIX 12544
#define NS 3136
#define NSL 14

typedef short bf16x8 __attribute__((ext_vector_type(8)));
typedef float f32x4 __attribute__((ext_vector_type(4)));

__device__ __forceinline__ short f2bf(float f) {
    unsigned u = __float_as_uint(f);
    u = (u + 0x7fff + ((u >> 16) & 1)) >> 16;   // RNE
    return (short)u;
}
__device__ __forceinline__ float bf2f(short s) {
    return __uint_as_float(((unsigned)(unsigned short)s) << 16);
}
__device__ __forceinline__ f32x4 mfma16(bf16x8 a, bf16x8 b, f32x4 c) {
    return __builtin_amdgcn_mfma_f32_16x16x32_bf16(a, b, c, 0, 0, 0);
}
// perm layout, K=128 operands (theta/phi/g/y)
__device__ __forceinline__ size_t pidx(int r, int k) {
    return (size_t)((r >> 4) * 4 + (k >> 5)) * 512 +
           (size_t)(((k >> 3) & 3) * 128 + (r & 15) * 8 + (k & 7));
}
// perm layout, K=256 operands (conv A inputs)
__device__ __forceinline__ size_t pidx256(int r, int k) {
    return (size_t)((r >> 4) * 8 + (k >> 5)) * 512 +
           (size_t)(((k >> 3) & 3) * 128 + (r & 15) * 8 + (k & 7));
}

struct Frag3 { bf16x8 h, m, l; };
struct Frag2 { bf16x8 h, m; };

__device__ __forceinline__ Frag3 ld3(const short* __restrict__ h, const short* __restrict__ m,
                                     const short* __restrict__ l, size_t off) {
    Frag3 f;
    f.h = *(const bf16x8*)(h + off);
    f.m = *(const bf16x8*)(m + off);
    f.l = *(const bf16x8*)(l + off);
    return f;
}
__device__ __forceinline__ Frag2 ld2(const short* __restrict__ h, const short* __restrict__ m,
                                     size_t off) {
    Frag2 f;
    f.h = *(const bf16x8*)(h + off);
    f.m = *(const bf16x8*)(m + off);
    return f;
}
// 5-term conv product: A 2-plane (exact to 2^-17) x W 3-plane, small terms first
__device__ __forceinline__ f32x4 mm5(Frag2 a, Frag3 w, f32x4 acc) {
    acc = mfma16(a.h, w.l, acc);
    acc = mfma16(a.m, w.m, acc);
    acc = mfma16(a.m, w.h, acc);
    acc = mfma16(a.h, w.m, acc);
    acc = mfma16(a.h, w.h, acc);
    return acc;
}
__device__ __forceinline__ f32x4 mm3(Frag2 a, Frag2 b, f32x4 acc) {
    acc = mfma16(a.m, b.h, acc);
    acc = mfma16(a.h, b.m, acc);
    acc = mfma16(a.h, b.h, acc);
    return acc;
}

// ---- weight pre-splits ----
__global__ void k_split3(const float* __restrict__ a, short* __restrict__ oh,
                         short* __restrict__ om, short* __restrict__ ol, int n) {
    int i = blockIdx.x * 256 + threadIdx.x;
    if (i >= n) return;
    float x = a[i];
    unsigned uh = __float_as_uint(x) & 0xffff0000u;
    float r1 = x - __uint_as_float(uh);
    unsigned um = __float_as_uint(r1) & 0xffff0000u;
    float r2 = r1 - __uint_as_float(um);
    oh[i] = (short)(uh >> 16);
    om[i] = (short)(um >> 16);
    ol[i] = f2bf(r2);
}
__global__ void k_split2(const float* __restrict__ a, short* __restrict__ oh,
                         short* __restrict__ om, int n) {
    int i = blockIdx.x * 256 + threadIdx.x;
    if (i >= n) return;
    float x = a[i];
    unsigned uh = __float_as_uint(x) & 0xffff0000u;
    oh[i] = (short)(uh >> 16);
    om[i] = f2bf(x - __uint_as_float(uh));
}

// ---- transpose + 2-plane split into perm(K=256): (C_,NPIX) fp32 -> planes ----
__global__ void k_transpose2p(const float* __restrict__ src, short* __restrict__ oh,
                              short* __restrict__ om) {
    __shared__ float tile[32][33];
    int b = blockIdx.z;
    const float* s = src + (size_t)b * C_ * NPIX;
    size_t ob = (size_t)b * NPIX * C_;
    int p0 = blockIdx.x * 32, c0 = blockIdx.y * 32;
    for (int i = threadIdx.y; i < 32; i += 8)
        tile[i][threadIdx.x] = s[(size_t)(c0 + i) * NPIX + p0 + threadIdx.x];
    __syncthreads();
    for (int i = threadIdx.y; i < 32; i += 8) {
        float v = tile[threadIdx.x][i];
        unsigned uh = __float_as_uint(v) & 0xffff0000u;
        size_t o = ob + pidx256(p0 + i, c0 + threadIdx.x);
        oh[o] = (short)(uh >> 16);
        om[o] = f2bf(v - __uint_as_float(uh));
    }
}

// ---- theta conv: A2(perm256) x W3, 5-term, 2-plane perm out. grid (NPIX/16, B), block 128 ----
__global__ __launch_bounds__(128) void k_conv5(const short* __restrict__ AH,
        const short* __restrict__ AM,
        const short* __restrict__ WH, const short* __restrict__ WM, const short* __restrict__ WL,
        const float* __restrict__ bias, short* __restrict__ oh, short* __restrict__ om) {
    int wid = threadIdx.x >> 6, lane = threadIdx.x & 63;
    int quad = lane >> 4, l16 = lane & 15;
    int b = blockIdx.y;
    size_t ab = (size_t)b * NPIX * C_;
    size_t ob = (size_t)b * NPIX * CI_;
    int rt = blockIdx.x;                        // 16-row tile
    int row0 = rt * 16;
    f32x4 acc[4] = {};
    for (int kt = 0; kt < 8; kt++) {
        Frag2 a = ld2(AH, AM, ab + ((size_t)rt * 8 + kt) * 512 + lane * 8);
#pragma unroll
        for (int c4 = 0; c4 < 4; c4++) {
            int c = (wid * 4 + c4) * 16 + l16;
            Frag3 w = ld3(WH, WM, WL, (size_t)c * C_ + kt * 32 + quad * 8);
            acc[c4] = mm5(a, w, acc[c4]);
        }
    }
#pragma unroll
    for (int c4 = 0; c4 < 4; c4++) {
        int c = (wid * 4 + c4) * 16 + l16;
        float bv = bias[c];
#pragma unroll
        for (int r = 0; r < 4; r++) {
            float v = acc[c4][r] + bv;
            unsigned uh = __float_as_uint(v) & 0xffff0000u;
            size_t o = ob + pidx(row0 + quad * 4 + r, c);
            oh[o] = (short)(uh >> 16);
            om[o] = f2bf(v - __uint_as_float(uh));
        }
    }
}

// ---- fused phi(5-term -> fp32 std) + g(3-term -> bf16 std). grid (NPIX/16, B), block 128 ----
__global__ __launch_bounds__(128) void k_convxg5(const short* __restrict__ AH,
        const short* __restrict__ AM,
        const short* __restrict__ PH, const short* __restrict__ PM, const short* __restrict__ PL,
        const short* __restrict__ GH, const short* __restrict__ GM,
        const float* __restrict__ pbias, const float* __restrict__ gbias,
        float* __restrict__ pfull, short* __restrict__ gout) {
    int wid = threadIdx.x >> 6, lane = threadIdx.x & 63;
    int quad = lane >> 4, l16 = lane & 15;
    int b = blockIdx.y;
    size_t ab = (size_t)b * NPIX * C_;
    float* Pb = pfull + (size_t)b * NPIX * CI_;
    short* Gb = gout + (size_t)b * NPIX * CI_;
    int rt = blockIdx.x;
    int row0 = rt * 16;
    f32x4 accp[4] = {}, accg[4] = {};
    for (int kt = 0; kt < 8; kt++) {
        Frag2 a = ld2(AH, AM, ab + ((size_t)rt * 8 + kt) * 512 + lane * 8);
#pragma unroll
        for (int c4 = 0; c4 < 4; c4++) {
            int c = (wid * 4 + c4) * 16 + l16;
            size_t wo = (size_t)c * C_ + kt * 32 + quad * 8;
            Frag3 wp = ld3(PH, PM, PL, wo);
            accp[c4] = mm5(a, wp, accp[c4]);
            Frag2 wg = ld2(GH, GM, wo);
            accg[c4] = mm3(a, wg, accg[c4]);
        }
    }
#pragma unroll
    for (int c4 = 0; c4 < 4; c4++) {
        int c = (wid * 4 + c4) * 16 + l16;
        float pbv = pbias[c], gbv = gbias[c];
#pragma unroll
        for (int r = 0; r < 4; r++) {
            size_t o = (size_t)(row0 + quad * 4 + r) * CI_ + c;
            Pb[o] = accp[c4][r] + pbv;
            Gb[o] = f2bf(accg[c4][r] + gbv);
        }
    }
}

// ---- pool: pfull fp32 -> phi 2-plane PERM; gfull bf16 -> gcf fp32 (ci, m) ----
__global__ void k_pool(const float* __restrict__ pfull, const short* __restrict__ gfull,
                       short* __restrict__ pth, short* __restrict__ ptm,
                       float* __restrict__ gcf) {
    int b = blockIdx.y;
    int idx = blockIdx.x * 256 + threadIdx.x;       // idx = m*128 + ci
    int ci = idx & 127, m = idx >> 7;
    int t = m / 196, r2i = m - t * 196;
    int h2 = r2i / 14, w2 = r2i - h2 * 14;
    size_t p = (size_t)t * 784 + (size_t)(2 * h2) * 28 + 2 * w2;
    size_t i0 = (size_t)b * NPIX * CI_ + p * CI_ + ci;
    float pv = fmaxf(fmaxf(pfull[i0], pfull[i0 + CI_]),
                     fmaxf(pfull[i0 + 28 * CI_], pfull[i0 + 29 * CI_]));
    unsigned uh = __float_as_uint(pv) & 0xffff0000u;
    size_t ob = (size_t)b * NS * CI_ + pidx(m, ci);
    pth[ob] = (short)(uh >> 16);
    ptm[ob] = f2bf(pv - __uint_as_float(uh));
    float g0 = fmaxf(fmaxf(bf2f(gfull[i0]), bf2f(gfull[i0 + CI_])),
                     fmaxf(bf2f(gfull[i0 + 28 * CI_]), bf2f(gfull[i0 + 29 * CI_])));
    gcf[(size_t)b * NS * CI_ + (size_t)ci * NS + m] = g0;
}

// ---- stats: S[m] = sum_n exp(f-32), 3-term, perm. grid (NS/64, NSL, B), block 256 ----
__global__ __launch_bounds__(256) void k_stats(
        const short* __restrict__ thh, const short* __restrict__ thm,
        const short* __restrict__ phh, const short* __restrict__ phm,
        float* __restrict__ Spart) {
    int wid = threadIdx.x >> 6, lane = threadIdx.x & 63;
    int quad = lane >> 4, l16 = lane & 15;
    int b = blockIdx.z;
    size_t tb = (size_t)b * NPIX * CI_, pb = (size_t)b * NS * CI_;
    int mt = blockIdx.x * 4 + wid;                  // m-tile (16 m)
    Frag2 bf[4];
#pragma unroll
    for (int kk = 0; kk < 4; kk++)
        bf[kk] = ld2(phh, phm, pb + ((size_t)mt * 4 + kk) * 512 + lane * 8);
    float S = 0.f;
    int t_beg = blockIdx.y * (784 / NSL), t_end = t_beg + 784 / NSL;
    for (int t = t_beg; t < t_end; t += 2) {
        f32x4 a0 = {}, a1 = {};
#pragma unroll
        for (int kk = 0; kk < 4; kk++) {
            Frag2 x0 = ld2(thh, thm, tb + ((size_t)t * 4 + kk) * 512 + lane * 8);
            Frag2 x1 = ld2(thh, thm, tb + ((size_t)(t + 1) * 4 + kk) * 512 + lane * 8);
            a0 = mm3(x0, bf[kk], a0);
            a1 = mm3(x1, bf[kk], a1);
        }
        S += __expf(a0[0] - 32.f) + __expf(a0[1] - 32.f) +
             __expf(a0[2] - 32.f) + __expf(a0[3] - 32.f) +
             __expf(a1[0] - 32.f) + __expf(a1[1] - 32.f) +
             __expf(a1[2] - 32.f) + __expf(a1[3] - 32.f);
    }
    S += __shfl_xor(S, 16, 64);
    S += __shfl_xor(S, 32, 64);
    if (quad == 0)
        Spart[((size_t)(b * NSL + blockIdx.y)) * NS + mt * 16 + l16] = S;
}

__global__ void k_combine(const float* __restrict__ Spart, float* __restrict__ wS) {
    int i = blockIdx.x * 256 + threadIdx.x;
    if (i >= B_ * NS) return;
    int b = i / NS, m = i - b * NS;
    float s = 0.f;
#pragma unroll
    for (int sl = 0; sl < NSL; sl++)
        s += Spart[((size_t)(b * NSL + sl)) * NS + m];
    wS[i] = 1.f / s;
}

// ---- g scale into PV-B perm layout ----
__global__ void k_gscale(const float* __restrict__ gcf, const float* __restrict__ wS,
                         short* __restrict__ gc) {
    int i = blockIdx.x * 256 + threadIdx.x;         // B*CI*(NS/8) threads
    int b = i / (CI_ * (NS / 8));
    int rem = i - b * CI_ * (NS / 8);
    int c = rem / (NS / 8);
    int m8 = rem - c * (NS / 8);
    int m = m8 * 8;
    const float* gr = gcf + ((size_t)b * CI_ + c) * NS + m;
    const float* wr = wS + (size_t)b * NS + m;
    short* go = gc + (size_t)b * NS * CI_ + ((size_t)(m8 >> 2) * 8 + (c >> 4)) * 512 +
                (m8 & 3) * 128 + (c & 15) * 8;
#pragma unroll
    for (int j = 0; j < 8; j++) go[j] = f2bf(gr[j] * wr[j]);
}

// ---- PV: f^T 3-term + shfl transform, p~=exp(f-32), 4 m-slices, bf16 partials.
// grid (NPIX/64, 4, B), block 256; wave = 16 n. ----
__global__ __launch_bounds__(256) void k_pv(
        const short* __restrict__ thh, const short* __restrict__ thm,
        const short* __restrict__ phh, const short* __restrict__ phm,
        const short* __restrict__ gp, short* __restrict__ part) {
    int wid = threadIdx.x >> 6, lane = threadIdx.x & 63;
    int quad = lane >> 4, l16 = lane & 15;
    int b = blockIdx.z, slice = blockIdx.y;
    int nt = blockIdx.x * 4 + wid;                  // n-tile (16 n)
    size_t tb = (size_t)b * NPIX * CI_, pb = (size_t)b * NS * CI_;
    const short* gpb = gp + (size_t)b * NS * CI_;
    Frag2 af[4];
#pragma unroll
    for (int kk = 0; kk < 4; kk++)
        af[kk] = ld2(thh, thm, tb + ((size_t)nt * 4 + kk) * 512 + lane * 8);
    f32x4 yacc[8] = {};
    int srcLo = ((2 * quad) & 3) * 16 + l16;
    int srcHi = ((2 * quad + 1) & 3) * 16 + l16;
    bool hiTile = quad >= 2;
    int s_beg = slice * 24 + (slice < 2 ? slice : 2);   // {25,25,24,24} of 98 steps
    int s_end = s_beg + 24 + (slice < 2 ? 1 : 0);
    for (int s = s_beg; s < s_end; s++) {
        f32x4 f0 = {}, f1 = {};
#pragma unroll
        for (int kk = 0; kk < 4; kk++) {
            Frag2 p0 = ld2(phh, phm, pb + ((size_t)(2 * s) * 4 + kk) * 512 + lane * 8);
            Frag2 p1 = ld2(phh, phm, pb + ((size_t)(2 * s + 1) * 4 + kk) * 512 + lane * 8);
            f0 = mm3(p0, af[kk], f0);
            f1 = mm3(p1, af[kk], f1);
        }
        unsigned t0d0 = (unsigned)(unsigned short)f2bf(__expf(f0[0] - 32.f)) |
                        ((unsigned)(unsigned short)f2bf(__expf(f0[1] - 32.f)) << 16);
        unsigned t0d1 = (unsigned)(unsigned short)f2bf(__expf(f0[2] - 32.f)) |
                        ((unsigned)(unsigned short)f2bf(__expf(f0[3] - 32.f)) << 16);
        unsigned t1d0 = (unsigned)(unsigned short)f2bf(__expf(f1[0] - 32.f)) |
                        ((unsigned)(unsigned short)f2bf(__expf(f1[1] - 32.f)) << 16);
        unsigned t1d1 = (unsigned)(unsigned short)f2bf(__expf(f1[2] - 32.f)) |
                        ((unsigned)(unsigned short)f2bf(__expf(f1[3] - 32.f)) << 16);
        unsigned lo0t0 = __shfl(t0d0, srcLo), lo1t0 = __shfl(t0d1, srcLo);
        unsigned hi0t0 = __shfl(t0d0, srcHi), hi1t0 = __shfl(t0d1, srcHi);
        unsigned lo0t1 = __shfl(t1d0, srcLo), lo1t1 = __shfl(t1d1, srcLo);
        unsigned hi0t1 = __shfl(t1d0, srcHi), hi1t1 = __shfl(t1d1, srcHi);
        unsigned pd[4];
        pd[0] = hiTile ? lo0t1 : lo0t0;
        pd[1] = hiTile ? lo1t1 : lo1t0;
        pd[2] = hiTile ? hi0t1 : hi0t0;
        pd[3] = hiTile ? hi1t1 : hi1t0;
        bf16x8 pa;
        __builtin_memcpy(&pa, pd, 16);
#pragma unroll
        for (int cc = 0; cc < 8; cc++) {
            bf16x8 gb = *(const bf16x8*)(gpb + (size_t)s * 4096 + cc * 512 + lane * 8);
            yacc[cc] = mfma16(pa, gb, yacc[cc]);
        }
    }
    short* po = part + ((size_t)slice * B_ + b) * NPIX * CI_;
#pragma unroll
    for (int cc = 0; cc < 8; cc++)
#pragma unroll
        for (int r = 0; r < 4; r++)
            po[pidx(nt * 16 + quad * 4 + r, cc * 16 + l16)] = f2bf(yacc[cc][r]);
}

// ---- combine 4 bf16 y-partials -> 2-plane bf16 (perm order preserved) ----
__global__ void k_ycombine(const short* __restrict__ part, short* __restrict__ yh,
                           short* __restrict__ ym) {
    size_t i = (size_t)blockIdx.x * 256 + threadIdx.x;
    const size_t n = (size_t)B_ * NPIX * CI_;
    if (i >= n) return;
    float v = bf2f(part[i]) + bf2f(part[n + i]) + bf2f(part[2 * n + i]) + bf2f(part[3 * n + i]);
    unsigned uh = __float_as_uint(v) & 0xffff0000u;
    yh[i] = (short)(uh >> 16);
    ym[i] = f2bf(v - __uint_as_float(uh));
}

// ---- W conv (3-term, perm y reads) + fused BN stats. grid (NPIX/64, C_/128, B) ----
__global__ __launch_bounds__(256) void k_wconv3(const short* __restrict__ yh,
        const short* __restrict__ ym, const short* __restrict__ WH,
        const short* __restrict__ WM, const float* __restrict__ bias,
        float* __restrict__ Wy, float* __restrict__ stat) {
    int wid = threadIdx.x >> 6, lane = threadIdx.x & 63;
    int quad = lane >> 4, l16 = lane & 15;
    int b = blockIdx.z;
    size_t yb = (size_t)b * NPIX * CI_;
    float* Wyb = Wy + (size_t)b * NPIX * C_;
    int tile = blockIdx.x * 4 + wid;
    int row0 = tile * 16;
    int col0 = blockIdx.y * 128;
    f32x4 acc[8] = {};
#pragma unroll
    for (int kk = 0; kk < 4; kk++) {
        size_t ao = yb + ((size_t)tile * 4 + kk) * 512 + lane * 8;
        bf16x8 ah = *(const bf16x8*)(yh + ao);
        bf16x8 am = *(const bf16x8*)(ym + ao);
#pragma unroll
        for (int cc = 0; cc < 8; cc++) {
            Frag2 w = ld2(WH, WM, (size_t)(col0 + cc * 16 + l16) * CI_ + kk * 32 + quad * 8);
            acc[cc] = mfma16(am, w.h, acc[cc]);
            acc[cc] = mfma16(ah, w.m, acc[cc]);
            acc[cc] = mfma16(ah, w.h, acc[cc]);
        }
    }
#pragma unroll
    for (int cc = 0; cc < 8; cc++) {
        int c = col0 + cc * 16 + l16;
        float bv = bias[c];
        float s1 = 0.f, s2 = 0.f;
#pragma unroll
        for (int r = 0; r < 4; r++) {
            float v = acc[cc][r] + bv;
            Wyb[(size_t)(row0 + quad * 4 + r) * C_ + c] = v;
            s1 += v;
            s2 += v * v;
        }
        s1 += __shfl_xor(s1, 16, 64); s1 += __shfl_xor(s1, 32, 64);
        s2 += __shfl_xor(s2, 16, 64); s2 += __shfl_xor(s2, 32, 64);
        if (quad == 0) {
            atomicAdd(&stat[c], s1);
            atomicAdd(&stat[C_ + c], s2);
        }
    }
}

__global__ void k_bnfin(const float* __restrict__ stat, const float* __restrict__ gamma,
                        const float* __restrict__ beta, float* __restrict__ sc,
                        float* __restrict__ sh) {
    int c = threadIdx.x;
    const float inv = 1.f / (float)(B_ * NPIX);
    float mean = stat[c] * inv;
    float var = stat[C_ + c] * inv - mean * mean;
    float s = gamma[c] * rsqrtf(var + 1e-5f);
    sc[c] = s;
    sh[c] = beta[c] - mean * s;
}

__global__ void k_final(const float* __restrict__ Wy, const float* __restrict__ x,
                        const float* __restrict__ sc, const float* __restrict__ sh,
                        float* __restrict__ out) {
    __shared__ float tile[32][33];
    int b = blockIdx.z;
    const float* Wyb = Wy + (size_t)b * NPIX * C_;
    const float* xb = x + (size_t)b * C_ * NPIX;
    float* ob = out + (size_t)b * C_ * NPIX;
    int p0 = blockIdx.x * 32, c0 = blockIdx.y * 32;
    for (int i = threadIdx.y; i < 32; i += 8)
        tile[i][threadIdx.x] = Wyb[(size_t)(p0 + i) * C_ + c0 + threadIdx.x];
    __syncthreads();
    for (int i = threadIdx.y; i < 32; i += 8) {
        int c = c0 + i;
        size_t o = (size_t)c * NPIX + p0 + threadIdx.x;
        ob[o] = tile[threadIdx.x][i] * sc[c] + sh[c] + xb[o];
    }
}

extern "C" void kernel_launch(void* const* d_in, const int* in_sizes, int n_in,
                              void* d_out, int out_size, void* d_ws, size_t ws_size,
                              hipStream_t stream) {
    (void)in_sizes; (void)n_in; (void)out_size; (void)ws_size;
    const float* x     = (const float*)d_in[0];
    const float* mask  = (const float*)d_in[1];
    const float* g_w   = (const float*)d_in[2];
    const float* g_b   = (const float*)d_in[3];
    const float* th_w  = (const float*)d_in[4];
    const float* th_b  = (const float*)d_in[5];
    const float* ph_w  = (const float*)d_in[6];
    const float* ph_b  = (const float*)d_in[7];
    const float* W_w   = (const float*)d_in[8];
    const float* W_b   = (const float*)d_in[9];
    const float* gamma = (const float*)d_in[10];
    const float* beta  = (const float*)d_in[11];
    float* out = (float*)d_out;

    char* ws = (char*)d_ws;
    // [0, 25.69MB) timeline: A-planes (2x12.85) -> {gcf,Spart,wS} -> part (4x6.42 bf16) -> Wy
    short* AH    = (short*)(ws + 0);              // 12,845,056
    short* AM    = (short*)(ws + 12845056);       // 12,845,056
    float* gcf   = (float*)(ws + 0);              // 3,211,264 (pool -> gscale)
    float* Spart = (float*)(ws + 4194304);        // 351,232
    float* wS    = (float*)(ws + 5242880);        // 25,088
    short* part  = (short*)(ws + 0);              // 25,690,112 (pv -> ycombine)
    float* Wy    = (float*)(ws + 0);              // 25,690,112 (wconv -> final)
    short* thH   = (short*)(ws + 25690112);       // 6,422,528 (perm)
    short* thM   = (short*)(ws + 32112640);       // 6,422,528 (perm)
    short* wwH   = (short*)(ws + 38535168);       // 65,536 (free gap; W split upfront)
    short* wwM   = wwH + 32768;
    float* pfull = (float*)(ws + 44957696);       // 12,845,056 (pre-pool)
    short* yH    = (short*)(ws + 44957696);       // alias after pool (perm)
    short* yM    = (short*)(ws + 51380224);       // (perm)
    short* gfull = (short*)(ws + 57802752);       // 6,422,528
    short* thwH  = (short*)(ws + 64225280);       // weight scratch (dead after convs)
    short* thwM  = thwH + 32768;
    short* thwL  = thwM + 32768;
    short* phwH  = thwL + 32768;
    short* phwM  = phwH + 32768;
    short* phwL  = phwM + 32768;
    short* gwH   = phwL + 32768;
    short* gwM   = gwH + 32768;
    short* ptH   = (short*)(ws + 64225280);       // 1,605,632 (perm, after convs)
    short* ptM   = (short*)(ws + 65830912);       // 1,605,632 (perm)
    short* gc    = (short*)(ws + 69042176);       // 1,605,632 (perm, scaled)
    float* stat  = (float*)(ws + 71099392);       // 2,048
    float* sc    = (float*)(ws + 71101440);       // 1,024
    float* sh    = (float*)(ws + 71102464);       // 1,024

    hipMemsetAsync(stat, 0, 2048, stream);

    k_split3<<<128, 256, 0, stream>>>(th_w, thwH, thwM, thwL, CI_ * C_);
    k_split3<<<128, 256, 0, stream>>>(ph_w, phwH, phwM, phwL, CI_ * C_);
    k_split2<<<128, 256, 0, stream>>>(g_w, gwH, gwM, CI_ * C_);
    k_split2<<<128, 256, 0, stream>>>(W_w, wwH, wwM, C_ * CI_);

    dim3 tb32(32, 8);
    k_transpose2p<<<dim3(NPIX / 32, C_ / 32, B_), tb32, 0, stream>>>(mask, AH, AM);
    k_conv5<<<dim3(NPIX / 16, B_), 128, 0, stream>>>(AH, AM, thwH, thwM, thwL, th_b, thH, thM);

    k_transpose2p<<<dim3(NPIX / 32, C_ / 32, B_), tb32, 0, stream>>>(x, AH, AM);
    k_convxg5<<<dim3(NPIX / 16, B_), 128, 0, stream>>>(AH, AM, phwH, phwM, phwL, gwH, gwM,
                                                       ph_b, g_b, pfull, gfull);

    k_pool<<<dim3(NS * CI_ / 256, B_), 256, 0, stream>>>(pfull, gfull, ptH, ptM, gcf);

    k_stats<<<dim3(NS / 64, NSL, B_), 256, 0, stream>>>(thH, thM, ptH, ptM, Spart);
    k_combine<<<(B_ * NS + 255) / 256, 256, 0, stream>>>(Spart, wS);
    k_gscale<<<(B_ * CI_ * (NS / 8)) / 256, 256, 0, stream>>>(gcf, wS, gc);

    k_pv<<<dim3(NPIX / 64, 4, B_), 256, 0, stream>>>(thH, thM, ptH, ptM, gc, part);

    k_ycombine<<<(int)(((size_t)B_ * NPIX * CI_ + 255) / 256), 256, 0, stream>>>(part, yH, yM);

    k_wconv3<<<dim3(NPIX / 64, C_ / 128, B_), 256, 0, stream>>>(yH, yM, wwH, wwM, W_b, Wy, stat);
    k_bnfin<<<1, 256, 0, stream>>>(stat, gamma, beta, sc, sh);
    k_final<<<dim3(NPIX / 32, C_ / 32, B_), tb32, 0, stream>>>(Wy, x, sc, sh, out);
}

// Round 9
// 530.358 us; speedup vs baseline: 2.9701x; 1.1588x over previous
//
#include <hip/hip_runtime.h>

// pSGM non-local block, MI355X (round 9 = round 8 with the divergent-shuffle bug fixed).
// r8 FAILED (absmax 74.8): mk_pa wrapped __shfl in ternaries on hiTile (divergent per
// quad) -> compiler branches -> ds_bpermute under partial exec pulls from inactive
// lanes -> zeros in p~. Fix: execute all 8 shuffles unconditionally (all lanes active),
// select afterwards (v_cndmask), exactly r7's working pattern.
// Structure (from r8): fp32 PV partials (m-slice x2) restore r6 precision; pv waves
// cover 32n and stats waves 32m (halve L2 stream per MFMA); convs 2 row-tiles/block;
// merged weight split.

#define B_ 2
#define C_ 256
#define CI_ 128
#define NPIX 12544
#define NS 3136
#define NSL 14

typedef short bf16x8 __attribute__((ext_vector_type(8)));
typedef float f32x4 __attribute__((ext_vector_type(4)));

__device__ __forceinline__ short f2bf(float f) {
    unsigned u = __float_as_uint(f);
    u = (u + 0x7fff + ((u >> 16) & 1)) >> 16;   // RNE
    return (short)u;
}
__device__ __forceinline__ float bf2f(short s) {
    return __uint_as_float(((unsigned)(unsigned short)s) << 16);
}
__device__ __forceinline__ f32x4 mfma16(bf16x8 a, bf16x8 b, f32x4 c) {
    return __builtin_amdgcn_mfma_f32_16x16x32_bf16(a, b, c, 0, 0, 0);
}
// perm layout, K=128 operands (theta/phi/g/y): frag-contiguous 1KB wave-loads
__device__ __forceinline__ size_t pidx(int r, int k) {
    return (size_t)((r >> 4) * 4 + (k >> 5)) * 512 +
           (size_t)(((k >> 3) & 3) * 128 + (r & 15) * 8 + (k & 7));
}
// perm layout, K=256 operands (conv A inputs)
__device__ __forceinline__ size_t pidx256(int r, int k) {
    return (size_t)((r >> 4) * 8 + (k >> 5)) * 512 +
           (size_t)(((k >> 3) & 3) * 128 + (r & 15) * 8 + (k & 7));
}

struct Frag3 { bf16x8 h, m, l; };
struct Frag2 { bf16x8 h, m; };

__device__ __forceinline__ Frag3 ld3(const short* __restrict__ h, const short* __restrict__ m,
                                     const short* __restrict__ l, size_t off) {
    Frag3 f;
    f.h = *(const bf16x8*)(h + off);
    f.m = *(const bf16x8*)(m + off);
    f.l = *(const bf16x8*)(l + off);
    return f;
}
__device__ __forceinline__ Frag2 ld2(const short* __restrict__ h, const short* __restrict__ m,
                                     size_t off) {
    Frag2 f;
    f.h = *(const bf16x8*)(h + off);
    f.m = *(const bf16x8*)(m + off);
    return f;
}
// 5-term conv product: A 2-plane (exact to 2^-17) x W 3-plane
__device__ __forceinline__ f32x4 mm5(Frag2 a, Frag3 w, f32x4 acc) {
    acc = mfma16(a.h, w.l, acc);
    acc = mfma16(a.m, w.m, acc);
    acc = mfma16(a.m, w.h, acc);
    acc = mfma16(a.h, w.m, acc);
    acc = mfma16(a.h, w.h, acc);
    return acc;
}
__device__ __forceinline__ f32x4 mm3(Frag2 a, Frag2 b, f32x4 acc) {
    acc = mfma16(a.m, b.h, acc);
    acc = mfma16(a.h, b.m, acc);
    acc = mfma16(a.h, b.h, acc);
    return acc;
}
// build PV A-frag from f^T tile pair. ALL shuffles unconditional (full exec mask);
// the hiTile select happens on materialized registers only (v_cndmask, no branch).
__device__ __forceinline__ bf16x8 mk_pa(f32x4 f0, f32x4 f1, int srcLo, int srcHi, bool hiTile) {
    unsigned t0d0 = (unsigned)(unsigned short)f2bf(__expf(f0[0] - 32.f)) |
                    ((unsigned)(unsigned short)f2bf(__expf(f0[1] - 32.f)) << 16);
    unsigned t0d1 = (unsigned)(unsigned short)f2bf(__expf(f0[2] - 32.f)) |
                    ((unsigned)(unsigned short)f2bf(__expf(f0[3] - 32.f)) << 16);
    unsigned t1d0 = (unsigned)(unsigned short)f2bf(__expf(f1[0] - 32.f)) |
                    ((unsigned)(unsigned short)f2bf(__expf(f1[1] - 32.f)) << 16);
    unsigned t1d1 = (unsigned)(unsigned short)f2bf(__expf(f1[2] - 32.f)) |
                    ((unsigned)(unsigned short)f2bf(__expf(f1[3] - 32.f)) << 16);
    unsigned lo0t0 = __shfl(t0d0, srcLo), lo1t0 = __shfl(t0d1, srcLo);
    unsigned hi0t0 = __shfl(t0d0, srcHi), hi1t0 = __shfl(t0d1, srcHi);
    unsigned lo0t1 = __shfl(t1d0, srcLo), lo1t1 = __shfl(t1d1, srcLo);
    unsigned hi0t1 = __shfl(t1d0, srcHi), hi1t1 = __shfl(t1d1, srcHi);
    unsigned pd[4];
    pd[0] = hiTile ? lo0t1 : lo0t0;
    pd[1] = hiTile ? lo1t1 : lo1t0;
    pd[2] = hiTile ? hi0t1 : hi0t0;
    pd[3] = hiTile ? hi1t1 : hi1t0;
    bf16x8 pa;
    __builtin_memcpy(&pa, pd, 16);
    return pa;
}

// ---- merged weight pre-split: theta/phi 3-plane, g/W 2-plane ----
__global__ void k_splitw(const float* __restrict__ thw, const float* __restrict__ phw,
                         const float* __restrict__ gw, const float* __restrict__ Ww,
                         short* __restrict__ thwH, short* __restrict__ thwM, short* __restrict__ thwL,
                         short* __restrict__ phwH, short* __restrict__ phwM, short* __restrict__ phwL,
                         short* __restrict__ gwH, short* __restrict__ gwM,
                         short* __restrict__ wwH, short* __restrict__ wwM) {
    int i = blockIdx.x * 256 + threadIdx.x;
    int which = i >> 15, j = i & 32767;
    if (which == 0) {
        float x = thw[j];
        unsigned uh = __float_as_uint(x) & 0xffff0000u;
        float r1 = x - __uint_as_float(uh);
        unsigned um = __float_as_uint(r1) & 0xffff0000u;
        thwH[j] = (short)(uh >> 16);
        thwM[j] = (short)(um >> 16);
        thwL[j] = f2bf(r1 - __uint_as_float(um));
    } else if (which == 1) {
        float x = phw[j];
        unsigned uh = __float_as_uint(x) & 0xffff0000u;
        float r1 = x - __uint_as_float(uh);
        unsigned um = __float_as_uint(r1) & 0xffff0000u;
        phwH[j] = (short)(uh >> 16);
        phwM[j] = (short)(um >> 16);
        phwL[j] = f2bf(r1 - __uint_as_float(um));
    } else if (which == 2) {
        float x = gw[j];
        unsigned uh = __float_as_uint(x) & 0xffff0000u;
        gwH[j] = (short)(uh >> 16);
        gwM[j] = f2bf(x - __uint_as_float(uh));
    } else {
        float x = Ww[j];
        unsigned uh = __float_as_uint(x) & 0xffff0000u;
        wwH[j] = (short)(uh >> 16);
        wwM[j] = f2bf(x - __uint_as_float(uh));
    }
}

// ---- transpose + 2-plane split into perm(K=256) ----
__global__ void k_transpose2p(const float* __restrict__ src, short* __restrict__ oh,
                              short* __restrict__ om) {
    __shared__ float tile[32][33];
    int b = blockIdx.z;
    const float* s = src + (size_t)b * C_ * NPIX;
    size_t ob = (size_t)b * NPIX * C_;
    int p0 = blockIdx.x * 32, c0 = blockIdx.y * 32;
    for (int i = threadIdx.y; i < 32; i += 8)
        tile[i][threadIdx.x] = s[(size_t)(c0 + i) * NPIX + p0 + threadIdx.x];
    __syncthreads();
    for (int i = threadIdx.y; i < 32; i += 8) {
        float v = tile[threadIdx.x][i];
        unsigned uh = __float_as_uint(v) & 0xffff0000u;
        size_t o = ob + pidx256(p0 + i, c0 + threadIdx.x);
        oh[o] = (short)(uh >> 16);
        om[o] = f2bf(v - __uint_as_float(uh));
    }
}

// ---- theta conv: 5-term, 2 row-tiles/block. grid (NPIX/32, B), block 128 ----
__global__ __launch_bounds__(128, 2) void k_conv5(const short* __restrict__ AH,
        const short* __restrict__ AM,
        const short* __restrict__ WH, const short* __restrict__ WM, const short* __restrict__ WL,
        const float* __restrict__ bias, short* __restrict__ oh, short* __restrict__ om) {
    int wid = threadIdx.x >> 6, lane = threadIdx.x & 63;
    int quad = lane >> 4, l16 = lane & 15;
    int b = blockIdx.y;
    size_t ab = (size_t)b * NPIX * C_;
    size_t ob = (size_t)b * NPIX * CI_;
    int rt0 = blockIdx.x * 2;
    f32x4 acc[2][4] = {};
    for (int kt = 0; kt < 8; kt++) {
        Frag2 a0 = ld2(AH, AM, ab + ((size_t)rt0 * 8 + kt) * 512 + lane * 8);
        Frag2 a1 = ld2(AH, AM, ab + ((size_t)(rt0 + 1) * 8 + kt) * 512 + lane * 8);
#pragma unroll
        for (int c4 = 0; c4 < 4; c4++) {
            int c = (wid * 4 + c4) * 16 + l16;
            Frag3 w = ld3(WH, WM, WL, (size_t)c * C_ + kt * 32 + quad * 8);
            acc[0][c4] = mm5(a0, w, acc[0][c4]);
            acc[1][c4] = mm5(a1, w, acc[1][c4]);
        }
    }
#pragma unroll
    for (int t2 = 0; t2 < 2; t2++)
#pragma unroll
        for (int c4 = 0; c4 < 4; c4++) {
            int c = (wid * 4 + c4) * 16 + l16;
            float bv = bias[c];
#pragma unroll
            for (int r = 0; r < 4; r++) {
                float v = acc[t2][c4][r] + bv;
                unsigned uh = __float_as_uint(v) & 0xffff0000u;
                size_t o = ob + pidx((rt0 + t2) * 16 + quad * 4 + r, c);
                oh[o] = (short)(uh >> 16);
                om[o] = f2bf(v - __uint_as_float(uh));
            }
        }
}

// ---- fused phi(5-term->fp32) + g(3-term->bf16), 2 row-tiles/block ----
__global__ __launch_bounds__(128, 2) void k_convxg5(const short* __restrict__ AH,
        const short* __restrict__ AM,
        const short* __restrict__ PH, const short* __restrict__ PM, const short* __restrict__ PL,
        const short* __restrict__ GH, const short* __restrict__ GM,
        const float* __restrict__ pbias, const float* __restrict__ gbias,
        float* __restrict__ pfull, short* __restrict__ gout) {
    int wid = threadIdx.x >> 6, lane = threadIdx.x & 63;
    int quad = lane >> 4, l16 = lane & 15;
    int b = blockIdx.y;
    size_t ab = (size_t)b * NPIX * C_;
    float* Pb = pfull + (size_t)b * NPIX * CI_;
    short* Gb = gout + (size_t)b * NPIX * CI_;
    int rt0 = blockIdx.x * 2;
    f32x4 accp[2][4] = {}, accg[2][4] = {};
    for (int kt = 0; kt < 8; kt++) {
        Frag2 a0 = ld2(AH, AM, ab + ((size_t)rt0 * 8 + kt) * 512 + lane * 8);
        Frag2 a1 = ld2(AH, AM, ab + ((size_t)(rt0 + 1) * 8 + kt) * 512 + lane * 8);
#pragma unroll
        for (int c4 = 0; c4 < 4; c4++) {
            int c = (wid * 4 + c4) * 16 + l16;
            size_t wo = (size_t)c * C_ + kt * 32 + quad * 8;
            Frag3 wp = ld3(PH, PM, PL, wo);
            accp[0][c4] = mm5(a0, wp, accp[0][c4]);
            accp[1][c4] = mm5(a1, wp, accp[1][c4]);
            Frag2 wg = ld2(GH, GM, wo);
            accg[0][c4] = mm3(a0, wg, accg[0][c4]);
            accg[1][c4] = mm3(a1, wg, accg[1][c4]);
        }
    }
#pragma unroll
    for (int t2 = 0; t2 < 2; t2++)
#pragma unroll
        for (int c4 = 0; c4 < 4; c4++) {
            int c = (wid * 4 + c4) * 16 + l16;
            float pbv = pbias[c], gbv = gbias[c];
#pragma unroll
            for (int r = 0; r < 4; r++) {
                size_t o = (size_t)((rt0 + t2) * 16 + quad * 4 + r) * CI_ + c;
                Pb[o] = accp[t2][c4][r] + pbv;
                Gb[o] = f2bf(accg[t2][c4][r] + gbv);
            }
        }
}

// ---- pool: pfull fp32 -> phi 2-plane PERM; gfull bf16 -> gcf fp32 (ci, m) ----
__global__ void k_pool(const float* __restrict__ pfull, const short* __restrict__ gfull,
                       short* __restrict__ pth, short* __restrict__ ptm,
                       float* __restrict__ gcf) {
    int b = blockIdx.y;
    int idx = blockIdx.x * 256 + threadIdx.x;       // idx = m*128 + ci
    int ci = idx & 127, m = idx >> 7;
    int t = m / 196, r2i = m - t * 196;
    int h2 = r2i / 14, w2 = r2i - h2 * 14;
    size_t p = (size_t)t * 784 + (size_t)(2 * h2) * 28 + 2 * w2;
    size_t i0 = (size_t)b * NPIX * CI_ + p * CI_ + ci;
    float pv = fmaxf(fmaxf(pfull[i0], pfull[i0 + CI_]),
                     fmaxf(pfull[i0 + 28 * CI_], pfull[i0 + 29 * CI_]));
    unsigned uh = __float_as_uint(pv) & 0xffff0000u;
    size_t ob = (size_t)b * NS * CI_ + pidx(m, ci);
    pth[ob] = (short)(uh >> 16);
    ptm[ob] = f2bf(pv - __uint_as_float(uh));
    float g0 = fmaxf(fmaxf(bf2f(gfull[i0]), bf2f(gfull[i0 + CI_])),
                     fmaxf(bf2f(gfull[i0 + 28 * CI_]), bf2f(gfull[i0 + 29 * CI_])));
    gcf[(size_t)b * NS * CI_ + (size_t)ci * NS + m] = g0;
}

// ---- stats: S[m]=sum_n exp(f-32); wave covers 32m (2 phi frag sets).
// grid (NS/64, NSL, B), block 128 ----
__global__ __launch_bounds__(128, 2) void k_stats(
        const short* __restrict__ thh, const short* __restrict__ thm,
        const short* __restrict__ phh, const short* __restrict__ phm,
        float* __restrict__ Spart) {
    int wid = threadIdx.x >> 6, lane = threadIdx.x & 63;
    int quad = lane >> 4, l16 = lane & 15;
    int b = blockIdx.z;
    size_t tb = (size_t)b * NPIX * CI_, pb = (size_t)b * NS * CI_;
    int mtA = blockIdx.x * 4 + wid * 2;             // m-tiles mtA, mtA+1
    Frag2 bfA[4], bfB[4];
#pragma unroll
    for (int kk = 0; kk < 4; kk++) {
        bfA[kk] = ld2(phh, phm, pb + ((size_t)mtA * 4 + kk) * 512 + lane * 8);
        bfB[kk] = ld2(phh, phm, pb + ((size_t)(mtA + 1) * 4 + kk) * 512 + lane * 8);
    }
    float SA = 0.f, SB = 0.f;
    int t_beg = blockIdx.y * (784 / NSL), t_end = t_beg + 784 / NSL;
    for (int t = t_beg; t < t_end; t += 2) {
        f32x4 aA0 = {}, aA1 = {}, aB0 = {}, aB1 = {};
#pragma unroll
        for (int kk = 0; kk < 4; kk++) {
            Frag2 x0 = ld2(thh, thm, tb + ((size_t)t * 4 + kk) * 512 + lane * 8);
            Frag2 x1 = ld2(thh, thm, tb + ((size_t)(t + 1) * 4 + kk) * 512 + lane * 8);
            aA0 = mm3(x0, bfA[kk], aA0);
            aA1 = mm3(x1, bfA[kk], aA1);
            aB0 = mm3(x0, bfB[kk], aB0);
            aB1 = mm3(x1, bfB[kk], aB1);
        }
        SA += __expf(aA0[0] - 32.f) + __expf(aA0[1] - 32.f) +
              __expf(aA0[2] - 32.f) + __expf(aA0[3] - 32.f) +
              __expf(aA1[0] - 32.f) + __expf(aA1[1] - 32.f) +
              __expf(aA1[2] - 32.f) + __expf(aA1[3] - 32.f);
        SB += __expf(aB0[0] - 32.f) + __expf(aB0[1] - 32.f) +
              __expf(aB0[2] - 32.f) + __expf(aB0[3] - 32.f) +
              __expf(aB1[0] - 32.f) + __expf(aB1[1] - 32.f) +
              __expf(aB1[2] - 32.f) + __expf(aB1[3] - 32.f);
    }
    SA += __shfl_xor(SA, 16, 64); SA += __shfl_xor(SA, 32, 64);
    SB += __shfl_xor(SB, 16, 64); SB += __shfl_xor(SB, 32, 64);
    if (quad == 0) {
        size_t o = ((size_t)(b * NSL + blockIdx.y)) * NS;
        Spart[o + mtA * 16 + l16] = SA;
        Spart[o + (mtA + 1) * 16 + l16] = SB;
    }
}

__global__ void k_combine(const float* __restrict__ Spart, float* __restrict__ wS) {
    int i = blockIdx.x * 256 + threadIdx.x;
    if (i >= B_ * NS) return;
    int b = i / NS, m = i - b * NS;
    float s = 0.f;
#pragma unroll
    for (int sl = 0; sl < NSL; sl++)
        s += Spart[((size_t)(b * NSL + sl)) * NS + m];
    wS[i] = 1.f / s;
}

// ---- g scale into PV-B perm layout ----
__global__ void k_gscale(const float* __restrict__ gcf, const float* __restrict__ wS,
                         short* __restrict__ gc) {
    int i = blockIdx.x * 256 + threadIdx.x;         // B*CI*(NS/8) threads
    int b = i / (CI_ * (NS / 8));
    int rem = i - b * CI_ * (NS / 8);
    int c = rem / (NS / 8);
    int m8 = rem - c * (NS / 8);
    int m = m8 * 8;
    const float* gr = gcf + ((size_t)b * CI_ + c) * NS + m;
    const float* wr = wS + (size_t)b * NS + m;
    short* go = gc + (size_t)b * NS * CI_ + ((size_t)(m8 >> 2) * 8 + (c >> 4)) * 512 +
                (m8 & 3) * 128 + (c & 15) * 8;
#pragma unroll
    for (int j = 0; j < 8; j++) go[j] = f2bf(gr[j] * wr[j]);
}

// ---- PV: wave covers 32n (2 theta frag sets + 2 acc sets), m-slice x2, fp32 partials.
// grid (NPIX/64, 2, B), block 128 ----
__global__ __launch_bounds__(128, 2) void k_pv(
        const short* __restrict__ thh, const short* __restrict__ thm,
        const short* __restrict__ phh, const short* __restrict__ phm,
        const short* __restrict__ gp, float* __restrict__ part) {
    int wid = threadIdx.x >> 6, lane = threadIdx.x & 63;
    int quad = lane >> 4, l16 = lane & 15;
    int b = blockIdx.z, slice = blockIdx.y;
    int ntA = blockIdx.x * 4 + wid * 2;             // n-tiles ntA, ntA+1
    size_t tb = (size_t)b * NPIX * CI_, pb = (size_t)b * NS * CI_;
    const short* gpb = gp + (size_t)b * NS * CI_;
    Frag2 afA[4], afB[4];
#pragma unroll
    for (int kk = 0; kk < 4; kk++) {
        afA[kk] = ld2(thh, thm, tb + ((size_t)ntA * 4 + kk) * 512 + lane * 8);
        afB[kk] = ld2(thh, thm, tb + ((size_t)(ntA + 1) * 4 + kk) * 512 + lane * 8);
    }
    f32x4 yaccA[8] = {}, yaccB[8] = {};
    int srcLo = ((2 * quad) & 3) * 16 + l16;
    int srcHi = ((2 * quad + 1) & 3) * 16 + l16;
    bool hiTile = quad >= 2;
    int s_beg = slice * 49, s_end = s_beg + 49;
    for (int s = s_beg; s < s_end; s++) {
        f32x4 fA0 = {}, fA1 = {}, fB0 = {}, fB1 = {};
#pragma unroll
        for (int kk = 0; kk < 4; kk++) {
            Frag2 p0 = ld2(phh, phm, pb + ((size_t)(2 * s) * 4 + kk) * 512 + lane * 8);
            Frag2 p1 = ld2(phh, phm, pb + ((size_t)(2 * s + 1) * 4 + kk) * 512 + lane * 8);
            fA0 = mm3(p0, afA[kk], fA0);
            fA1 = mm3(p1, afA[kk], fA1);
            fB0 = mm3(p0, afB[kk], fB0);
            fB1 = mm3(p1, afB[kk], fB1);
        }
        bf16x8 paA = mk_pa(fA0, fA1, srcLo, srcHi, hiTile);
        bf16x8 paB = mk_pa(fB0, fB1, srcLo, srcHi, hiTile);
#pragma unroll
        for (int cc = 0; cc < 8; cc++) {
            bf16x8 gb = *(const bf16x8*)(gpb + (size_t)s * 4096 + cc * 512 + lane * 8);
            yaccA[cc] = mfma16(paA, gb, yaccA[cc]);
            yaccB[cc] = mfma16(paB, gb, yaccB[cc]);
        }
    }
    float* po = part + ((size_t)(slice * B_ + b)) * NPIX * CI_;
#pragma unroll
    for (int cc = 0; cc < 8; cc++)
#pragma unroll
        for (int r = 0; r < 4; r++) {
            po[pidx(ntA * 16 + quad * 4 + r, cc * 16 + l16)] = yaccA[cc][r];
            po[pidx((ntA + 1) * 16 + quad * 4 + r, cc * 16 + l16)] = yaccB[cc][r];
        }
}

// ---- combine 2 fp32 y-partials -> 2-plane bf16 (perm order preserved) ----
__global__ void k_ycombine(const float* __restrict__ part, short* __restrict__ yh,
                           short* __restrict__ ym) {
    size_t i = (size_t)blockIdx.x * 256 + threadIdx.x;
    const size_t n = (size_t)B_ * NPIX * CI_;
    if (i >= n) return;
    float v = part[i] + part[n + i];
    unsigned uh = __float_as_uint(v) & 0xffff0000u;
    yh[i] = (short)(uh >> 16);
    ym[i] = f2bf(v - __uint_as_float(uh));
}

// ---- W conv (3-term, perm y reads) + fused BN stats. grid (NPIX/64, C_/128, B) ----
__global__ __launch_bounds__(256) void k_wconv3(const short* __restrict__ yh,
        const short* __restrict__ ym, const short* __restrict__ WH,
        const short* __restrict__ WM, const float* __restrict__ bias,
        float* __restrict__ Wy, float* __restrict__ stat) {
    int wid = threadIdx.x >> 6, lane = threadIdx.x & 63;
    int quad = lane >> 4, l16 = lane & 15;
    int b = blockIdx.z;
    size_t yb = (size_t)b * NPIX * CI_;
    float* Wyb = Wy + (size_t)b * NPIX * C_;
    int tile = blockIdx.x * 4 + wid;
    int row0 = tile * 16;
    int col0 = blockIdx.y * 128;
    f32x4 acc[8] = {};
#pragma unroll
    for (int kk = 0; kk < 4; kk++) {
        size_t ao = yb + ((size_t)tile * 4 + kk) * 512 + lane * 8;
        bf16x8 ah = *(const bf16x8*)(yh + ao);
        bf16x8 am = *(const bf16x8*)(ym + ao);
#pragma unroll
        for (int cc = 0; cc < 8; cc++) {
            Frag2 w = ld2(WH, WM, (size_t)(col0 + cc * 16 + l16) * CI_ + kk * 32 + quad * 8);
            acc[cc] = mfma16(am, w.h, acc[cc]);
            acc[cc] = mfma16(ah, w.m, acc[cc]);
            acc[cc] = mfma16(ah, w.h, acc[cc]);
        }
    }
#pragma unroll
    for (int cc = 0; cc < 8; cc++) {
        int c = col0 + cc * 16 + l16;
        float bv = bias[c];
        float s1 = 0.f, s2 = 0.f;
#pragma unroll
        for (int r = 0; r < 4; r++) {
            float v = acc[cc][r] + bv;
            Wyb[(size_t)(row0 + quad * 4 + r) * C_ + c] = v;
            s1 += v;
            s2 += v * v;
        }
        s1 += __shfl_xor(s1, 16, 64); s1 += __shfl_xor(s1, 32, 64);
        s2 += __shfl_xor(s2, 16, 64); s2 += __shfl_xor(s2, 32, 64);
        if (quad == 0) {
            atomicAdd(&stat[c], s1);
            atomicAdd(&stat[C_ + c], s2);
        }
    }
}

__global__ void k_bnfin(const float* __restrict__ stat, const float* __restrict__ gamma,
                        const float* __restrict__ beta, float* __restrict__ sc,
                        float* __restrict__ sh) {
    int c = threadIdx.x;
    const float inv = 1.f / (float)(B_ * NPIX);
    float mean = stat[c] * inv;
    float var = stat[C_ + c] * inv - mean * mean;
    float s = gamma[c] * rsqrtf(var + 1e-5f);
    sc[c] = s;
    sh[c] = beta[c] - mean * s;
}

__global__ void k_final(const float* __restrict__ Wy, const float* __restrict__ x,
                        const float* __restrict__ sc, const float* __restrict__ sh,
                        float* __restrict__ out) {
    __shared__ float tile[32][33];
    int b = blockIdx.z;
    const float* Wyb = Wy + (size_t)b * NPIX * C_;
    const float* xb = x + (size_t)b * C_ * NPIX;
    float* ob = out + (size_t)b * C_ * NPIX;
    int p0 = blockIdx.x * 32, c0 = blockIdx.y * 32;
    for (int i = threadIdx.y; i < 32; i += 8)
        tile[i][threadIdx.x] = Wyb[(size_t)(p0 + i) * C_ + c0 + threadIdx.x];
    __syncthreads();
    for (int i = threadIdx.y; i < 32; i += 8) {
        int c = c0 + i;
        size_t o = (size_t)c * NPIX + p0 + threadIdx.x;
        ob[o] = tile[threadIdx.x][i] * sc[c] + sh[c] + xb[o];
    }
}

extern "C" void kernel_launch(void* const* d_in, const int* in_sizes, int n_in,
                              void* d_out, int out_size, void* d_ws, size_t ws_size,
                              hipStream_t stream) {
    (void)in_sizes; (void)n_in; (void)out_size; (void)ws_size;
    const float* x     = (const float*)d_in[0];
    const float* mask  = (const float*)d_in[1];
    const float* g_w   = (const float*)d_in[2];
    const float* g_b   = (const float*)d_in[3];
    const float* th_w  = (const float*)d_in[4];
    const float* th_b  = (const float*)d_in[5];
    const float* ph_w  = (const float*)d_in[6];
    const float* ph_b  = (const float*)d_in[7];
    const float* W_w   = (const float*)d_in[8];
    const float* W_b   = (const float*)d_in[9];
    const float* gamma = (const float*)d_in[10];
    const float* beta  = (const float*)d_in[11];
    float* out = (float*)d_out;

    char* ws = (char*)d_ws;
    // [0, 25.69MB) timeline: A-planes -> {gcf,Spart,wS} -> part (2x12.85 fp32) -> Wy
    short* AH    = (short*)(ws + 0);              // 12,845,056
    short* AM    = (short*)(ws + 12845056);       // 12,845,056
    float* gcf   = (float*)(ws + 0);              // 3,211,264 (pool -> gscale)
    float* Spart = (float*)(ws + 4194304);        // 351,232
    float* wS    = (float*)(ws + 5242880);        // 25,088
    float* part  = (float*)(ws + 0);              // 25,690,112 (pv -> ycombine)
    float* Wy    = (float*)(ws + 0);              // 25,690,112 (wconv -> final)
    short* thH   = (short*)(ws + 25690112);       // 6,422,528 (perm)
    short* thM   = (short*)(ws + 32112640);       // 6,422,528 (perm)
    short* wwH   = (short*)(ws + 38535168);       // 65,536 x2
    short* wwM   = wwH + 32768;
    float* pfull = (float*)(ws + 44957696);       // 12,845,056 (pre-pool)
    short* yH    = (short*)(ws + 44957696);       // alias after pool (perm)
    short* yM    = (short*)(ws + 51380224);       // (perm)
    short* gfull = (short*)(ws + 57802752);       // 6,422,528
    short* thwH  = (short*)(ws + 64225280);       // weight scratch (dead after convs)
    short* thwM  = thwH + 32768;
    short* thwL  = thwM + 32768;
    short* phwH  = thwL + 32768;
    short* phwM  = phwH + 32768;
    short* phwL  = phwM + 32768;
    short* gwH   = phwL + 32768;
    short* gwM   = gwH + 32768;
    short* ptH   = (short*)(ws + 64225280);       // 1,605,632 (perm, after convs)
    short* ptM   = (short*)(ws + 65830912);       // 1,605,632 (perm)
    short* gc    = (short*)(ws + 69042176);       // 1,605,632 (perm, scaled)
    float* stat  = (float*)(ws + 71099392);       // 2,048
    float* sc    = (float*)(ws + 71101440);       // 1,024
    float* sh    = (float*)(ws + 71102464);       // 1,024

    hipMemsetAsync(stat, 0, 2048, stream);

    k_splitw<<<512, 256, 0, stream>>>(th_w, ph_w, g_w, W_w, thwH, thwM, thwL,
                                      phwH, phwM, phwL, gwH, gwM, wwH, wwM);

    dim3 tb32(32, 8);
    k_transpose2p<<<dim3(NPIX / 32, C_ / 32, B_), tb32, 0, stream>>>(mask, AH, AM);
    k_conv5<<<dim3(NPIX / 32, B_), 128, 0, stream>>>(AH, AM, thwH, thwM, thwL, th_b, thH, thM);

    k_transpose2p<<<dim3(NPIX / 32, C_ / 32, B_), tb32, 0, stream>>>(x, AH, AM);
    k_convxg5<<<dim3(NPIX / 32, B_), 128, 0, stream>>>(AH, AM, phwH, phwM, phwL, gwH, gwM,
                                                       ph_b, g_b, pfull, gfull);

    k_pool<<<dim3(NS * CI_ / 256, B_), 256, 0, stream>>>(pfull, gfull, ptH, ptM, gcf);

    k_stats<<<dim3(NS / 64, NSL, B_), 128, 0, stream>>>(thH, thM, ptH, ptM, Spart);
    k_combine<<<(B_ * NS + 255) / 256, 256, 0, stream>>>(Spart, wS);
    k_gscale<<<(B_ * CI_ * (NS / 8)) / 256, 256, 0, stream>>>(gcf, wS, gc);

    k_pv<<<dim3(NPIX / 64, 2, B_), 128, 0, stream>>>(thH, thM, ptH, ptM, gc, part);

    k_ycombine<<<(int)(((size_t)B_ * NPIX * CI_ + 255) / 256), 256, 0, stream>>>(part, yH, yM);

    k_wconv3<<<dim3(NPIX / 64, C_ / 128, B_), 256, 0, stream>>>(yH, yM, wwH, wwM, W_b, Wy, stat);
    k_bnfin<<<1, 256, 0, stream>>>(stat, gamma, beta, sc, sh);
    k_final<<<dim3(NPIX / 32, C_ / 32, B_), tb32, 0, stream>>>(Wy, x, sc, sh, out);
}

// Round 10
// 521.575 us; speedup vs baseline: 3.0201x; 1.0168x over previous
//
#include <hip/hip_runtime.h>

// pSGM non-local block, MI355X (round 10: pv occupancy x2 via fp16 partials).
// r9: 530us, absmax 0.5; k_pv 139us @ MfmaUtil 23 / Occ 16.4 — 1.5 waves/SIMD can't
// hide the per-step L2 latency. |y| <= max|g| ~5 so fp16 partials are safe
// (delta ~0.008 -> +0.25 absmax worst case; r7's bf16 datum scales to this).
// r10: pv m-slice x4, fp16 partials (25.69MB exact fit) -> 3136 waves = 3/SIMD;
// stats NSL 28 -> 21.4 waves/CU; ycombine sums 4 fp16.

#define B_ 2
#define C_ 256
#define CI_ 128
#define NPIX 12544
#define NS 3136
#define NSL 28

typedef short bf16x8 __attribute__((ext_vector_type(8)));
typedef float f32x4 __attribute__((ext_vector_type(4)));

__device__ __forceinline__ short f2bf(float f) {
    unsigned u = __float_as_uint(f);
    u = (u + 0x7fff + ((u >> 16) & 1)) >> 16;   // RNE
    return (short)u;
}
__device__ __forceinline__ float bf2f(short s) {
    return __uint_as_float(((unsigned)(unsigned short)s) << 16);
}
__device__ __forceinline__ short f2h(float f) {
    _Float16 h = (_Float16)f;
    short s;
    __builtin_memcpy(&s, &h, 2);
    return s;
}
__device__ __forceinline__ float h2f(short s) {
    _Float16 h;
    __builtin_memcpy(&h, &s, 2);
    return (float)h;
}
__device__ __forceinline__ f32x4 mfma16(bf16x8 a, bf16x8 b, f32x4 c) {
    return __builtin_amdgcn_mfma_f32_16x16x32_bf16(a, b, c, 0, 0, 0);
}
// perm layout, K=128 operands (theta/phi/g/y): frag-contiguous 1KB wave-loads
__device__ __forceinline__ size_t pidx(int r, int k) {
    return (size_t)((r >> 4) * 4 + (k >> 5)) * 512 +
           (size_t)(((k >> 3) & 3) * 128 + (r & 15) * 8 + (k & 7));
}
// perm layout, K=256 operands (conv A inputs)
__device__ __forceinline__ size_t pidx256(int r, int k) {
    return (size_t)((r >> 4) * 8 + (k >> 5)) * 512 +
           (size_t)(((k >> 3) & 3) * 128 + (r & 15) * 8 + (k & 7));
}

struct Frag3 { bf16x8 h, m, l; };
struct Frag2 { bf16x8 h, m; };

__device__ __forceinline__ Frag3 ld3(const short* __restrict__ h, const short* __restrict__ m,
                                     const short* __restrict__ l, size_t off) {
    Frag3 f;
    f.h = *(const bf16x8*)(h + off);
    f.m = *(const bf16x8*)(m + off);
    f.l = *(const bf16x8*)(l + off);
    return f;
}
__device__ __forceinline__ Frag2 ld2(const short* __restrict__ h, const short* __restrict__ m,
                                     size_t off) {
    Frag2 f;
    f.h = *(const bf16x8*)(h + off);
    f.m = *(const bf16x8*)(m + off);
    return f;
}
// 5-term conv product: A 2-plane (exact to 2^-17) x W 3-plane
__device__ __forceinline__ f32x4 mm5(Frag2 a, Frag3 w, f32x4 acc) {
    acc = mfma16(a.h, w.l, acc);
    acc = mfma16(a.m, w.m, acc);
    acc = mfma16(a.m, w.h, acc);
    acc = mfma16(a.h, w.m, acc);
    acc = mfma16(a.h, w.h, acc);
    return acc;
}
__device__ __forceinline__ f32x4 mm3(Frag2 a, Frag2 b, f32x4 acc) {
    acc = mfma16(a.m, b.h, acc);
    acc = mfma16(a.h, b.m, acc);
    acc = mfma16(a.h, b.h, acc);
    return acc;
}
// build PV A-frag from f^T tile pair. ALL shuffles unconditional (full exec mask);
// select on materialized registers only (v_cndmask, no divergent branch around shfl).
__device__ __forceinline__ bf16x8 mk_pa(f32x4 f0, f32x4 f1, int srcLo, int srcHi, bool hiTile) {
    unsigned t0d0 = (unsigned)(unsigned short)f2bf(__expf(f0[0] - 32.f)) |
                    ((unsigned)(unsigned short)f2bf(__expf(f0[1] - 32.f)) << 16);
    unsigned t0d1 = (unsigned)(unsigned short)f2bf(__expf(f0[2] - 32.f)) |
                    ((unsigned)(unsigned short)f2bf(__expf(f0[3] - 32.f)) << 16);
    unsigned t1d0 = (unsigned)(unsigned short)f2bf(__expf(f1[0] - 32.f)) |
                    ((unsigned)(unsigned short)f2bf(__expf(f1[1] - 32.f)) << 16);
    unsigned t1d1 = (unsigned)(unsigned short)f2bf(__expf(f1[2] - 32.f)) |
                    ((unsigned)(unsigned short)f2bf(__expf(f1[3] - 32.f)) << 16);
    unsigned lo0t0 = __shfl(t0d0, srcLo), lo1t0 = __shfl(t0d1, srcLo);
    unsigned hi0t0 = __shfl(t0d0, srcHi), hi1t0 = __shfl(t0d1, srcHi);
    unsigned lo0t1 = __shfl(t1d0, srcLo), lo1t1 = __shfl(t1d1, srcLo);
    unsigned hi0t1 = __shfl(t1d0, srcHi), hi1t1 = __shfl(t1d1, srcHi);
    unsigned pd[4];
    pd[0] = hiTile ? lo0t1 : lo0t0;
    pd[1] = hiTile ? lo1t1 : lo1t0;
    pd[2] = hiTile ? hi0t1 : hi0t0;
    pd[3] = hiTile ? hi1t1 : hi1t0;
    bf16x8 pa;
    __builtin_memcpy(&pa, pd, 16);
    return pa;
}

// ---- merged weight pre-split: theta/phi 3-plane, g/W 2-plane ----
__global__ void k_splitw(const float* __restrict__ thw, const float* __restrict__ phw,
                         const float* __restrict__ gw, const float* __restrict__ Ww,
                         short* __restrict__ thwH, short* __restrict__ thwM, short* __restrict__ thwL,
                         short* __restrict__ phwH, short* __restrict__ phwM, short* __restrict__ phwL,
                         short* __restrict__ gwH, short* __restrict__ gwM,
                         short* __restrict__ wwH, short* __restrict__ wwM) {
    int i = blockIdx.x * 256 + threadIdx.x;
    int which = i >> 15, j = i & 32767;
    if (which == 0) {
        float x = thw[j];
        unsigned uh = __float_as_uint(x) & 0xffff0000u;
        float r1 = x - __uint_as_float(uh);
        unsigned um = __float_as_uint(r1) & 0xffff0000u;
        thwH[j] = (short)(uh >> 16);
        thwM[j] = (short)(um >> 16);
        thwL[j] = f2bf(r1 - __uint_as_float(um));
    } else if (which == 1) {
        float x = phw[j];
        unsigned uh = __float_as_uint(x) & 0xffff0000u;
        float r1 = x - __uint_as_float(uh);
        unsigned um = __float_as_uint(r1) & 0xffff0000u;
        phwH[j] = (short)(uh >> 16);
        phwM[j] = (short)(um >> 16);
        phwL[j] = f2bf(r1 - __uint_as_float(um));
    } else if (which == 2) {
        float x = gw[j];
        unsigned uh = __float_as_uint(x) & 0xffff0000u;
        gwH[j] = (short)(uh >> 16);
        gwM[j] = f2bf(x - __uint_as_float(uh));
    } else {
        float x = Ww[j];
        unsigned uh = __float_as_uint(x) & 0xffff0000u;
        wwH[j] = (short)(uh >> 16);
        wwM[j] = f2bf(x - __uint_as_float(uh));
    }
}

// ---- transpose + 2-plane split into perm(K=256) ----
__global__ void k_transpose2p(const float* __restrict__ src, short* __restrict__ oh,
                              short* __restrict__ om) {
    __shared__ float tile[32][33];
    int b = blockIdx.z;
    const float* s = src + (size_t)b * C_ * NPIX;
    size_t ob = (size_t)b * NPIX * C_;
    int p0 = blockIdx.x * 32, c0 = blockIdx.y * 32;
    for (int i = threadIdx.y; i < 32; i += 8)
        tile[i][threadIdx.x] = s[(size_t)(c0 + i) * NPIX + p0 + threadIdx.x];
    __syncthreads();
    for (int i = threadIdx.y; i < 32; i += 8) {
        float v = tile[threadIdx.x][i];
        unsigned uh = __float_as_uint(v) & 0xffff0000u;
        size_t o = ob + pidx256(p0 + i, c0 + threadIdx.x);
        oh[o] = (short)(uh >> 16);
        om[o] = f2bf(v - __uint_as_float(uh));
    }
}

// ---- theta conv: 5-term, 2 row-tiles/block. grid (NPIX/32, B), block 128 ----
__global__ __launch_bounds__(128, 2) void k_conv5(const short* __restrict__ AH,
        const short* __restrict__ AM,
        const short* __restrict__ WH, const short* __restrict__ WM, const short* __restrict__ WL,
        const float* __restrict__ bias, short* __restrict__ oh, short* __restrict__ om) {
    int wid = threadIdx.x >> 6, lane = threadIdx.x & 63;
    int quad = lane >> 4, l16 = lane & 15;
    int b = blockIdx.y;
    size_t ab = (size_t)b * NPIX * C_;
    size_t ob = (size_t)b * NPIX * CI_;
    int rt0 = blockIdx.x * 2;
    f32x4 acc[2][4] = {};
    for (int kt = 0; kt < 8; kt++) {
        Frag2 a0 = ld2(AH, AM, ab + ((size_t)rt0 * 8 + kt) * 512 + lane * 8);
        Frag2 a1 = ld2(AH, AM, ab + ((size_t)(rt0 + 1) * 8 + kt) * 512 + lane * 8);
#pragma unroll
        for (int c4 = 0; c4 < 4; c4++) {
            int c = (wid * 4 + c4) * 16 + l16;
            Frag3 w = ld3(WH, WM, WL, (size_t)c * C_ + kt * 32 + quad * 8);
            acc[0][c4] = mm5(a0, w, acc[0][c4]);
            acc[1][c4] = mm5(a1, w, acc[1][c4]);
        }
    }
#pragma unroll
    for (int t2 = 0; t2 < 2; t2++)
#pragma unroll
        for (int c4 = 0; c4 < 4; c4++) {
            int c = (wid * 4 + c4) * 16 + l16;
            float bv = bias[c];
#pragma unroll
            for (int r = 0; r < 4; r++) {
                float v = acc[t2][c4][r] + bv;
                unsigned uh = __float_as_uint(v) & 0xffff0000u;
                size_t o = ob + pidx((rt0 + t2) * 16 + quad * 4 + r, c);
                oh[o] = (short)(uh >> 16);
                om[o] = f2bf(v - __uint_as_float(uh));
            }
        }
}

// ---- fused phi(5-term->fp32) + g(3-term->bf16), 2 row-tiles/block ----
__global__ __launch_bounds__(128, 2) void k_convxg5(const short* __restrict__ AH,
        const short* __restrict__ AM,
        const short* __restrict__ PH, const short* __restrict__ PM, const short* __restrict__ PL,
        const short* __restrict__ GH, const short* __restrict__ GM,
        const float* __restrict__ pbias, const float* __restrict__ gbias,
        float* __restrict__ pfull, short* __restrict__ gout) {
    int wid = threadIdx.x >> 6, lane = threadIdx.x & 63;
    int quad = lane >> 4, l16 = lane & 15;
    int b = blockIdx.y;
    size_t ab = (size_t)b * NPIX * C_;
    float* Pb = pfull + (size_t)b * NPIX * CI_;
    short* Gb = gout + (size_t)b * NPIX * CI_;
    int rt0 = blockIdx.x * 2;
    f32x4 accp[2][4] = {}, accg[2][4] = {};
    for (int kt = 0; kt < 8; kt++) {
        Frag2 a0 = ld2(AH, AM, ab + ((size_t)rt0 * 8 + kt) * 512 + lane * 8);
        Frag2 a1 = ld2(AH, AM, ab + ((size_t)(rt0 + 1) * 8 + kt) * 512 + lane * 8);
#pragma unroll
        for (int c4 = 0; c4 < 4; c4++) {
            int c = (wid * 4 + c4) * 16 + l16;
            size_t wo = (size_t)c * C_ + kt * 32 + quad * 8;
            Frag3 wp = ld3(PH, PM, PL, wo);
            accp[0][c4] = mm5(a0, wp, accp[0][c4]);
            accp[1][c4] = mm5(a1, wp, accp[1][c4]);
            Frag2 wg = ld2(GH, GM, wo);
            accg[0][c4] = mm3(a0, wg, accg[0][c4]);
            accg[1][c4] = mm3(a1, wg, accg[1][c4]);
        }
    }
#pragma unroll
    for (int t2 = 0; t2 < 2; t2++)
#pragma unroll
        for (int c4 = 0; c4 < 4; c4++) {
            int c = (wid * 4 + c4) * 16 + l16;
            float pbv = pbias[c], gbv = gbias[c];
#pragma unroll
            for (int r = 0; r < 4; r++) {
                size_t o = (size_t)((rt0 + t2) * 16 + quad * 4 + r) * CI_ + c;
                Pb[o] = accp[t2][c4][r] + pbv;
                Gb[o] = f2bf(accg[t2][c4][r] + gbv);
            }
        }
}

// ---- pool: pfull fp32 -> phi 2-plane PERM; gfull bf16 -> gcf fp32 (ci, m) ----
__global__ void k_pool(const float* __restrict__ pfull, const short* __restrict__ gfull,
                       short* __restrict__ pth, short* __restrict__ ptm,
                       float* __restrict__ gcf) {
    int b = blockIdx.y;
    int idx = blockIdx.x * 256 + threadIdx.x;       // idx = m*128 + ci
    int ci = idx & 127, m = idx >> 7;
    int t = m / 196, r2i = m - t * 196;
    int h2 = r2i / 14, w2 = r2i - h2 * 14;
    size_t p = (size_t)t * 784 + (size_t)(2 * h2) * 28 + 2 * w2;
    size_t i0 = (size_t)b * NPIX * CI_ + p * CI_ + ci;
    float pv = fmaxf(fmaxf(pfull[i0], pfull[i0 + CI_]),
                     fmaxf(pfull[i0 + 28 * CI_], pfull[i0 + 29 * CI_]));
    unsigned uh = __float_as_uint(pv) & 0xffff0000u;
    size_t ob = (size_t)b * NS * CI_ + pidx(m, ci);
    pth[ob] = (short)(uh >> 16);
    ptm[ob] = f2bf(pv - __uint_as_float(uh));
    float g0 = fmaxf(fmaxf(bf2f(gfull[i0]), bf2f(gfull[i0 + CI_])),
                     fmaxf(bf2f(gfull[i0 + 28 * CI_]), bf2f(gfull[i0 + 29 * CI_])));
    gcf[(size_t)b * NS * CI_ + (size_t)ci * NS + m] = g0;
}

// ---- stats: S[m]=sum_n exp(f-32); wave covers 32m. grid (NS/64, NSL, B), block 128 ----
__global__ __launch_bounds__(128, 2) void k_stats(
        const short* __restrict__ thh, const short* __restrict__ thm,
        const short* __restrict__ phh, const short* __restrict__ phm,
        float* __restrict__ Spart) {
    int wid = threadIdx.x >> 6, lane = threadIdx.x & 63;
    int quad = lane >> 4, l16 = lane & 15;
    int b = blockIdx.z;
    size_t tb = (size_t)b * NPIX * CI_, pb = (size_t)b * NS * CI_;
    int mtA = blockIdx.x * 4 + wid * 2;             // m-tiles mtA, mtA+1
    Frag2 bfA[4], bfB[4];
#pragma unroll
    for (int kk = 0; kk < 4; kk++) {
        bfA[kk] = ld2(phh, phm, pb + ((size_t)mtA * 4 + kk) * 512 + lane * 8);
        bfB[kk] = ld2(phh, phm, pb + ((size_t)(mtA + 1) * 4 + kk) * 512 + lane * 8);
    }
    float SA = 0.f, SB = 0.f;
    int t_beg = blockIdx.y * (784 / NSL), t_end = t_beg + 784 / NSL;
    for (int t = t_beg; t < t_end; t += 2) {
        f32x4 aA0 = {}, aA1 = {}, aB0 = {}, aB1 = {};
#pragma unroll
        for (int kk = 0; kk < 4; kk++) {
            Frag2 x0 = ld2(thh, thm, tb + ((size_t)t * 4 + kk) * 512 + lane * 8);
            Frag2 x1 = ld2(thh, thm, tb + ((size_t)(t + 1) * 4 + kk) * 512 + lane * 8);
            aA0 = mm3(x0, bfA[kk], aA0);
            aA1 = mm3(x1, bfA[kk], aA1);
            aB0 = mm3(x0, bfB[kk], aB0);
            aB1 = mm3(x1, bfB[kk], aB1);
        }
        SA += __expf(aA0[0] - 32.f) + __expf(aA0[1] - 32.f) +
              __expf(aA0[2] - 32.f) + __expf(aA0[3] - 32.f) +
              __expf(aA1[0] - 32.f) + __expf(aA1[1] - 32.f) +
              __expf(aA1[2] - 32.f) + __expf(aA1[3] - 32.f);
        SB += __expf(aB0[0] - 32.f) + __expf(aB0[1] - 32.f) +
              __expf(aB0[2] - 32.f) + __expf(aB0[3] - 32.f) +
              __expf(aB1[0] - 32.f) + __expf(aB1[1] - 32.f) +
              __expf(aB1[2] - 32.f) + __expf(aB1[3] - 32.f);
    }
    SA += __shfl_xor(SA, 16, 64); SA += __shfl_xor(SA, 32, 64);
    SB += __shfl_xor(SB, 16, 64); SB += __shfl_xor(SB, 32, 64);
    if (quad == 0) {
        size_t o = ((size_t)(b * NSL + blockIdx.y)) * NS;
        Spart[o + mtA * 16 + l16] = SA;
        Spart[o + (mtA + 1) * 16 + l16] = SB;
    }
}

__global__ void k_combine(const float* __restrict__ Spart, float* __restrict__ wS) {
    int i = blockIdx.x * 256 + threadIdx.x;
    if (i >= B_ * NS) return;
    int b = i / NS, m = i - b * NS;
    float s = 0.f;
#pragma unroll
    for (int sl = 0; sl < NSL; sl++)
        s += Spart[((size_t)(b * NSL + sl)) * NS + m];
    wS[i] = 1.f / s;
}

// ---- g scale into PV-B perm layout ----
__global__ void k_gscale(const float* __restrict__ gcf, const float* __restrict__ wS,
                         short* __restrict__ gc) {
    int i = blockIdx.x * 256 + threadIdx.x;         // B*CI*(NS/8) threads
    int b = i / (CI_ * (NS / 8));
    int rem = i - b * CI_ * (NS / 8);
    int c = rem / (NS / 8);
    int m8 = rem - c * (NS / 8);
    int m = m8 * 8;
    const float* gr = gcf + ((size_t)b * CI_ + c) * NS + m;
    const float* wr = wS + (size_t)b * NS + m;
    short* go = gc + (size_t)b * NS * CI_ + ((size_t)(m8 >> 2) * 8 + (c >> 4)) * 512 +
                (m8 & 3) * 128 + (c & 15) * 8;
#pragma unroll
    for (int j = 0; j < 8; j++) go[j] = f2bf(gr[j] * wr[j]);
}

// ---- PV: wave covers 32n, m-slice x4, fp16 partials. grid (NPIX/64, 4, B), block 128 ----
__global__ __launch_bounds__(128, 2) void k_pv(
        const short* __restrict__ thh, const short* __restrict__ thm,
        const short* __restrict__ phh, const short* __restrict__ phm,
        const short* __restrict__ gp, short* __restrict__ part) {
    int wid = threadIdx.x >> 6, lane = threadIdx.x & 63;
    int quad = lane >> 4, l16 = lane & 15;
    int b = blockIdx.z, slice = blockIdx.y;
    int ntA = blockIdx.x * 4 + wid * 2;             // n-tiles ntA, ntA+1
    size_t tb = (size_t)b * NPIX * CI_, pb = (size_t)b * NS * CI_;
    const short* gpb = gp + (size_t)b * NS * CI_;
    Frag2 afA[4], afB[4];
#pragma unroll
    for (int kk = 0; kk < 4; kk++) {
        afA[kk] = ld2(thh, thm, tb + ((size_t)ntA * 4 + kk) * 512 + lane * 8);
        afB[kk] = ld2(thh, thm, tb + ((size_t)(ntA + 1) * 4 + kk) * 512 + lane * 8);
    }
    f32x4 yaccA[8] = {}, yaccB[8] = {};
    int srcLo = ((2 * quad) & 3) * 16 + l16;
    int srcHi = ((2 * quad + 1) & 3) * 16 + l16;
    bool hiTile = quad >= 2;
    int s_beg = slice * 24 + (slice < 2 ? slice : 2);   // {25,25,24,24} of 98
    int s_end = s_beg + 24 + (slice < 2 ? 1 : 0);
    for (int s = s_beg; s < s_end; s++) {
        f32x4 fA0 = {}, fA1 = {}, fB0 = {}, fB1 = {};
#pragma unroll
        for (int kk = 0; kk < 4; kk++) {
            Frag2 p0 = ld2(phh, phm, pb + ((size_t)(2 * s) * 4 + kk) * 512 + lane * 8);
            Frag2 p1 = ld2(phh, phm, pb + ((size_t)(2 * s + 1) * 4 + kk) * 512 + lane * 8);
            fA0 = mm3(p0, afA[kk], fA0);
            fA1 = mm3(p1, afA[kk], fA1);
            fB0 = mm3(p0, afB[kk], fB0);
            fB1 = mm3(p1, afB[kk], fB1);
        }
        bf16x8 paA = mk_pa(fA0, fA1, srcLo, srcHi, hiTile);
        bf16x8 paB = mk_pa(fB0, fB1, srcLo, srcHi, hiTile);
#pragma unroll
        for (int cc = 0; cc < 8; cc++) {
            bf16x8 gb = *(const bf16x8*)(gpb + (size_t)s * 4096 + cc * 512 + lane * 8);
            yaccA[cc] = mfma16(paA, gb, yaccA[cc]);
            yaccB[cc] = mfma16(paB, gb, yaccB[cc]);
        }
    }
    short* po = part + ((size_t)slice * B_ + b) * NPIX * CI_;
#pragma unroll
    for (int cc = 0; cc < 8; cc++)
#pragma unroll
        for (int r = 0; r < 4; r++) {
            po[pidx(ntA * 16 + quad * 4 + r, cc * 16 + l16)] = f2h(yaccA[cc][r]);
            po[pidx((ntA + 1) * 16 + quad * 4 + r, cc * 16 + l16)] = f2h(yaccB[cc][r]);
        }
}

// ---- combine 4 fp16 y-partials -> 2-plane bf16 (perm order preserved) ----
__global__ void k_ycombine(const short* __restrict__ part, short* __restrict__ yh,
                           short* __restrict__ ym) {
    size_t i = (size_t)blockIdx.x * 256 + threadIdx.x;
    const size_t n = (size_t)B_ * NPIX * CI_;
    if (i >= n) return;
    float v = h2f(part[i]) + h2f(part[n + i]) + h2f(part[2 * n + i]) + h2f(part[3 * n + i]);
    unsigned uh = __float_as_uint(v) & 0xffff0000u;
    yh[i] = (short)(uh >> 16);
    ym[i] = f2bf(v - __uint_as_float(uh));
}

// ---- W conv (3-term, perm y reads) + fused BN stats. grid (NPIX/64, C_/128, B) ----
__global__ __launch_bounds__(256) void k_wconv3(const short* __restrict__ yh,
        const short* __restrict__ ym, const short* __restrict__ WH,
        const short* __restrict__ WM, const float* __restrict__ bias,
        float* __restrict__ Wy, float* __restrict__ stat) {
    int wid = threadIdx.x >> 6, lane = threadIdx.x & 63;
    int quad = lane >> 4, l16 = lane & 15;
    int b = blockIdx.z;
    size_t yb = (size_t)b * NPIX * CI_;
    float* Wyb = Wy + (size_t)b * NPIX * C_;
    int tile = blockIdx.x * 4 + wid;
    int row0 = tile * 16;
    int col0 = blockIdx.y * 128;
    f32x4 acc[8] = {};
#pragma unroll
    for (int kk = 0; kk < 4; kk++) {
        size_t ao = yb + ((size_t)tile * 4 + kk) * 512 + lane * 8;
        bf16x8 ah = *(const bf16x8*)(yh + ao);
        bf16x8 am = *(const bf16x8*)(ym + ao);
#pragma unroll
        for (int cc = 0; cc < 8; cc++) {
            Frag2 w = ld2(WH, WM, (size_t)(col0 + cc * 16 + l16) * CI_ + kk * 32 + quad * 8);
            acc[cc] = mfma16(am, w.h, acc[cc]);
            acc[cc] = mfma16(ah, w.m, acc[cc]);
            acc[cc] = mfma16(ah, w.h, acc[cc]);
        }
    }
#pragma unroll
    for (int cc = 0; cc < 8; cc++) {
        int c = col0 + cc * 16 + l16;
        float bv = bias[c];
        float s1 = 0.f, s2 = 0.f;
#pragma unroll
        for (int r = 0; r < 4; r++) {
            float v = acc[cc][r] + bv;
            Wyb[(size_t)(row0 + quad * 4 + r) * C_ + c] = v;
            s1 += v;
            s2 += v * v;
        }
        s1 += __shfl_xor(s1, 16, 64); s1 += __shfl_xor(s1, 32, 64);
        s2 += __shfl_xor(s2, 16, 64); s2 += __shfl_xor(s2, 32, 64);
        if (quad == 0) {
            atomicAdd(&stat[c], s1);
            atomicAdd(&stat[C_ + c], s2);
        }
    }
}

__global__ void k_bnfin(const float* __restrict__ stat, const float* __restrict__ gamma,
                        const float* __restrict__ beta, float* __restrict__ sc,
                        float* __restrict__ sh) {
    int c = threadIdx.x;
    const float inv = 1.f / (float)(B_ * NPIX);
    float mean = stat[c] * inv;
    float var = stat[C_ + c] * inv - mean * mean;
    float s = gamma[c] * rsqrtf(var + 1e-5f);
    sc[c] = s;
    sh[c] = beta[c] - mean * s;
}

__global__ void k_final(const float* __restrict__ Wy, const float* __restrict__ x,
                        const float* __restrict__ sc, const float* __restrict__ sh,
                        float* __restrict__ out) {
    __shared__ float tile[32][33];
    int b = blockIdx.z;
    const float* Wyb = Wy + (size_t)b * NPIX * C_;
    const float* xb = x + (size_t)b * C_ * NPIX;
    float* ob = out + (size_t)b * C_ * NPIX;
    int p0 = blockIdx.x * 32, c0 = blockIdx.y * 32;
    for (int i = threadIdx.y; i < 32; i += 8)
        tile[i][threadIdx.x] = Wyb[(size_t)(p0 + i) * C_ + c0 + threadIdx.x];
    __syncthreads();
    for (int i = threadIdx.y; i < 32; i += 8) {
        int c = c0 + i;
        size_t o = (size_t)c * NPIX + p0 + threadIdx.x;
        ob[o] = tile[threadIdx.x][i] * sc[c] + sh[c] + xb[o];
    }
}

extern "C" void kernel_launch(void* const* d_in, const int* in_sizes, int n_in,
                              void* d_out, int out_size, void* d_ws, size_t ws_size,
                              hipStream_t stream) {
    (void)in_sizes; (void)n_in; (void)out_size; (void)ws_size;
    const float* x     = (const float*)d_in[0];
    const float* mask  = (const float*)d_in[1];
    const float* g_w   = (const float*)d_in[2];
    const float* g_b   = (const float*)d_in[3];
    const float* th_w  = (const float*)d_in[4];
    const float* th_b  = (const float*)d_in[5];
    const float* ph_w  = (const float*)d_in[6];
    const float* ph_b  = (const float*)d_in[7];
    const float* W_w   = (const float*)d_in[8];
    const float* W_b   = (const float*)d_in[9];
    const float* gamma = (const float*)d_in[10];
    const float* beta  = (const float*)d_in[11];
    float* out = (float*)d_out;

    char* ws = (char*)d_ws;
    // [0, 25.69MB) timeline: A-planes -> {gcf,Spart,wS} -> part (4 slices fp16) -> Wy
    short* AH    = (short*)(ws + 0);              // 12,845,056
    short* AM    = (short*)(ws + 12845056);       // 12,845,056
    float* gcf   = (float*)(ws + 0);              // 3,211,264 (pool -> gscale)
    float* Spart = (float*)(ws + 4194304);        // 702,464 (NSL=28)
    float* wS    = (float*)(ws + 5242880);        // 25,088
    short* part  = (short*)(ws + 0);              // 25,690,112 = 4 x 6,422,528 (fp16)
    float* Wy    = (float*)(ws + 0);              // 25,690,112 (wconv -> final)
    short* thH   = (short*)(ws + 25690112);       // 6,422,528 (perm)
    short* thM   = (short*)(ws + 32112640);       // 6,422,528 (perm)
    short* wwH   = (short*)(ws + 38535168);       // 65,536 x2
    short* wwM   = wwH + 32768;
    float* pfull = (float*)(ws + 44957696);       // 12,845,056 (pre-pool)
    short* yH    = (short*)(ws + 44957696);       // alias after pool (perm)
    short* yM    = (short*)(ws + 51380224);       // (perm)
    short* gfull = (short*)(ws + 57802752);       // 6,422,528
    short* thwH  = (short*)(ws + 64225280);       // weight scratch (dead after convs)
    short* thwM  = thwH + 32768;
    short* thwL  = thwM + 32768;
    short* phwH  = thwL + 32768;
    short* phwM  = phwH + 32768;
    short* phwL  = phwM + 32768;
    short* gwH   = phwL + 32768;
    short* gwM   = gwH + 32768;
    short* ptH   = (short*)(ws + 64225280);       // 1,605,632 (perm, after convs)
    short* ptM   = (short*)(ws + 65830912);       // 1,605,632 (perm)
    short* gc    = (short*)(ws + 69042176);       // 1,605,632 (perm, scaled)
    float* stat  = (float*)(ws + 71099392);       // 2,048
    float* sc    = (float*)(ws + 71101440);       // 1,024
    float* sh    = (float*)(ws + 71102464);       // 1,024

    hipMemsetAsync(stat, 0, 2048, stream);

    k_splitw<<<512, 256, 0, stream>>>(th_w, ph_w, g_w, W_w, thwH, thwM, thwL,
                                      phwH, phwM, phwL, gwH, gwM, wwH, wwM);

    dim3 tb32(32, 8);
    k_transpose2p<<<dim3(NPIX / 32, C_ / 32, B_), tb32, 0, stream>>>(mask, AH, AM);
    k_conv5<<<dim3(NPIX / 32, B_), 128, 0, stream>>>(AH, AM, thwH, thwM, thwL, th_b, thH, thM);

    k_transpose2p<<<dim3(NPIX / 32, C_ / 32, B_), tb32, 0, stream>>>(x, AH, AM);
    k_convxg5<<<dim3(NPIX / 32, B_), 128, 0, stream>>>(AH, AM, phwH, phwM, phwL, gwH, gwM,
                                                       ph_b, g_b, pfull, gfull);

    k_pool<<<dim3(NS * CI_ / 256, B_), 256, 0, stream>>>(pfull, gfull, ptH, ptM, gcf);

    k_stats<<<dim3(NS / 64, NSL, B_), 128, 0, stream>>>(thH, thM, ptH, ptM, Spart);
    k_combine<<<(B_ * NS + 255) / 256, 256, 0, stream>>>(Spart, wS);
    k_gscale<<<(B_ * CI_ * (NS / 8)) / 256, 256, 0, stream>>>(gcf, wS, gc);

    k_pv<<<dim3(NPIX / 64, 4, B_), 128, 0, stream>>>(thH, thM, ptH, ptM, gc, part);

    k_ycombine<<<(int)(((size_t)B_ * NPIX * CI_ + 255) / 256), 256, 0, stream>>>(part, yH, yM);

    k_wconv3<<<dim3(NPIX / 64, C_ / 128, B_), 256, 0, stream>>>(yH, yM, wwH, wwM, W_b, Wy, stat);
    k_bnfin<<<1, 256, 0, stream>>>(stat, gamma, beta, sc, sh);
    k_final<<<dim3(NPIX / 32, C_ / 32, B_), tb32, 0, stream>>>(Wy, x, sc, sh, out);
}